// Round 3
// baseline (159.440 us; speedup 1.0000x reference)
//
#include <hip/hip_runtime.h>
#include <math.h>

// Problem dims (fixed by the reference)
#define B_DIM 4096
#define F_DIM 1024
#define C_DIM 2047
#define C_PAD 2048
#define DEPTH 11

typedef __attribute__((ext_vector_type(8))) short bf16x8;
typedef __attribute__((ext_vector_type(4))) float f32x4;
typedef unsigned short ushort_t;

#define AS1(p) ((const __attribute__((address_space(1))) void*)(p))
#define AS3(p) ((__attribute__((address_space(3))) void*)(p))

// ---------------------------------------------------------------------------
// bf16 split helpers (RNE)
// ---------------------------------------------------------------------------
__device__ __forceinline__ unsigned short f2bf(float f) {
    unsigned int u = __float_as_uint(f);
    unsigned int r = (u + 0x7fffu + ((u >> 16) & 1u)) >> 16;
    return (unsigned short)r;
}
__device__ __forceinline__ float bf2f(unsigned short h) {
    return __uint_as_float(((unsigned int)h) << 16);
}

// ---------------------------------------------------------------------------
// Fused convert: x (B,F) -> xhi/xlo ; w (C,F) -> whi/wlo (padded to C_PAD rows)
// ---------------------------------------------------------------------------
#define XTOT (B_DIM * F_DIM)          // 4194304
#define WTOT (C_PAD * F_DIM)          // 2097152

__global__ __launch_bounds__(256) void cvt_kernel(
    const float* __restrict__ x, const float* __restrict__ w,
    unsigned short* __restrict__ xhi, unsigned short* __restrict__ xlo,
    unsigned short* __restrict__ whi, unsigned short* __restrict__ wlo)
{
    const int i = (blockIdx.x * 256 + threadIdx.x) * 4;
    if (i < XTOT) {
        float4 v = *(const float4*)(x + i);
        ushort4 h, l;
        h.x = f2bf(v.x); l.x = f2bf(v.x - bf2f(h.x));
        h.y = f2bf(v.y); l.y = f2bf(v.y - bf2f(h.y));
        h.z = f2bf(v.z); l.z = f2bf(v.z - bf2f(h.z));
        h.w = f2bf(v.w); l.w = f2bf(v.w - bf2f(h.w));
        *(ushort4*)(xhi + i) = h;
        *(ushort4*)(xlo + i) = l;
    } else {
        const int j = i - XTOT;                    // < WTOT
        const int row = j >> 10;                   // F = 1024
        ushort4 h = {0, 0, 0, 0}, l = {0, 0, 0, 0};
        if (row < C_DIM) {
            float4 v = *(const float4*)(w + j);
            h.x = f2bf(v.x); l.x = f2bf(v.x - bf2f(h.x));
            h.y = f2bf(v.y); l.y = f2bf(v.y - bf2f(h.y));
            h.z = f2bf(v.z); l.z = f2bf(v.z - bf2f(h.z));
            h.w = f2bf(v.w); l.w = f2bf(v.w - bf2f(h.w));
        }
        *(ushort4*)(whi + j) = h;
        *(ushort4*)(wlo + j) = l;
    }
}

// ---------------------------------------------------------------------------
// K-split MFMA GEMM. blockIdx.z selects the K-partition:
//   z=0: xhi.whi^T (K=1024) + xlo.whi^T (k<512)   -> e0 = d_out (+bias)
//   z=1: xhi.wlo^T (K=1024) + xlo.whi^T (k>=512)  -> e1 in ws (stride C_PAD)
// 128x128 tile, BK=32, 256 threads (4 waves 2x2), 16x16x32 bf16 MFMA,
// global_load_lds width-16 staging, 2-way-free chunk swizzle s(row)=(row>>1)&3.
// ---------------------------------------------------------------------------
__global__ __launch_bounds__(256) void gemm_mfma_split(
    const unsigned short* __restrict__ xhi, const unsigned short* __restrict__ xlo,
    const unsigned short* __restrict__ whi, const unsigned short* __restrict__ wlo,
    const float* __restrict__ bias, float* __restrict__ e0, float* __restrict__ e1)
{
    __shared__ unsigned short smemA[128 * 32];  // [row][k] 64B rows
    __shared__ unsigned short smemB[128 * 32];

    const int tid  = threadIdx.x;
    const int lane = tid & 63;
    const int wave = tid >> 6;
    const int wr = wave >> 1, wc = wave & 1;
    const int bn = blockIdx.x, bm = blockIdx.y, z = blockIdx.z;

    f32x4 acc[4][4] = {};

    // staging: slot s = tid (+256); row = s>>2, chunk = s&3
    // LDS slot (row,c) holds global chunk c ^ s(row), s(row) = (row>>1)&3
    const int r0 = tid >> 2,          c0 = tid & 3;
    const int r1 = (tid + 256) >> 2,  c1 = tid & 3;
    const int sc0 = ((c0 ^ ((r0 >> 1) & 3)) << 3);  // element offset in k-tile
    const int sc1 = ((c1 ^ ((r1 >> 1) & 3)) << 3);

    const size_t arow0 = (size_t)(bm * 128 + r0) * F_DIM;
    const size_t arow1 = (size_t)(bm * 128 + r1) * F_DIM;
    const size_t brow0 = (size_t)(bn * 128 + r0) * F_DIM;
    const size_t brow1 = (size_t)(bn * 128 + r1) * F_DIM;

    unsigned short* ldsA0 = smemA + wave * 512;
    unsigned short* ldsA1 = smemA + 2048 + wave * 512;
    unsigned short* ldsB0 = smemB + wave * 512;
    unsigned short* ldsB1 = smemB + 2048 + wave * 512;

    const int fra = wr * 64 + (lane & 15);
    const int frb = wc * 64 + (lane & 15);
    const int kc  = lane >> 4;

    // sub-segment tables
    const unsigned short* sA[2];
    const unsigned short* sB[2];
    int kb[2], ke[2];
    sA[0] = xhi; sB[0] = z ? wlo : whi; kb[0] = 0;           ke[0] = 1024;
    sA[1] = xlo; sB[1] = whi;           kb[1] = z ? 512 : 0; ke[1] = kb[1] + 512;

#pragma unroll
    for (int ss = 0; ss < 2; ++ss) {
        const unsigned short* Ap = sA[ss];
        const unsigned short* Bp = sB[ss];
        for (int k0 = kb[ss]; k0 < ke[ss]; k0 += 32) {
            __builtin_amdgcn_global_load_lds(AS1(Ap + arow0 + k0 + sc0), AS3(ldsA0), 16, 0, 0);
            __builtin_amdgcn_global_load_lds(AS1(Ap + arow1 + k0 + sc1), AS3(ldsA1), 16, 0, 0);
            __builtin_amdgcn_global_load_lds(AS1(Bp + brow0 + k0 + sc0), AS3(ldsB0), 16, 0, 0);
            __builtin_amdgcn_global_load_lds(AS1(Bp + brow1 + k0 + sc1), AS3(ldsB1), 16, 0, 0);
            __syncthreads();

            bf16x8 af[4], bfr[4];
#pragma unroll
            for (int m = 0; m < 4; ++m) {
                const int row = fra + m * 16;
                af[m] = *(const bf16x8*)(smemA + row * 32 + ((kc ^ ((row >> 1) & 3)) << 3));
            }
#pragma unroll
            for (int n = 0; n < 4; ++n) {
                const int row = frb + n * 16;
                bfr[n] = *(const bf16x8*)(smemB + row * 32 + ((kc ^ ((row >> 1) & 3)) << 3));
            }
#pragma unroll
            for (int m = 0; m < 4; ++m)
#pragma unroll
                for (int n = 0; n < 4; ++n)
                    acc[m][n] = __builtin_amdgcn_mfma_f32_16x16x32_bf16(
                        af[m], bfr[n], acc[m][n], 0, 0, 0);
            __syncthreads();
        }
    }

    // Epilogue: C/D layout col = lane&15, row = (lane>>4)*4 + r
    const int colbase = bn * 128 + wc * 64 + (lane & 15);
    const int rowbase = bm * 128 + wr * 64 + ((lane >> 4) << 2);
    if (z == 0) {
#pragma unroll
        for (int m = 0; m < 4; ++m)
#pragma unroll
            for (int n = 0; n < 4; ++n) {
                const int gc = colbase + n * 16;
                if (gc < C_DIM) {
                    const float bv = bias[gc];
#pragma unroll
                    for (int r = 0; r < 4; ++r)
                        e0[(size_t)(rowbase + m * 16 + r) * C_DIM + gc] = acc[m][n][r] + bv;
                }
            }
    } else {
#pragma unroll
        for (int m = 0; m < 4; ++m)
#pragma unroll
            for (int n = 0; n < 4; ++n) {
                const int gc = colbase + n * 16;
#pragma unroll
                for (int r = 0; r < 4; ++r)
                    e1[(size_t)(rowbase + m * 16 + r) * C_PAD + gc] = acc[m][n][r];
            }
    }
}

// ---------------------------------------------------------------------------
// Fallback: 3-segment in-kernel MFMA GEMM (used if ws too small for e1)
// ---------------------------------------------------------------------------
__global__ __launch_bounds__(256) void gemm_mfma_kernel(
    const unsigned short* __restrict__ xhi, const unsigned short* __restrict__ xlo,
    const unsigned short* __restrict__ whi, const unsigned short* __restrict__ wlo,
    const float* __restrict__ bias, float* __restrict__ e)
{
    __shared__ unsigned short smemA[128 * 32];
    __shared__ unsigned short smemB[128 * 32];

    const int tid  = threadIdx.x;
    const int lane = tid & 63;
    const int wave = tid >> 6;
    const int wr = wave >> 1, wc = wave & 1;
    const int bn = blockIdx.x, bm = blockIdx.y;

    f32x4 acc[4][4] = {};
    const int r0 = tid >> 2,         c0 = tid & 3;
    const int r1 = (tid + 256) >> 2, c1 = tid & 3;
    const int sc0 = ((c0 ^ ((r0 >> 1) & 3)) << 3);
    const int sc1 = ((c1 ^ ((r1 >> 1) & 3)) << 3);

    const size_t arow0 = (size_t)(bm * 128 + r0) * F_DIM;
    const size_t arow1 = (size_t)(bm * 128 + r1) * F_DIM;
    const size_t brow0 = (size_t)(bn * 128 + r0) * F_DIM;
    const size_t brow1 = (size_t)(bn * 128 + r1) * F_DIM;

    unsigned short* ldsA0 = smemA + wave * 512;
    unsigned short* ldsA1 = smemA + 2048 + wave * 512;
    unsigned short* ldsB0 = smemB + wave * 512;
    unsigned short* ldsB1 = smemB + 2048 + wave * 512;

    const int fra = wr * 64 + (lane & 15);
    const int frb = wc * 64 + (lane & 15);
    const int kc  = lane >> 4;

    for (int seg = 0; seg < 3; ++seg) {
        const unsigned short* Ap = (seg == 2) ? xlo : xhi;
        const unsigned short* Bp = (seg == 1) ? wlo : whi;
        for (int k0 = 0; k0 < F_DIM; k0 += 32) {
            __builtin_amdgcn_global_load_lds(AS1(Ap + arow0 + k0 + sc0), AS3(ldsA0), 16, 0, 0);
            __builtin_amdgcn_global_load_lds(AS1(Ap + arow1 + k0 + sc1), AS3(ldsA1), 16, 0, 0);
            __builtin_amdgcn_global_load_lds(AS1(Bp + brow0 + k0 + sc0), AS3(ldsB0), 16, 0, 0);
            __builtin_amdgcn_global_load_lds(AS1(Bp + brow1 + k0 + sc1), AS3(ldsB1), 16, 0, 0);
            __syncthreads();

            bf16x8 af[4], bfr[4];
#pragma unroll
            for (int m = 0; m < 4; ++m) {
                const int row = fra + m * 16;
                af[m] = *(const bf16x8*)(smemA + row * 32 + ((kc ^ ((row >> 1) & 3)) << 3));
            }
#pragma unroll
            for (int n = 0; n < 4; ++n) {
                const int row = frb + n * 16;
                bfr[n] = *(const bf16x8*)(smemB + row * 32 + ((kc ^ ((row >> 1) & 3)) << 3));
            }
#pragma unroll
            for (int m = 0; m < 4; ++m)
#pragma unroll
                for (int n = 0; n < 4; ++n)
                    acc[m][n] = __builtin_amdgcn_mfma_f32_16x16x32_bf16(
                        af[m], bfr[n], acc[m][n], 0, 0, 0);
            __syncthreads();
        }
    }

    const int colbase = bn * 128 + wc * 64 + (lane & 15);
    const int rowbase = bm * 128 + wr * 64 + ((lane >> 4) << 2);
#pragma unroll
    for (int m = 0; m < 4; ++m)
#pragma unroll
        for (int n = 0; n < 4; ++n) {
            const int gc = colbase + n * 16;
            if (gc < C_DIM) {
                const float bv = bias[gc];
#pragma unroll
                for (int r = 0; r < 4; ++r)
                    e[(size_t)(rowbase + m * 16 + r) * C_DIM + gc] = acc[m][n][r] + bv;
            }
        }
}

// ---------------------------------------------------------------------------
// Tree-CRF: block per batch row, compressed LDS (ping-pong levels + alpha-diff)
// ---------------------------------------------------------------------------
__device__ __forceinline__ float lse2(float a, float b) {
    float m = fmaxf(a, b);
    return m + __logf(1.f + __expf(fminf(a, b) - m));
}

template <int HAS_E1>
__global__ __launch_bounds__(256) void crf_kernel(
    const float* __restrict__ pairs,  // (C,C,2,2)
    const float* __restrict__ e1,     // (B,C_PAD) partial, or null
    float* __restrict__ eo)           // (B,C): e0 in, probability out
{
    __shared__ float se[C_DIM];       // scalar emission e
    __shared__ float da[1023];        // alpha[1]-alpha[0] for internal nodes
    __shared__ float P0[2048];        // level ping-pong (pairs of labels)
    __shared__ float P1[2048];

    const int row = blockIdx.x;
    const int tid = threadIdx.x;
    float* erow = eo + (size_t)row * C_DIM;
    const float* e1row = e1 + (size_t)row * C_PAD;

    for (int c = tid; c < C_DIM; c += 256)
        se[c] = HAS_E1 ? (erow[c] + e1row[c]) : erow[c];
    __syncthreads();

    // ---- Up-sweep: levels l = 10..1, one thread per parent ----
    float* cur = P0;   // child-level alpha (both labels)
    float* nxt = P1;
    for (int l = DEPTH - 1; l >= 1; --l) {
        const int np  = 1 << (l - 1);
        const int pg0 = np - 1;
        const bool leaf = (l == DEPTH - 1);
        for (int i = tid; i < np; i += 256) {
            const int p = pg0 + i;
            float a0 = 0.f, a1 = 0.f;
#pragma unroll
            for (int s = 0; s < 2; ++s) {
                const int c  = 2 * p + 1 + s;
                const int jc = 2 * i + s;
                float ca0 = 0.f, ca1 = 0.f;
                if (!leaf) { ca0 = cur[jc * 2]; ca1 = cur[jc * 2 + 1]; }
                const float l0 = -se[c] + ca0;
                const float l1 =  se[c] + ca1;
                const float4 pe = *(const float4*)(pairs + ((size_t)p * C_DIM + c) * 4);
                a0 += lse2(pe.x + l0, pe.y + l1);
                a1 += lse2(pe.z + l0, pe.w + l1);
            }
            nxt[i * 2]     = a0;
            nxt[i * 2 + 1] = a1;
            da[p] = a1 - a0;
        }
        __syncthreads();
        float* t = cur; cur = nxt; nxt = t;
    }

    // ---- Root output ----
    if (tid == 0) {
        const float d = 2.f * se[0] + da[0];
        erow[0] = 1.f / (1.f + __expf(-d));
    }

    // ---- Down-sweep: levels l = 1..10, one thread per child; emit output ----
    float* bcur = P0;
    float* bnxt = P1;
    for (int l = 1; l <= DEPTH - 1; ++l) {
        const int nc  = 1 << l;
        const int cg0 = nc - 1;
        const bool top = (l == 1);
        for (int j = tid; j < nc; j += 256) {
            const int c  = cg0 + j;
            const int p  = (c - 1) >> 1;
            const int ip = j >> 1;
            float b0 = 0.f, b1 = 0.f;
            if (!top) { b0 = bcur[ip * 2]; b1 = bcur[ip * 2 + 1]; }
            const float lp0 = -se[p] + b0;
            const float lp1 =  se[p] + b1;
            const float4 pe = *(const float4*)(pairs + ((size_t)p * C_DIM + c) * 4);
            const float bc0 = lse2(lp0 + pe.x, lp1 + pe.z);
            const float bc1 = lse2(lp0 + pe.y, lp1 + pe.w);
            bnxt[j * 2]     = bc0;
            bnxt[j * 2 + 1] = bc1;
            float d = 2.f * se[c] + (bc1 - bc0);
            if (c < 1023) d += da[c];
            erow[c] = 1.f / (1.f + __expf(-d));
        }
        __syncthreads();
        float* t = bcur; bcur = bnxt; bnxt = t;
    }
}

// ---------------------------------------------------------------------------
extern "C" void kernel_launch(void* const* d_in, const int* in_sizes, int n_in,
                              void* d_out, int out_size, void* d_ws, size_t ws_size,
                              hipStream_t stream) {
    const float* x     = (const float*)d_in[0];
    const float* w     = (const float*)d_in[1];
    const float* bias  = (const float*)d_in[2];
    const float* pairs = (const float*)d_in[3];
    float* out = (float*)d_out;

    const size_t cvt_need = ((size_t)2 * XTOT + (size_t)2 * WTOT) * 2;  // 24 MiB
    const size_t e1_need  = (size_t)B_DIM * C_PAD * 4;                  // 32 MiB

    unsigned short* xhi = (unsigned short*)d_ws;
    unsigned short* xlo = xhi + (size_t)XTOT;
    unsigned short* whi = xlo + (size_t)XTOT;
    unsigned short* wlo = whi + (size_t)WTOT;
    float* e1 = (float*)(wlo + (size_t)WTOT);

    cvt_kernel<<<(XTOT + WTOT) / (256 * 4), 256, 0, stream>>>(x, w, xhi, xlo, whi, wlo);

    if (ws_size >= cvt_need + e1_need) {
        dim3 ggrid(C_PAD / 128, B_DIM / 128, 2);
        gemm_mfma_split<<<ggrid, 256, 0, stream>>>(xhi, xlo, whi, wlo, bias, out, e1);
        crf_kernel<1><<<B_DIM, 256, 0, stream>>>(pairs, e1, out);
    } else {
        dim3 ggrid(C_PAD / 128, B_DIM / 128);
        gemm_mfma_kernel<<<ggrid, 256, 0, stream>>>(xhi, xlo, whi, wlo, bias, out);
        crf_kernel<0><<<B_DIM, 256, 0, stream>>>(pairs, (const float*)nullptr, out);
    }
}

// Round 4
// 142.974 us; speedup vs baseline: 1.1152x; 1.1152x over previous
//
#include <hip/hip_runtime.h>
#include <math.h>

// Problem dims (fixed by the reference)
#define B_DIM 4096
#define F_DIM 1024
#define C_DIM 2047
#define C_PAD 2048
#define DEPTH 11

typedef __attribute__((ext_vector_type(8))) short bf16x8;
typedef __attribute__((ext_vector_type(4))) float f32x4;

#define AS1(p) ((const __attribute__((address_space(1))) void*)(p))
#define AS3(p) ((__attribute__((address_space(3))) void*)(p))

// ---------------------------------------------------------------------------
// bf16 split helpers (RNE)
// ---------------------------------------------------------------------------
__device__ __forceinline__ unsigned short f2bf(float f) {
    unsigned int u = __float_as_uint(f);
    unsigned int r = (u + 0x7fffu + ((u >> 16) & 1u)) >> 16;
    return (unsigned short)r;
}
__device__ __forceinline__ float bf2f(unsigned short h) {
    return __uint_as_float(((unsigned int)h) << 16);
}

// ---------------------------------------------------------------------------
// Fused convert: x (B,F) -> xhi/xlo ; w (C,F) -> whi/wlo (padded to C_PAD rows)
// ---------------------------------------------------------------------------
#define XTOT (B_DIM * F_DIM)          // 4194304
#define WTOT (C_PAD * F_DIM)          // 2097152

__global__ __launch_bounds__(256) void cvt_kernel(
    const float* __restrict__ x, const float* __restrict__ w,
    unsigned short* __restrict__ xhi, unsigned short* __restrict__ xlo,
    unsigned short* __restrict__ whi, unsigned short* __restrict__ wlo)
{
    const int i = (blockIdx.x * 256 + threadIdx.x) * 4;
    if (i < XTOT) {
        float4 v = *(const float4*)(x + i);
        ushort4 h, l;
        h.x = f2bf(v.x); l.x = f2bf(v.x - bf2f(h.x));
        h.y = f2bf(v.y); l.y = f2bf(v.y - bf2f(h.y));
        h.z = f2bf(v.z); l.z = f2bf(v.z - bf2f(h.z));
        h.w = f2bf(v.w); l.w = f2bf(v.w - bf2f(h.w));
        *(ushort4*)(xhi + i) = h;
        *(ushort4*)(xlo + i) = l;
    } else {
        const int j = i - XTOT;                    // < WTOT
        const int row = j >> 10;                   // F = 1024
        ushort4 h = {0, 0, 0, 0}, l = {0, 0, 0, 0};
        if (row < C_DIM) {
            float4 v = *(const float4*)(w + j);
            h.x = f2bf(v.x); l.x = f2bf(v.x - bf2f(h.x));
            h.y = f2bf(v.y); l.y = f2bf(v.y - bf2f(h.y));
            h.z = f2bf(v.z); l.z = f2bf(v.z - bf2f(h.z));
            h.w = f2bf(v.w); l.w = f2bf(v.w - bf2f(h.w));
        }
        *(ushort4*)(whi + j) = h;
        *(ushort4*)(wlo + j) = l;
    }
}

// ---------------------------------------------------------------------------
// Pack the 2046 tree-edge potentials into a contiguous table:
//   packed[c] = pairs[(c-1)/2][c]   (float4 = [y_par][y_child] 2x2), c in 1..2046
// One-time gather; kills the 32KB-stride scatter in the CRF hot loop.
// ---------------------------------------------------------------------------
__global__ __launch_bounds__(256) void pack_kernel(
    const float* __restrict__ pairs, float4* __restrict__ packed)
{
    const int c = blockIdx.x * 256 + threadIdx.x;
    if (c >= 1 && c < C_DIM) {
        const int p = (c - 1) >> 1;
        packed[c] = *(const float4*)(pairs + ((size_t)p * C_DIM + c) * 4);
    }
}

// ---------------------------------------------------------------------------
// MFMA GEMM: e = x @ W^T + bias over 3 split-bf16 segments (effective K=3072)
// 128x128 tile, BK=32, 256 threads (4 waves, 2x2), 16x16x32 bf16 MFMA.
// global_load_lds width-16 staging; conflict-free chunk swizzle s(row)=(row>>1)&3.
// ---------------------------------------------------------------------------
__global__ __launch_bounds__(256) void gemm_mfma_kernel(
    const unsigned short* __restrict__ xhi, const unsigned short* __restrict__ xlo,
    const unsigned short* __restrict__ whi, const unsigned short* __restrict__ wlo,
    const float* __restrict__ bias, float* __restrict__ e)
{
    __shared__ unsigned short smemA[128 * 32];  // [row][k] 64B rows
    __shared__ unsigned short smemB[128 * 32];

    const int tid  = threadIdx.x;
    const int lane = tid & 63;
    const int wave = tid >> 6;
    const int wr = wave >> 1, wc = wave & 1;
    const int bn = blockIdx.x, bm = blockIdx.y;

    f32x4 acc[4][4] = {};
    const int r0 = tid >> 2,         c0 = tid & 3;
    const int r1 = (tid + 256) >> 2, c1 = tid & 3;
    const int sc0 = ((c0 ^ ((r0 >> 1) & 3)) << 3);
    const int sc1 = ((c1 ^ ((r1 >> 1) & 3)) << 3);

    const size_t arow0 = (size_t)(bm * 128 + r0) * F_DIM;
    const size_t arow1 = (size_t)(bm * 128 + r1) * F_DIM;
    const size_t brow0 = (size_t)(bn * 128 + r0) * F_DIM;
    const size_t brow1 = (size_t)(bn * 128 + r1) * F_DIM;

    unsigned short* ldsA0 = smemA + wave * 512;
    unsigned short* ldsA1 = smemA + 2048 + wave * 512;
    unsigned short* ldsB0 = smemB + wave * 512;
    unsigned short* ldsB1 = smemB + 2048 + wave * 512;

    const int fra = wr * 64 + (lane & 15);
    const int frb = wc * 64 + (lane & 15);
    const int kc  = lane >> 4;

    for (int seg = 0; seg < 3; ++seg) {
        const unsigned short* Ap = (seg == 2) ? xlo : xhi;
        const unsigned short* Bp = (seg == 1) ? wlo : whi;
        for (int k0 = 0; k0 < F_DIM; k0 += 32) {
            __builtin_amdgcn_global_load_lds(AS1(Ap + arow0 + k0 + sc0), AS3(ldsA0), 16, 0, 0);
            __builtin_amdgcn_global_load_lds(AS1(Ap + arow1 + k0 + sc1), AS3(ldsA1), 16, 0, 0);
            __builtin_amdgcn_global_load_lds(AS1(Bp + brow0 + k0 + sc0), AS3(ldsB0), 16, 0, 0);
            __builtin_amdgcn_global_load_lds(AS1(Bp + brow1 + k0 + sc1), AS3(ldsB1), 16, 0, 0);
            __syncthreads();

            bf16x8 af[4], bfr[4];
#pragma unroll
            for (int m = 0; m < 4; ++m) {
                const int row = fra + m * 16;
                af[m] = *(const bf16x8*)(smemA + row * 32 + ((kc ^ ((row >> 1) & 3)) << 3));
            }
#pragma unroll
            for (int n = 0; n < 4; ++n) {
                const int row = frb + n * 16;
                bfr[n] = *(const bf16x8*)(smemB + row * 32 + ((kc ^ ((row >> 1) & 3)) << 3));
            }
#pragma unroll
            for (int m = 0; m < 4; ++m)
#pragma unroll
                for (int n = 0; n < 4; ++n)
                    acc[m][n] = __builtin_amdgcn_mfma_f32_16x16x32_bf16(
                        af[m], bfr[n], acc[m][n], 0, 0, 0);
            __syncthreads();
        }
    }

    // Epilogue: C/D layout col = lane&15, row = (lane>>4)*4 + r
    const int colbase = bn * 128 + wc * 64 + (lane & 15);
    const int rowbase = bm * 128 + wr * 64 + ((lane >> 4) << 2);
#pragma unroll
    for (int m = 0; m < 4; ++m)
#pragma unroll
        for (int n = 0; n < 4; ++n) {
            const int gc = colbase + n * 16;
            if (gc < C_DIM) {
                const float bv = bias[gc];
#pragma unroll
                for (int r = 0; r < 4; ++r)
                    e[(size_t)(rowbase + m * 16 + r) * C_DIM + gc] = acc[m][n][r] + bv;
            }
        }
}

// ---------------------------------------------------------------------------
// Fallback f32 GEMM (only if ws too small for the bf16 split buffers)
// ---------------------------------------------------------------------------
#define BMF 64
#define BNF 64
#define BKF 16

__global__ __launch_bounds__(256) void gemm_f32_kernel(
    const float* __restrict__ x, const float* __restrict__ w,
    const float* __restrict__ bias, float* __restrict__ e)
{
    __shared__ float As[BKF][BMF];
    __shared__ float Bs[BKF][BNF];
    const int bn = blockIdx.x, bm = blockIdx.y;
    const int tid = threadIdx.x;
    const int tx = tid & 15, ty = tid >> 4;
    const int m0 = ty * 4, n0 = tx * 4;
    const int lrow = tid >> 2, lc4 = (tid & 3) * 4;
    const int gm = bm * BMF + lrow;
    const int gn = bn * BNF + lrow;
    const bool wvalid = (gn < C_DIM);
    const float* xp = x + (size_t)gm * F_DIM + lc4;
    const float* wp = wvalid ? (w + (size_t)gn * F_DIM + lc4) : w;
    float acc[4][4] = {};
    for (int k0 = 0; k0 < F_DIM; k0 += BKF) {
        float4 av = *(const float4*)(xp + k0);
        float4 bv = make_float4(0.f, 0.f, 0.f, 0.f);
        if (wvalid) bv = *(const float4*)(wp + k0);
        As[lc4 + 0][lrow] = av.x; As[lc4 + 1][lrow] = av.y;
        As[lc4 + 2][lrow] = av.z; As[lc4 + 3][lrow] = av.w;
        Bs[lc4 + 0][lrow] = bv.x; Bs[lc4 + 1][lrow] = bv.y;
        Bs[lc4 + 2][lrow] = bv.z; Bs[lc4 + 3][lrow] = bv.w;
        __syncthreads();
#pragma unroll
        for (int k = 0; k < BKF; ++k) {
            float4 a = *(const float4*)&As[k][m0];
            float4 b = *(const float4*)&Bs[k][n0];
            acc[0][0] += a.x * b.x; acc[0][1] += a.x * b.y; acc[0][2] += a.x * b.z; acc[0][3] += a.x * b.w;
            acc[1][0] += a.y * b.x; acc[1][1] += a.y * b.y; acc[1][2] += a.y * b.z; acc[1][3] += a.y * b.w;
            acc[2][0] += a.z * b.x; acc[2][1] += a.z * b.y; acc[2][2] += a.z * b.z; acc[2][3] += a.z * b.w;
            acc[3][0] += a.w * b.x; acc[3][1] += a.w * b.y; acc[3][2] += a.w * b.z; acc[3][3] += a.w * b.w;
        }
        __syncthreads();
    }
    const int gmo = bm * BMF + m0, gno = bn * BNF + n0;
#pragma unroll
    for (int i = 0; i < 4; ++i)
#pragma unroll
        for (int j = 0; j < 4; ++j) {
            int n = gno + j;
            if (n < C_DIM) e[(size_t)(gmo + i) * C_DIM + n] = acc[i][j] + bias[n];
        }
}

// ---------------------------------------------------------------------------
// Tree-CRF: one block per batch row; LDS level ping-pong + alpha-diff.
// PACKED=1: edge potentials from contiguous packed[c] (coalesced).
// PACKED=0: from raw pairs (scattered; fallback only).
// ---------------------------------------------------------------------------
__device__ __forceinline__ float lse2(float a, float b) {
    float m = fmaxf(a, b);
    return m + __logf(1.f + __expf(fminf(a, b) - m));
}

template <int PACKED>
__global__ __launch_bounds__(256) void crf_kernel(
    const float* __restrict__ pairs,    // raw (C,C,2,2), used if !PACKED
    const float4* __restrict__ packed,  // packed[c], used if PACKED
    float* __restrict__ eo)             // (B,C): e in, probability out
{
    __shared__ float se[C_DIM];       // scalar emission e
    __shared__ float da[1023];        // alpha[1]-alpha[0] for internal nodes
    __shared__ float P0[2048];        // level ping-pong (pairs of labels)
    __shared__ float P1[2048];

    const int row = blockIdx.x;
    const int tid = threadIdx.x;
    float* erow = eo + (size_t)row * C_DIM;

    for (int c = tid; c < C_DIM; c += 256)
        se[c] = erow[c];
    __syncthreads();

    // ---- Up-sweep: levels l = 10..1, one thread per parent ----
    float* cur = P0;   // child-level alpha (both labels)
    float* nxt = P1;
    for (int l = DEPTH - 1; l >= 1; --l) {
        const int np  = 1 << (l - 1);
        const int pg0 = np - 1;
        const bool leaf = (l == DEPTH - 1);
        for (int i = tid; i < np; i += 256) {
            const int p = pg0 + i;
            float a0 = 0.f, a1 = 0.f;
#pragma unroll
            for (int s = 0; s < 2; ++s) {
                const int c  = 2 * p + 1 + s;
                const int jc = 2 * i + s;
                float ca0 = 0.f, ca1 = 0.f;
                if (!leaf) { ca0 = cur[jc * 2]; ca1 = cur[jc * 2 + 1]; }
                const float l0 = -se[c] + ca0;
                const float l1 =  se[c] + ca1;
                const float4 pe = PACKED ? packed[c]
                    : *(const float4*)(pairs + ((size_t)p * C_DIM + c) * 4);
                a0 += lse2(pe.x + l0, pe.y + l1);
                a1 += lse2(pe.z + l0, pe.w + l1);
            }
            nxt[i * 2]     = a0;
            nxt[i * 2 + 1] = a1;
            da[p] = a1 - a0;
        }
        __syncthreads();
        float* t = cur; cur = nxt; nxt = t;
    }

    // ---- Root output ----
    if (tid == 0) {
        const float d = 2.f * se[0] + da[0];
        erow[0] = 1.f / (1.f + __expf(-d));
    }

    // ---- Down-sweep: levels l = 1..10, one thread per child; emit output ----
    float* bcur = P0;
    float* bnxt = P1;
    for (int l = 1; l <= DEPTH - 1; ++l) {
        const int nc  = 1 << l;
        const int cg0 = nc - 1;
        const bool top = (l == 1);
        for (int j = tid; j < nc; j += 256) {
            const int c  = cg0 + j;
            const int p  = (c - 1) >> 1;
            const int ip = j >> 1;
            float b0 = 0.f, b1 = 0.f;
            if (!top) { b0 = bcur[ip * 2]; b1 = bcur[ip * 2 + 1]; }
            const float lp0 = -se[p] + b0;
            const float lp1 =  se[p] + b1;
            const float4 pe = PACKED ? packed[c]
                : *(const float4*)(pairs + ((size_t)p * C_DIM + c) * 4);
            const float bc0 = lse2(lp0 + pe.x, lp1 + pe.z);
            const float bc1 = lse2(lp0 + pe.y, lp1 + pe.w);
            bnxt[j * 2]     = bc0;
            bnxt[j * 2 + 1] = bc1;
            float d = 2.f * se[c] + (bc1 - bc0);
            if (c < 1023) d += da[c];
            erow[c] = 1.f / (1.f + __expf(-d));
        }
        __syncthreads();
        float* t = bcur; bcur = bnxt; bnxt = t;
    }
}

// ---------------------------------------------------------------------------
extern "C" void kernel_launch(void* const* d_in, const int* in_sizes, int n_in,
                              void* d_out, int out_size, void* d_ws, size_t ws_size,
                              hipStream_t stream) {
    const float* x     = (const float*)d_in[0];
    const float* w     = (const float*)d_in[1];
    const float* bias  = (const float*)d_in[2];
    const float* pairs = (const float*)d_in[3];
    float* out = (float*)d_out;

    const size_t cvt_need  = ((size_t)2 * XTOT + (size_t)2 * WTOT) * 2;  // 24 MiB
    const size_t pack_need = (size_t)C_PAD * 16;                         // 32 KiB

    unsigned short* xhi = (unsigned short*)d_ws;
    unsigned short* xlo = xhi + (size_t)XTOT;
    unsigned short* whi = xlo + (size_t)XTOT;
    unsigned short* wlo = whi + (size_t)WTOT;
    float4* packed = (float4*)(wlo + (size_t)WTOT);

    const bool can_mfma = (ws_size >= cvt_need);
    const bool can_pack = (ws_size >= cvt_need + pack_need);

    if (can_mfma) {
        cvt_kernel<<<(XTOT + WTOT) / (256 * 4), 256, 0, stream>>>(x, w, xhi, xlo, whi, wlo);
        if (can_pack)
            pack_kernel<<<C_PAD / 256, 256, 0, stream>>>(pairs, packed);
        dim3 ggrid(C_PAD / 128, B_DIM / 128);
        gemm_mfma_kernel<<<ggrid, 256, 0, stream>>>(xhi, xlo, whi, wlo, bias, out);
    } else {
        dim3 ggrid((C_DIM + BNF - 1) / BNF, B_DIM / BMF);
        gemm_f32_kernel<<<ggrid, 256, 0, stream>>>(x, w, bias, out);
    }

    if (can_pack)
        crf_kernel<1><<<B_DIM, 256, 0, stream>>>(nullptr, packed, out);
    else
        crf_kernel<0><<<B_DIM, 256, 0, stream>>>(pairs, nullptr, out);
}

// Round 5
// 140.066 us; speedup vs baseline: 1.1383x; 1.0208x over previous
//
#include <hip/hip_runtime.h>
#include <math.h>

// Problem dims (fixed by the reference)
#define B_DIM 4096
#define F_DIM 1024
#define C_DIM 2047
#define C_PAD 2048
#define DEPTH 11

#define LOG2E 1.4426950408889634f

typedef __attribute__((ext_vector_type(8))) short bf16x8;
typedef __attribute__((ext_vector_type(4))) float f32x4;

#define AS1(p) ((const __attribute__((address_space(1))) void*)(p))
#define AS3(p) ((__attribute__((address_space(3))) void*)(p))

// ---------------------------------------------------------------------------
// bf16 split helpers (RNE)
// ---------------------------------------------------------------------------
__device__ __forceinline__ unsigned short f2bf(float f) {
    unsigned int u = __float_as_uint(f);
    unsigned int r = (u + 0x7fffu + ((u >> 16) & 1u)) >> 16;
    return (unsigned short)r;
}
__device__ __forceinline__ float bf2f(unsigned short h) {
    return __uint_as_float(((unsigned int)h) << 16);
}

// ---------------------------------------------------------------------------
// Fused convert: x (B,F) -> xhi/xlo ; w (C,F) -> whi/wlo (padded to C_PAD rows)
// ---------------------------------------------------------------------------
#define XTOT (B_DIM * F_DIM)          // 4194304
#define WTOT (C_PAD * F_DIM)          // 2097152

__global__ __launch_bounds__(256) void cvt_kernel(
    const float* __restrict__ x, const float* __restrict__ w,
    unsigned short* __restrict__ xhi, unsigned short* __restrict__ xlo,
    unsigned short* __restrict__ whi, unsigned short* __restrict__ wlo)
{
    const int i = (blockIdx.x * 256 + threadIdx.x) * 4;
    if (i < XTOT) {
        float4 v = *(const float4*)(x + i);
        ushort4 h, l;
        h.x = f2bf(v.x); l.x = f2bf(v.x - bf2f(h.x));
        h.y = f2bf(v.y); l.y = f2bf(v.y - bf2f(h.y));
        h.z = f2bf(v.z); l.z = f2bf(v.z - bf2f(h.z));
        h.w = f2bf(v.w); l.w = f2bf(v.w - bf2f(h.w));
        *(ushort4*)(xhi + i) = h;
        *(ushort4*)(xlo + i) = l;
    } else {
        const int j = i - XTOT;                    // < WTOT
        const int row = j >> 10;                   // F = 1024
        ushort4 h = {0, 0, 0, 0}, l = {0, 0, 0, 0};
        if (row < C_DIM) {
            float4 v = *(const float4*)(w + j);
            h.x = f2bf(v.x); l.x = f2bf(v.x - bf2f(h.x));
            h.y = f2bf(v.y); l.y = f2bf(v.y - bf2f(h.y));
            h.z = f2bf(v.z); l.z = f2bf(v.z - bf2f(h.z));
            h.w = f2bf(v.w); l.w = f2bf(v.w - bf2f(h.w));
        }
        *(ushort4*)(whi + j) = h;
        *(ushort4*)(wlo + j) = l;
    }
}

// ---------------------------------------------------------------------------
// Pack the 2046 tree-edge potentials contiguously, PRE-SCALED by log2(e):
//   packed[c] = pairs[(c-1)/2][c] * LOG2E  (float4 [y_par][y_child]), c in 1..2046
// ---------------------------------------------------------------------------
__global__ __launch_bounds__(256) void pack_kernel(
    const float* __restrict__ pairs, float4* __restrict__ packed)
{
    const int c = blockIdx.x * 256 + threadIdx.x;
    if (c >= 1 && c < C_DIM) {
        const int p = (c - 1) >> 1;
        float4 v = *(const float4*)(pairs + ((size_t)p * C_DIM + c) * 4);
        v.x *= LOG2E; v.y *= LOG2E; v.z *= LOG2E; v.w *= LOG2E;
        packed[c] = v;
    }
}

// ---------------------------------------------------------------------------
// MFMA GEMM: e = x @ W^T + bias over 3 split-bf16 segments (effective K=3072)
// 128x128 tile, BK=32, 256 threads (4 waves, 2x2), 16x16x32 bf16 MFMA.
// global_load_lds width-16 staging; conflict-free chunk swizzle s(row)=(row>>1)&3.
// ---------------------------------------------------------------------------
__global__ __launch_bounds__(256) void gemm_mfma_kernel(
    const unsigned short* __restrict__ xhi, const unsigned short* __restrict__ xlo,
    const unsigned short* __restrict__ whi, const unsigned short* __restrict__ wlo,
    const float* __restrict__ bias, float* __restrict__ e)
{
    __shared__ unsigned short smemA[128 * 32];  // [row][k] 64B rows
    __shared__ unsigned short smemB[128 * 32];

    const int tid  = threadIdx.x;
    const int lane = tid & 63;
    const int wave = tid >> 6;
    const int wr = wave >> 1, wc = wave & 1;
    const int bn = blockIdx.x, bm = blockIdx.y;

    f32x4 acc[4][4] = {};
    const int r0 = tid >> 2,         c0 = tid & 3;
    const int r1 = (tid + 256) >> 2, c1 = tid & 3;
    const int sc0 = ((c0 ^ ((r0 >> 1) & 3)) << 3);
    const int sc1 = ((c1 ^ ((r1 >> 1) & 3)) << 3);

    const size_t arow0 = (size_t)(bm * 128 + r0) * F_DIM;
    const size_t arow1 = (size_t)(bm * 128 + r1) * F_DIM;
    const size_t brow0 = (size_t)(bn * 128 + r0) * F_DIM;
    const size_t brow1 = (size_t)(bn * 128 + r1) * F_DIM;

    unsigned short* ldsA0 = smemA + wave * 512;
    unsigned short* ldsA1 = smemA + 2048 + wave * 512;
    unsigned short* ldsB0 = smemB + wave * 512;
    unsigned short* ldsB1 = smemB + 2048 + wave * 512;

    const int fra = wr * 64 + (lane & 15);
    const int frb = wc * 64 + (lane & 15);
    const int kc  = lane >> 4;

    for (int seg = 0; seg < 3; ++seg) {
        const unsigned short* Ap = (seg == 2) ? xlo : xhi;
        const unsigned short* Bp = (seg == 1) ? wlo : whi;
        for (int k0 = 0; k0 < F_DIM; k0 += 32) {
            __builtin_amdgcn_global_load_lds(AS1(Ap + arow0 + k0 + sc0), AS3(ldsA0), 16, 0, 0);
            __builtin_amdgcn_global_load_lds(AS1(Ap + arow1 + k0 + sc1), AS3(ldsA1), 16, 0, 0);
            __builtin_amdgcn_global_load_lds(AS1(Bp + brow0 + k0 + sc0), AS3(ldsB0), 16, 0, 0);
            __builtin_amdgcn_global_load_lds(AS1(Bp + brow1 + k0 + sc1), AS3(ldsB1), 16, 0, 0);
            __syncthreads();

            bf16x8 af[4], bfr[4];
#pragma unroll
            for (int m = 0; m < 4; ++m) {
                const int row = fra + m * 16;
                af[m] = *(const bf16x8*)(smemA + row * 32 + ((kc ^ ((row >> 1) & 3)) << 3));
            }
#pragma unroll
            for (int n = 0; n < 4; ++n) {
                const int row = frb + n * 16;
                bfr[n] = *(const bf16x8*)(smemB + row * 32 + ((kc ^ ((row >> 1) & 3)) << 3));
            }
#pragma unroll
            for (int m = 0; m < 4; ++m)
#pragma unroll
                for (int n = 0; n < 4; ++n)
                    acc[m][n] = __builtin_amdgcn_mfma_f32_16x16x32_bf16(
                        af[m], bfr[n], acc[m][n], 0, 0, 0);
            __syncthreads();
        }
    }

    const int colbase = bn * 128 + wc * 64 + (lane & 15);
    const int rowbase = bm * 128 + wr * 64 + ((lane >> 4) << 2);
#pragma unroll
    for (int m = 0; m < 4; ++m)
#pragma unroll
        for (int n = 0; n < 4; ++n) {
            const int gc = colbase + n * 16;
            if (gc < C_DIM) {
                const float bv = bias[gc];
#pragma unroll
                for (int r = 0; r < 4; ++r)
                    e[(size_t)(rowbase + m * 16 + r) * C_DIM + gc] = acc[m][n][r] + bv;
            }
        }
}

// ---------------------------------------------------------------------------
// Fallback f32 GEMM (only if ws too small for the bf16 split buffers)
// ---------------------------------------------------------------------------
#define BMF 64
#define BNF 64
#define BKF 16

__global__ __launch_bounds__(256) void gemm_f32_kernel(
    const float* __restrict__ x, const float* __restrict__ w,
    const float* __restrict__ bias, float* __restrict__ e)
{
    __shared__ float As[BKF][BMF];
    __shared__ float Bs[BKF][BNF];
    const int bn = blockIdx.x, bm = blockIdx.y;
    const int tid = threadIdx.x;
    const int tx = tid & 15, ty = tid >> 4;
    const int m0 = ty * 4, n0 = tx * 4;
    const int lrow = tid >> 2, lc4 = (tid & 3) * 4;
    const int gm = bm * BMF + lrow;
    const int gn = bn * BNF + lrow;
    const bool wvalid = (gn < C_DIM);
    const float* xp = x + (size_t)gm * F_DIM + lc4;
    const float* wp = wvalid ? (w + (size_t)gn * F_DIM + lc4) : w;
    float acc[4][4] = {};
    for (int k0 = 0; k0 < F_DIM; k0 += BKF) {
        float4 av = *(const float4*)(xp + k0);
        float4 bv = make_float4(0.f, 0.f, 0.f, 0.f);
        if (wvalid) bv = *(const float4*)(wp + k0);
        As[lc4 + 0][lrow] = av.x; As[lc4 + 1][lrow] = av.y;
        As[lc4 + 2][lrow] = av.z; As[lc4 + 3][lrow] = av.w;
        Bs[lc4 + 0][lrow] = bv.x; Bs[lc4 + 1][lrow] = bv.y;
        Bs[lc4 + 2][lrow] = bv.z; Bs[lc4 + 3][lrow] = bv.w;
        __syncthreads();
#pragma unroll
        for (int k = 0; k < BKF; ++k) {
            float4 a = *(const float4*)&As[k][m0];
            float4 b = *(const float4*)&Bs[k][n0];
            acc[0][0] += a.x * b.x; acc[0][1] += a.x * b.y; acc[0][2] += a.x * b.z; acc[0][3] += a.x * b.w;
            acc[1][0] += a.y * b.x; acc[1][1] += a.y * b.y; acc[1][2] += a.y * b.z; acc[1][3] += a.y * b.w;
            acc[2][0] += a.z * b.x; acc[2][1] += a.z * b.y; acc[2][2] += a.z * b.z; acc[2][3] += a.z * b.w;
            acc[3][0] += a.w * b.x; acc[3][1] += a.w * b.y; acc[3][2] += a.w * b.z; acc[3][3] += a.w * b.w;
        }
        __syncthreads();
    }
    const int gmo = bm * BMF + m0, gno = bn * BNF + n0;
#pragma unroll
    for (int i = 0; i < 4; ++i)
#pragma unroll
        for (int j = 0; j < 4; ++j) {
            int n = gno + j;
            if (n < C_DIM) e[(size_t)(gmo + i) * C_DIM + n] = acc[i][j] + bias[n];
        }
}

// ---------------------------------------------------------------------------
// Tree-CRF: ONE WAVE (64-thread block) per batch row, all in log2 domain.
// LDS 20.5 KB/row -> 8 blocks/CU; single-wave barriers are ~free.
//   se2[c] = e[c]*log2e; potentials pre-scaled by log2e (pack_kernel).
//   lse2_2(a,b) = max + log2(1 + 2^(min-max));  out = 1/(1+2^(-d)).
// ---------------------------------------------------------------------------
__device__ __forceinline__ float lse2_2(float a, float b) {
    float m = fmaxf(a, b);
    return m + __log2f(1.f + exp2f(fminf(a, b) - m));
}

template <int PACKED>
__global__ __launch_bounds__(64) void crf_kernel(
    const float* __restrict__ pairs,    // raw (C,C,2,2), used if !PACKED
    const float4* __restrict__ packed,  // packed[c]*log2e, used if PACKED
    float* __restrict__ eo)             // (B,C): e in, probability out
{
    __shared__ float se[C_DIM];       // emission * log2e
    __shared__ float da[1023];        // alpha[1]-alpha[0], internal nodes
    __shared__ float P0[1024];        // level ping-pong (<=512 nodes * 2)
    __shared__ float P1[1024];

    const int row  = blockIdx.x;
    const int lane = threadIdx.x;
    float* erow = eo + (size_t)row * C_DIM;

    for (int c = lane; c < C_DIM; c += 64)
        se[c] = erow[c] * LOG2E;
    __syncthreads();

    // ---- Up-sweep: levels l = 10..1, one lane per parent ----
    float* cur = P0;
    float* nxt = P1;
    for (int l = DEPTH - 1; l >= 1; --l) {
        const int np  = 1 << (l - 1);
        const int pg0 = np - 1;
        const bool leaf = (l == DEPTH - 1);
        for (int i = lane; i < np; i += 64) {
            const int p = pg0 + i;
            float a0 = 0.f, a1 = 0.f;
#pragma unroll
            for (int s = 0; s < 2; ++s) {
                const int c  = 2 * p + 1 + s;
                const int jc = 2 * i + s;
                float ca0 = 0.f, ca1 = 0.f;
                if (!leaf) { ca0 = cur[jc * 2]; ca1 = cur[jc * 2 + 1]; }
                const float l0 = -se[c] + ca0;
                const float l1 =  se[c] + ca1;
                float4 pe;
                if (PACKED) pe = packed[c];
                else {
                    pe = *(const float4*)(pairs + ((size_t)p * C_DIM + c) * 4);
                    pe.x *= LOG2E; pe.y *= LOG2E; pe.z *= LOG2E; pe.w *= LOG2E;
                }
                a0 += lse2_2(pe.x + l0, pe.y + l1);
                a1 += lse2_2(pe.z + l0, pe.w + l1);
            }
            nxt[i * 2]     = a0;
            nxt[i * 2 + 1] = a1;
            da[p] = a1 - a0;
        }
        __syncthreads();
        float* t = cur; cur = nxt; nxt = t;
    }

    // ---- Root output ----
    if (lane == 0) {
        const float d = 2.f * se[0] + da[0];
        erow[0] = __builtin_amdgcn_rcpf(1.f + exp2f(-d));
    }

    // ---- Down-sweep: levels l = 1..10, one lane per child; emit output ----
    float* bcur = P0;
    float* bnxt = P1;
    for (int l = 1; l <= DEPTH - 1; ++l) {
        const int nc  = 1 << l;
        const int cg0 = nc - 1;
        const bool top  = (l == 1);
        const bool last = (l == DEPTH - 1);
        for (int j = lane; j < nc; j += 64) {
            const int c  = cg0 + j;
            const int p  = (c - 1) >> 1;
            const int ip = j >> 1;
            float b0 = 0.f, b1 = 0.f;
            if (!top) { b0 = bcur[ip * 2]; b1 = bcur[ip * 2 + 1]; }
            const float lp0 = -se[p] + b0;
            const float lp1 =  se[p] + b1;
            float4 pe;
            if (PACKED) pe = packed[c];
            else {
                pe = *(const float4*)(pairs + ((size_t)p * C_DIM + c) * 4);
                pe.x *= LOG2E; pe.y *= LOG2E; pe.z *= LOG2E; pe.w *= LOG2E;
            }
            const float bc0 = lse2_2(lp0 + pe.x, lp1 + pe.z);
            const float bc1 = lse2_2(lp0 + pe.y, lp1 + pe.w);
            if (!last) {                      // level-10 betas are never consumed
                bnxt[j * 2]     = bc0;
                bnxt[j * 2 + 1] = bc1;
            }
            float d = 2.f * se[c] + (bc1 - bc0);
            if (c < 1023) d += da[c];
            erow[c] = __builtin_amdgcn_rcpf(1.f + exp2f(-d));
        }
        __syncthreads();
        float* t = bcur; bcur = bnxt; bnxt = t;
    }
}

// ---------------------------------------------------------------------------
extern "C" void kernel_launch(void* const* d_in, const int* in_sizes, int n_in,
                              void* d_out, int out_size, void* d_ws, size_t ws_size,
                              hipStream_t stream) {
    const float* x     = (const float*)d_in[0];
    const float* w     = (const float*)d_in[1];
    const float* bias  = (const float*)d_in[2];
    const float* pairs = (const float*)d_in[3];
    float* out = (float*)d_out;

    const size_t cvt_need  = ((size_t)2 * XTOT + (size_t)2 * WTOT) * 2;  // 24 MiB
    const size_t pack_need = (size_t)C_PAD * 16;                         // 32 KiB

    unsigned short* xhi = (unsigned short*)d_ws;
    unsigned short* xlo = xhi + (size_t)XTOT;
    unsigned short* whi = xlo + (size_t)XTOT;
    unsigned short* wlo = whi + (size_t)WTOT;
    float4* packed = (float4*)(wlo + (size_t)WTOT);

    const bool can_mfma = (ws_size >= cvt_need);
    const bool can_pack = (ws_size >= cvt_need + pack_need);

    if (can_mfma) {
        cvt_kernel<<<(XTOT + WTOT) / (256 * 4), 256, 0, stream>>>(x, w, xhi, xlo, whi, wlo);
        if (can_pack)
            pack_kernel<<<C_PAD / 256, 256, 0, stream>>>(pairs, packed);
        dim3 ggrid(C_PAD / 128, B_DIM / 128);
        gemm_mfma_kernel<<<ggrid, 256, 0, stream>>>(xhi, xlo, whi, wlo, bias, out);
    } else {
        dim3 ggrid((C_DIM + BNF - 1) / BNF, B_DIM / BMF);
        gemm_f32_kernel<<<ggrid, 256, 0, stream>>>(x, w, bias, out);
    }

    if (can_pack)
        crf_kernel<1><<<B_DIM, 64, 0, stream>>>(nullptr, packed, out);
    else
        crf_kernel<0><<<B_DIM, 64, 0, stream>>>(pairs, nullptr, out);
}

// Round 6
// 82.349 us; speedup vs baseline: 1.9362x; 1.7009x over previous
//
#include <hip/hip_runtime.h>
#include <math.h>

// Problem dims (fixed by the reference)
#define B_DIM 4096
#define F_DIM 1024
#define C_DIM 2047
#define C_PAD 2048
#define DEPTH 11

#define LOG2E 1.4426950408889634f

typedef __attribute__((ext_vector_type(8))) short bf16x8;
typedef __attribute__((ext_vector_type(4))) float f32x4;

#define AS1(p) ((const __attribute__((address_space(1))) void*)(p))
#define AS3(p) ((__attribute__((address_space(3))) void*)(p))

// ---------------------------------------------------------------------------
// bf16 helpers (RNE)
// ---------------------------------------------------------------------------
__device__ __forceinline__ unsigned short f2bf(float f) {
    unsigned int u = __float_as_uint(f);
    unsigned int r = (u + 0x7fffu + ((u >> 16) & 1u)) >> 16;
    return (unsigned short)r;
}

// ---------------------------------------------------------------------------
// Convert: x (B,F) f32 -> xb bf16 ; w (C,F) f32 -> wb bf16 (padded to C_PAD)
// ---------------------------------------------------------------------------
#define XTOT (B_DIM * F_DIM)          // 4194304
#define WTOT (C_PAD * F_DIM)          // 2097152

__global__ __launch_bounds__(256) void cvt_kernel(
    const float* __restrict__ x, const float* __restrict__ w,
    unsigned short* __restrict__ xb, unsigned short* __restrict__ wb)
{
    const int i = (blockIdx.x * 256 + threadIdx.x) * 4;
    if (i < XTOT) {
        float4 v = *(const float4*)(x + i);
        ushort4 h;
        h.x = f2bf(v.x); h.y = f2bf(v.y); h.z = f2bf(v.z); h.w = f2bf(v.w);
        *(ushort4*)(xb + i) = h;
    } else {
        const int j = i - XTOT;                    // < WTOT
        const int row = j >> 10;                   // F = 1024
        ushort4 h = {0, 0, 0, 0};
        if (row < C_DIM) {
            float4 v = *(const float4*)(w + j);
            h.x = f2bf(v.x); h.y = f2bf(v.y); h.z = f2bf(v.z); h.w = f2bf(v.w);
        }
        *(ushort4*)(wb + j) = h;
    }
}

// ---------------------------------------------------------------------------
// Pack the 2046 tree-edge potentials contiguously, PRE-SCALED by log2(e):
//   packed[c] = pairs[(c-1)/2][c] * LOG2E, c in 1..2046
// ---------------------------------------------------------------------------
__global__ __launch_bounds__(256) void pack_kernel(
    const float* __restrict__ pairs, float4* __restrict__ packed)
{
    const int c = blockIdx.x * 256 + threadIdx.x;
    if (c >= 1 && c < C_DIM) {
        const int p = (c - 1) >> 1;
        float4 v = *(const float4*)(pairs + ((size_t)p * C_DIM + c) * 4);
        v.x *= LOG2E; v.y *= LOG2E; v.z *= LOG2E; v.w *= LOG2E;
        packed[c] = v;
    }
}

// ---------------------------------------------------------------------------
// MFMA GEMM: e = x @ W^T + bias, single bf16 product, K=1024.
// 128x128 tile, BK=32, 256 threads (4 waves 2x2), 16x16x32 bf16 MFMA,
// global_load_lds width-16 staging; conflict-free chunk swizzle s(row)=(row>>1)&3.
// ---------------------------------------------------------------------------
__global__ __launch_bounds__(256) void gemm_bf16_kernel(
    const unsigned short* __restrict__ xb, const unsigned short* __restrict__ wb,
    const float* __restrict__ bias, float* __restrict__ e)
{
    __shared__ unsigned short smemA[128 * 32];  // [row][k] 64B rows
    __shared__ unsigned short smemB[128 * 32];

    const int tid  = threadIdx.x;
    const int lane = tid & 63;
    const int wave = tid >> 6;
    const int wr = wave >> 1, wc = wave & 1;
    const int bn = blockIdx.x, bm = blockIdx.y;

    f32x4 acc[4][4] = {};
    const int r0 = tid >> 2,         c0 = tid & 3;
    const int r1 = (tid + 256) >> 2, c1 = tid & 3;
    const int sc0 = ((c0 ^ ((r0 >> 1) & 3)) << 3);
    const int sc1 = ((c1 ^ ((r1 >> 1) & 3)) << 3);

    const size_t arow0 = (size_t)(bm * 128 + r0) * F_DIM;
    const size_t arow1 = (size_t)(bm * 128 + r1) * F_DIM;
    const size_t brow0 = (size_t)(bn * 128 + r0) * F_DIM;
    const size_t brow1 = (size_t)(bn * 128 + r1) * F_DIM;

    unsigned short* ldsA0 = smemA + wave * 512;
    unsigned short* ldsA1 = smemA + 2048 + wave * 512;
    unsigned short* ldsB0 = smemB + wave * 512;
    unsigned short* ldsB1 = smemB + 2048 + wave * 512;

    const int fra = wr * 64 + (lane & 15);
    const int frb = wc * 64 + (lane & 15);
    const int kc  = lane >> 4;

    for (int k0 = 0; k0 < F_DIM; k0 += 32) {
        __builtin_amdgcn_global_load_lds(AS1(xb + arow0 + k0 + sc0), AS3(ldsA0), 16, 0, 0);
        __builtin_amdgcn_global_load_lds(AS1(xb + arow1 + k0 + sc1), AS3(ldsA1), 16, 0, 0);
        __builtin_amdgcn_global_load_lds(AS1(wb + brow0 + k0 + sc0), AS3(ldsB0), 16, 0, 0);
        __builtin_amdgcn_global_load_lds(AS1(wb + brow1 + k0 + sc1), AS3(ldsB1), 16, 0, 0);
        __syncthreads();

        bf16x8 af[4], bfr[4];
#pragma unroll
        for (int m = 0; m < 4; ++m) {
            const int row = fra + m * 16;
            af[m] = *(const bf16x8*)(smemA + row * 32 + ((kc ^ ((row >> 1) & 3)) << 3));
        }
#pragma unroll
        for (int n = 0; n < 4; ++n) {
            const int row = frb + n * 16;
            bfr[n] = *(const bf16x8*)(smemB + row * 32 + ((kc ^ ((row >> 1) & 3)) << 3));
        }
#pragma unroll
        for (int m = 0; m < 4; ++m)
#pragma unroll
            for (int n = 0; n < 4; ++n)
                acc[m][n] = __builtin_amdgcn_mfma_f32_16x16x32_bf16(
                    af[m], bfr[n], acc[m][n], 0, 0, 0);
        __syncthreads();
    }

    const int colbase = bn * 128 + wc * 64 + (lane & 15);
    const int rowbase = bm * 128 + wr * 64 + ((lane >> 4) << 2);
#pragma unroll
    for (int m = 0; m < 4; ++m)
#pragma unroll
        for (int n = 0; n < 4; ++n) {
            const int gc = colbase + n * 16;
            if (gc < C_DIM) {
                const float bv = bias[gc];
#pragma unroll
                for (int r = 0; r < 4; ++r)
                    e[(size_t)(rowbase + m * 16 + r) * C_DIM + gc] = acc[m][n][r] + bv;
            }
        }
}

// ---------------------------------------------------------------------------
// Fallback f32 GEMM (only if ws too small)
// ---------------------------------------------------------------------------
#define BMF 64
#define BNF 64
#define BKF 16

__global__ __launch_bounds__(256) void gemm_f32_kernel(
    const float* __restrict__ x, const float* __restrict__ w,
    const float* __restrict__ bias, float* __restrict__ e)
{
    __shared__ float As[BKF][BMF];
    __shared__ float Bs[BKF][BNF];
    const int bn = blockIdx.x, bm = blockIdx.y;
    const int tid = threadIdx.x;
    const int tx = tid & 15, ty = tid >> 4;
    const int m0 = ty * 4, n0 = tx * 4;
    const int lrow = tid >> 2, lc4 = (tid & 3) * 4;
    const int gm = bm * BMF + lrow;
    const int gn = bn * BNF + lrow;
    const bool wvalid = (gn < C_DIM);
    const float* xp = x + (size_t)gm * F_DIM + lc4;
    const float* wp = wvalid ? (w + (size_t)gn * F_DIM + lc4) : w;
    float acc[4][4] = {};
    for (int k0 = 0; k0 < F_DIM; k0 += BKF) {
        float4 av = *(const float4*)(xp + k0);
        float4 bv = make_float4(0.f, 0.f, 0.f, 0.f);
        if (wvalid) bv = *(const float4*)(wp + k0);
        As[lc4 + 0][lrow] = av.x; As[lc4 + 1][lrow] = av.y;
        As[lc4 + 2][lrow] = av.z; As[lc4 + 3][lrow] = av.w;
        Bs[lc4 + 0][lrow] = bv.x; Bs[lc4 + 1][lrow] = bv.y;
        Bs[lc4 + 2][lrow] = bv.z; Bs[lc4 + 3][lrow] = bv.w;
        __syncthreads();
#pragma unroll
        for (int k = 0; k < BKF; ++k) {
            float4 a = *(const float4*)&As[k][m0];
            float4 b = *(const float4*)&Bs[k][n0];
            acc[0][0] += a.x * b.x; acc[0][1] += a.x * b.y; acc[0][2] += a.x * b.z; acc[0][3] += a.x * b.w;
            acc[1][0] += a.y * b.x; acc[1][1] += a.y * b.y; acc[1][2] += a.y * b.z; acc[1][3] += a.y * b.w;
            acc[2][0] += a.z * b.x; acc[2][1] += a.z * b.y; acc[2][2] += a.z * b.z; acc[2][3] += a.z * b.w;
            acc[3][0] += a.w * b.x; acc[3][1] += a.w * b.y; acc[3][2] += a.w * b.z; acc[3][3] += a.w * b.w;
        }
        __syncthreads();
    }
    const int gmo = bm * BMF + m0, gno = bn * BNF + n0;
#pragma unroll
    for (int i = 0; i < 4; ++i)
#pragma unroll
        for (int j = 0; j < 4; ++j) {
            int n = gno + j;
            if (n < C_DIM) e[(size_t)(gmo + i) * C_DIM + n] = acc[i][j] + bias[n];
        }
}

// ---------------------------------------------------------------------------
// Tree-CRF, barrier-free: ONE WAVE per batch row, ZERO LDS.
// Lane L owns the subtree rooted at level-6 node (63+L): levels 6..10 fully
// in-lane (unrolled, static register indexing); levels 5..0 via __shfl.
// All math in log2 domain (packed pre-scaled, emissions scaled at load).
// ---------------------------------------------------------------------------
__device__ __forceinline__ float lse2_2(float a, float b) {
    float m = fmaxf(a, b);
    return m + __log2f(1.f + exp2f(fminf(a, b) - m));
}
__device__ __forceinline__ float sigmoid2(float d) {
    return __builtin_amdgcn_rcpf(1.f + exp2f(-d));
}

__global__ __launch_bounds__(64) void crf_wave_kernel(
    const float4* __restrict__ packed,  // packed[c] * log2e
    float* __restrict__ eo)             // (B,C): e in, probability out
{
    const int row  = blockIdx.x;
    const int lane = threadIdx.x;
    float* erow = eo + (size_t)row * C_DIM;

    const int L16 = 16 * lane, L8 = 8 * lane, L4 = 4 * lane, L2 = 2 * lane;

    // ================= subtree UP (levels 10 -> 6), per-lane =================
    float a3v[8][2], da3[8];            // alphas/diffs of level-9 nodes
#pragma unroll
    for (int t = 0; t < 8; ++t) {
        const int c0 = 1023 + L16 + 2 * t, c1 = c0 + 1;   // leaf children (lvl 10)
        float e0 = erow[c0] * LOG2E, e1 = erow[c1] * LOG2E;
        float4 p0 = packed[c0], p1 = packed[c1];
        float a0 = lse2_2(p0.x - e0, p0.y + e0) + lse2_2(p1.x - e1, p1.y + e1);
        float a1 = lse2_2(p0.z - e0, p0.w + e0) + lse2_2(p1.z - e1, p1.w + e1);
        a3v[t][0] = a0; a3v[t][1] = a1; da3[t] = a1 - a0;
    }
    float a2v[4][2], da2[4];            // level-8
#pragma unroll
    for (int t = 0; t < 4; ++t) {
        const int c0 = 511 + L8 + 2 * t, c1 = c0 + 1;     // children (lvl 9)
        float e0 = erow[c0] * LOG2E, e1 = erow[c1] * LOG2E;
        float4 p0 = packed[c0], p1 = packed[c1];
        float l00 = -e0 + a3v[2*t][0],   l01 = e0 + a3v[2*t][1];
        float l10 = -e1 + a3v[2*t+1][0], l11 = e1 + a3v[2*t+1][1];
        float a0 = lse2_2(p0.x + l00, p0.y + l01) + lse2_2(p1.x + l10, p1.y + l11);
        float a1 = lse2_2(p0.z + l00, p0.w + l01) + lse2_2(p1.z + l10, p1.w + l11);
        a2v[t][0] = a0; a2v[t][1] = a1; da2[t] = a1 - a0;
    }
    float a1v[2][2], da1[2];            // level-7
#pragma unroll
    for (int t = 0; t < 2; ++t) {
        const int c0 = 255 + L4 + 2 * t, c1 = c0 + 1;     // children (lvl 8)
        float e0 = erow[c0] * LOG2E, e1 = erow[c1] * LOG2E;
        float4 p0 = packed[c0], p1 = packed[c1];
        float l00 = -e0 + a2v[2*t][0],   l01 = e0 + a2v[2*t][1];
        float l10 = -e1 + a2v[2*t+1][0], l11 = e1 + a2v[2*t+1][1];
        float a0 = lse2_2(p0.x + l00, p0.y + l01) + lse2_2(p1.x + l10, p1.y + l11);
        float a1 = lse2_2(p0.z + l00, p0.w + l01) + lse2_2(p1.z + l10, p1.w + l11);
        a1v[t][0] = a0; a1v[t][1] = a1; da1[t] = a1 - a0;
    }
    float sa0, sa1, da0;                // level-6 root of subtree
    {
        const int c0 = 127 + L2, c1 = c0 + 1;             // children (lvl 7)
        float e0 = erow[c0] * LOG2E, e1 = erow[c1] * LOG2E;
        float4 p0 = packed[c0], p1 = packed[c1];
        float l00 = -e0 + a1v[0][0], l01 = e0 + a1v[0][1];
        float l10 = -e1 + a1v[1][0], l11 = e1 + a1v[1][1];
        sa0 = lse2_2(p0.x + l00, p0.y + l01) + lse2_2(p1.x + l10, p1.y + l11);
        sa1 = lse2_2(p0.z + l00, p0.w + l01) + lse2_2(p1.z + l10, p1.w + l11);
        da0 = sa1 - sa0;
    }
    const float e6 = erow[63 + lane] * LOG2E;

    // ================= shuffle UP (levels 5 -> 0), no barriers ==============
    float e_self = e6;                  // emission of current child-level node
    float da_sh[6];
#pragma unroll
    for (int lvl = 5; lvl >= 0; --lvl) {
        const int lbase = (1 << (lvl + 1)) - 1;           // child level base
        const int j0 = (2 * lane) & 63, j1 = (2 * lane + 1) & 63;
        float c0a0 = __shfl(sa0, j0, 64), c0a1 = __shfl(sa1, j0, 64);
        float c1a0 = __shfl(sa0, j1, 64), c1a1 = __shfl(sa1, j1, 64);
        float ce0  = __shfl(e_self, j0, 64), ce1 = __shfl(e_self, j1, 64);
        float4 p0 = packed[lbase + L2];
        float4 p1 = packed[lbase + L2 + 1];
        float l00 = -ce0 + c0a0, l01 = ce0 + c0a1;
        float l10 = -ce1 + c1a0, l11 = ce1 + c1a1;
        float na0 = lse2_2(p0.x + l00, p0.y + l01) + lse2_2(p1.x + l10, p1.y + l11);
        float na1 = lse2_2(p0.z + l00, p0.w + l01) + lse2_2(p1.z + l10, p1.w + l11);
        sa0 = na0; sa1 = na1;
        da_sh[lvl] = na1 - na0;
        e_self = erow[(1 << lvl) - 1 + lane] * LOG2E;     // parent-level emission
    }

    // ================= shuffle DOWN (levels 0 -> 5) =========================
    float sb0 = 0.f, sb1 = 0.f;         // beta(root) = 0 (all lanes start 0)
#pragma unroll
    for (int lvl = 0; lvl <= 5; ++lvl) {
        const int np = 1 << lvl, pbase = np - 1;
        float e_par = erow[pbase + lane] * LOG2E;         // valid lane<np; reads pre-write
        const int jp = lane >> 1;
        float pb0 = __shfl(sb0, jp, 64), pb1 = __shfl(sb1, jp, 64);
        float pe  = __shfl(e_par, jp, 64);
        float4 pk = packed[2 * np - 1 + lane];            // child id >= 1
        float lp0 = -pe + pb0, lp1 = pe + pb1;
        float nb0 = lse2_2(lp0 + pk.x, lp1 + pk.z);
        float nb1 = lse2_2(lp0 + pk.y, lp1 + pk.w);
        if (lane < np)                                    // emit parent output
            erow[pbase + lane] = sigmoid2(2.f * e_par + da_sh[lvl] + (sb1 - sb0));
        sb0 = nb0; sb1 = nb1;                             // beta of level lvl+1
    }
    // now (sb0,sb1) = beta of level-6 node (63+lane), valid all 64 lanes

    // ================= subtree DOWN (levels 6 -> 10), per-lane ==============
    float b1v[2][2];                    // betas of level-7 nodes
    {
        float lp0 = -e6 + sb0, lp1 = e6 + sb1;
        const int c0 = 127 + L2;
        float4 p0 = packed[c0], p1 = packed[c0 + 1];
        b1v[0][0] = lse2_2(lp0 + p0.x, lp1 + p0.z);
        b1v[0][1] = lse2_2(lp0 + p0.y, lp1 + p0.w);
        b1v[1][0] = lse2_2(lp0 + p1.x, lp1 + p1.z);
        b1v[1][1] = lse2_2(lp0 + p1.y, lp1 + p1.w);
        erow[63 + lane] = sigmoid2(2.f * e6 + da0 + (sb1 - sb0));
    }
    float b2v[4][2];                    // betas of level-8 nodes
#pragma unroll
    for (int t = 0; t < 2; ++t) {
        const int n = 127 + L2 + t;
        float ep = erow[n] * LOG2E;
        float4 p0 = packed[255 + L4 + 2 * t], p1 = packed[255 + L4 + 2 * t + 1];
        float q0 = -ep + b1v[t][0], q1 = ep + b1v[t][1];
        b2v[2*t][0]   = lse2_2(q0 + p0.x, q1 + p0.z);
        b2v[2*t][1]   = lse2_2(q0 + p0.y, q1 + p0.w);
        b2v[2*t+1][0] = lse2_2(q0 + p1.x, q1 + p1.z);
        b2v[2*t+1][1] = lse2_2(q0 + p1.y, q1 + p1.w);
        erow[n] = sigmoid2(2.f * ep + da1[t] + (b1v[t][1] - b1v[t][0]));
    }
    float b3v[8][2];                    // betas of level-9 nodes
#pragma unroll
    for (int t = 0; t < 4; ++t) {
        const int n = 255 + L4 + t;
        float ep = erow[n] * LOG2E;
        float4 p0 = packed[511 + L8 + 2 * t], p1 = packed[511 + L8 + 2 * t + 1];
        float q0 = -ep + b2v[t][0], q1 = ep + b2v[t][1];
        b3v[2*t][0]   = lse2_2(q0 + p0.x, q1 + p0.z);
        b3v[2*t][1]   = lse2_2(q0 + p0.y, q1 + p0.w);
        b3v[2*t+1][0] = lse2_2(q0 + p1.x, q1 + p1.z);
        b3v[2*t+1][1] = lse2_2(q0 + p1.y, q1 + p1.w);
        erow[n] = sigmoid2(2.f * ep + da2[t] + (b2v[t][1] - b2v[t][0]));
    }
    float b4v[16][2];                   // betas of level-10 leaves
#pragma unroll
    for (int t = 0; t < 8; ++t) {
        const int n = 511 + L8 + t;
        float ep = erow[n] * LOG2E;
        float4 p0 = packed[1023 + L16 + 2 * t], p1 = packed[1023 + L16 + 2 * t + 1];
        float q0 = -ep + b3v[t][0], q1 = ep + b3v[t][1];
        b4v[2*t][0]   = lse2_2(q0 + p0.x, q1 + p0.z);
        b4v[2*t][1]   = lse2_2(q0 + p0.y, q1 + p0.w);
        b4v[2*t+1][0] = lse2_2(q0 + p1.x, q1 + p1.z);
        b4v[2*t+1][1] = lse2_2(q0 + p1.y, q1 + p1.w);
        erow[n] = sigmoid2(2.f * ep + da3[t] + (b3v[t][1] - b3v[t][0]));
    }
#pragma unroll
    for (int t = 0; t < 16; ++t) {      // leaf outputs (alpha = 0)
        const int n = 1023 + L16 + t;
        float ep = erow[n] * LOG2E;
        erow[n] = sigmoid2(2.f * ep + (b4v[t][1] - b4v[t][0]));
    }
}

// ---------------------------------------------------------------------------
// Fallback CRF (block-per-row, LDS) reading raw pairs — only if ws too small.
// ---------------------------------------------------------------------------
__global__ __launch_bounds__(64) void crf_fallback_kernel(
    const float* __restrict__ pairs, float* __restrict__ eo)
{
    __shared__ float se[C_DIM];
    __shared__ float da[1023];
    __shared__ float P0[1024];
    __shared__ float P1[1024];

    const int row  = blockIdx.x;
    const int lane = threadIdx.x;
    float* erow = eo + (size_t)row * C_DIM;

    for (int c = lane; c < C_DIM; c += 64) se[c] = erow[c] * LOG2E;
    __syncthreads();

    float* cur = P0; float* nxt = P1;
    for (int l = DEPTH - 1; l >= 1; --l) {
        const int np = 1 << (l - 1);
        const int pg0 = np - 1;
        const bool leaf = (l == DEPTH - 1);
        for (int i = lane; i < np; i += 64) {
            const int p = pg0 + i;
            float a0 = 0.f, a1 = 0.f;
#pragma unroll
            for (int s = 0; s < 2; ++s) {
                const int c = 2 * p + 1 + s;
                const int jc = 2 * i + s;
                float ca0 = 0.f, ca1 = 0.f;
                if (!leaf) { ca0 = cur[jc * 2]; ca1 = cur[jc * 2 + 1]; }
                const float l0 = -se[c] + ca0;
                const float l1 =  se[c] + ca1;
                float4 pe = *(const float4*)(pairs + ((size_t)p * C_DIM + c) * 4);
                pe.x *= LOG2E; pe.y *= LOG2E; pe.z *= LOG2E; pe.w *= LOG2E;
                a0 += lse2_2(pe.x + l0, pe.y + l1);
                a1 += lse2_2(pe.z + l0, pe.w + l1);
            }
            nxt[i * 2] = a0; nxt[i * 2 + 1] = a1;
            da[p] = a1 - a0;
        }
        __syncthreads();
        float* t = cur; cur = nxt; nxt = t;
    }
    if (lane == 0) erow[0] = sigmoid2(2.f * se[0] + da[0]);

    float* bcur = P0; float* bnxt = P1;
    for (int l = 1; l <= DEPTH - 1; ++l) {
        const int nc = 1 << l;
        const int cg0 = nc - 1;
        const bool top = (l == 1), last = (l == DEPTH - 1);
        for (int j = lane; j < nc; j += 64) {
            const int c = cg0 + j;
            const int p = (c - 1) >> 1;
            const int ip = j >> 1;
            float b0 = 0.f, b1 = 0.f;
            if (!top) { b0 = bcur[ip * 2]; b1 = bcur[ip * 2 + 1]; }
            const float lp0 = -se[p] + b0;
            const float lp1 =  se[p] + b1;
            float4 pe = *(const float4*)(pairs + ((size_t)p * C_DIM + c) * 4);
            pe.x *= LOG2E; pe.y *= LOG2E; pe.z *= LOG2E; pe.w *= LOG2E;
            const float bc0 = lse2_2(lp0 + pe.x, lp1 + pe.z);
            const float bc1 = lse2_2(lp0 + pe.y, lp1 + pe.w);
            if (!last) { bnxt[j * 2] = bc0; bnxt[j * 2 + 1] = bc1; }
            float d = 2.f * se[c] + (bc1 - bc0);
            if (c < 1023) d += da[c];
            erow[c] = sigmoid2(d);
        }
        __syncthreads();
        float* t = bcur; bcur = bnxt; bnxt = t;
    }
}

// ---------------------------------------------------------------------------
extern "C" void kernel_launch(void* const* d_in, const int* in_sizes, int n_in,
                              void* d_out, int out_size, void* d_ws, size_t ws_size,
                              hipStream_t stream) {
    const float* x     = (const float*)d_in[0];
    const float* w     = (const float*)d_in[1];
    const float* bias  = (const float*)d_in[2];
    const float* pairs = (const float*)d_in[3];
    float* out = (float*)d_out;

    const size_t need = (size_t)(XTOT + WTOT) * 2 + (size_t)C_PAD * 16;  // ~12.6 MiB

    unsigned short* xb = (unsigned short*)d_ws;
    unsigned short* wb = xb + (size_t)XTOT;
    float4* packed = (float4*)(wb + (size_t)WTOT);

    if (ws_size >= need) {
        cvt_kernel<<<(XTOT + WTOT) / (256 * 4), 256, 0, stream>>>(x, w, xb, wb);
        pack_kernel<<<C_PAD / 256, 256, 0, stream>>>(pairs, packed);
        dim3 ggrid(C_PAD / 128, B_DIM / 128);
        gemm_bf16_kernel<<<ggrid, 256, 0, stream>>>(xb, wb, bias, out);
        crf_wave_kernel<<<B_DIM, 64, 0, stream>>>(packed, out);
    } else {
        dim3 ggrid((C_DIM + BNF - 1) / BNF, B_DIM / BMF);
        gemm_f32_kernel<<<ggrid, 256, 0, stream>>>(x, w, bias, out);
        crf_fallback_kernel<<<B_DIM, 64, 0, stream>>>(pairs, out);
    }
}

// Round 7
// 80.813 us; speedup vs baseline: 1.9730x; 1.0190x over previous
//
#include <hip/hip_runtime.h>
#include <math.h>

// Problem dims (fixed by the reference)
#define B_DIM 4096
#define F_DIM 1024
#define C_DIM 2047
#define C_PAD 2048
#define DEPTH 11

#define LOG2E 1.4426950408889634f

typedef __attribute__((ext_vector_type(8))) short bf16x8;
typedef __attribute__((ext_vector_type(4))) float f32x4;

#define AS1(p) ((const __attribute__((address_space(1))) void*)(p))
#define AS3(p) ((__attribute__((address_space(3))) void*)(p))

// ---------------------------------------------------------------------------
// bf16 helpers (RNE)
// ---------------------------------------------------------------------------
__device__ __forceinline__ unsigned short f2bf(float f) {
    unsigned int u = __float_as_uint(f);
    unsigned int r = (u + 0x7fffu + ((u >> 16) & 1u)) >> 16;
    return (unsigned short)r;
}

// ---------------------------------------------------------------------------
// Convert: x (B,F) f32 -> xb bf16 ; w (C,F) f32 -> wb bf16 (padded to C_PAD)
// ---------------------------------------------------------------------------
#define XTOT (B_DIM * F_DIM)          // 4194304
#define WTOT (C_PAD * F_DIM)          // 2097152

__global__ __launch_bounds__(256) void cvt_kernel(
    const float* __restrict__ x, const float* __restrict__ w,
    unsigned short* __restrict__ xb, unsigned short* __restrict__ wb)
{
    const int i = (blockIdx.x * 256 + threadIdx.x) * 4;
    if (i < XTOT) {
        float4 v = *(const float4*)(x + i);
        ushort4 h;
        h.x = f2bf(v.x); h.y = f2bf(v.y); h.z = f2bf(v.z); h.w = f2bf(v.w);
        *(ushort4*)(xb + i) = h;
    } else {
        const int j = i - XTOT;                    // < WTOT
        const int row = j >> 10;                   // F = 1024
        ushort4 h = {0, 0, 0, 0};
        if (row < C_DIM) {
            float4 v = *(const float4*)(w + j);
            h.x = f2bf(v.x); h.y = f2bf(v.y); h.z = f2bf(v.z); h.w = f2bf(v.w);
        }
        *(ushort4*)(wb + j) = h;
    }
}

// ---------------------------------------------------------------------------
// Pack the 2046 tree-edge potentials contiguously, PRE-SCALED by log2(e):
//   packed[c] = pairs[(c-1)/2][c] * LOG2E, c in 1..2046
// ---------------------------------------------------------------------------
__global__ __launch_bounds__(256) void pack_kernel(
    const float* __restrict__ pairs, float4* __restrict__ packed)
{
    const int c = blockIdx.x * 256 + threadIdx.x;
    if (c >= 1 && c < C_DIM) {
        const int p = (c - 1) >> 1;
        float4 v = *(const float4*)(pairs + ((size_t)p * C_DIM + c) * 4);
        v.x *= LOG2E; v.y *= LOG2E; v.z *= LOG2E; v.w *= LOG2E;
        packed[c] = v;
    }
}

// ---------------------------------------------------------------------------
// MFMA GEMM: eb[r*2048 + c + 1] = (x @ W^T + bias)[r,c]  (padded, +1 shifted
// so the CRF's per-lane node blocks are 16B-aligned).
// 128x128 tile, BK=32, 256 threads (4 waves 2x2), 16x16x32 bf16 MFMA,
// global_load_lds width-16 staging; conflict-free chunk swizzle s(row)=(row>>1)&3.
// ---------------------------------------------------------------------------
__global__ __launch_bounds__(256) void gemm_bf16_kernel(
    const unsigned short* __restrict__ xb, const unsigned short* __restrict__ wb,
    const float* __restrict__ bias, float* __restrict__ eb)
{
    __shared__ unsigned short smemA[128 * 32];  // [row][k] 64B rows
    __shared__ unsigned short smemB[128 * 32];

    const int tid  = threadIdx.x;
    const int lane = tid & 63;
    const int wave = tid >> 6;
    const int wr = wave >> 1, wc = wave & 1;
    const int bn = blockIdx.x, bm = blockIdx.y;

    f32x4 acc[4][4] = {};
    const int r0 = tid >> 2,         c0 = tid & 3;
    const int r1 = (tid + 256) >> 2, c1 = tid & 3;
    const int sc0 = ((c0 ^ ((r0 >> 1) & 3)) << 3);
    const int sc1 = ((c1 ^ ((r1 >> 1) & 3)) << 3);

    const size_t arow0 = (size_t)(bm * 128 + r0) * F_DIM;
    const size_t arow1 = (size_t)(bm * 128 + r1) * F_DIM;
    const size_t brow0 = (size_t)(bn * 128 + r0) * F_DIM;
    const size_t brow1 = (size_t)(bn * 128 + r1) * F_DIM;

    unsigned short* ldsA0 = smemA + wave * 512;
    unsigned short* ldsA1 = smemA + 2048 + wave * 512;
    unsigned short* ldsB0 = smemB + wave * 512;
    unsigned short* ldsB1 = smemB + 2048 + wave * 512;

    const int fra = wr * 64 + (lane & 15);
    const int frb = wc * 64 + (lane & 15);
    const int kc  = lane >> 4;

    for (int k0 = 0; k0 < F_DIM; k0 += 32) {
        __builtin_amdgcn_global_load_lds(AS1(xb + arow0 + k0 + sc0), AS3(ldsA0), 16, 0, 0);
        __builtin_amdgcn_global_load_lds(AS1(xb + arow1 + k0 + sc1), AS3(ldsA1), 16, 0, 0);
        __builtin_amdgcn_global_load_lds(AS1(wb + brow0 + k0 + sc0), AS3(ldsB0), 16, 0, 0);
        __builtin_amdgcn_global_load_lds(AS1(wb + brow1 + k0 + sc1), AS3(ldsB1), 16, 0, 0);
        __syncthreads();

        bf16x8 af[4], bfr[4];
#pragma unroll
        for (int m = 0; m < 4; ++m) {
            const int row = fra + m * 16;
            af[m] = *(const bf16x8*)(smemA + row * 32 + ((kc ^ ((row >> 1) & 3)) << 3));
        }
#pragma unroll
        for (int n = 0; n < 4; ++n) {
            const int row = frb + n * 16;
            bfr[n] = *(const bf16x8*)(smemB + row * 32 + ((kc ^ ((row >> 1) & 3)) << 3));
        }
#pragma unroll
        for (int m = 0; m < 4; ++m)
#pragma unroll
            for (int n = 0; n < 4; ++n)
                acc[m][n] = __builtin_amdgcn_mfma_f32_16x16x32_bf16(
                    af[m], bfr[n], acc[m][n], 0, 0, 0);
        __syncthreads();
    }

    const int colbase = bn * 128 + wc * 64 + (lane & 15);
    const int rowbase = bm * 128 + wr * 64 + ((lane >> 4) << 2);
#pragma unroll
    for (int m = 0; m < 4; ++m)
#pragma unroll
        for (int n = 0; n < 4; ++n) {
            const int gc = colbase + n * 16;
            if (gc < C_DIM) {
                const float bv = bias[gc];
#pragma unroll
                for (int r = 0; r < 4; ++r)
                    eb[(size_t)(rowbase + m * 16 + r) * C_PAD + gc + 1] = acc[m][n][r] + bv;
            }
        }
}

// ---------------------------------------------------------------------------
// Fallback f32 GEMM (only if ws too small) — writes d_out directly
// ---------------------------------------------------------------------------
#define BMF 64
#define BNF 64
#define BKF 16

__global__ __launch_bounds__(256) void gemm_f32_kernel(
    const float* __restrict__ x, const float* __restrict__ w,
    const float* __restrict__ bias, float* __restrict__ e)
{
    __shared__ float As[BKF][BMF];
    __shared__ float Bs[BKF][BNF];
    const int bn = blockIdx.x, bm = blockIdx.y;
    const int tid = threadIdx.x;
    const int tx = tid & 15, ty = tid >> 4;
    const int m0 = ty * 4, n0 = tx * 4;
    const int lrow = tid >> 2, lc4 = (tid & 3) * 4;
    const int gm = bm * BMF + lrow;
    const int gn = bn * BNF + lrow;
    const bool wvalid = (gn < C_DIM);
    const float* xp = x + (size_t)gm * F_DIM + lc4;
    const float* wp = wvalid ? (w + (size_t)gn * F_DIM + lc4) : w;
    float acc[4][4] = {};
    for (int k0 = 0; k0 < F_DIM; k0 += BKF) {
        float4 av = *(const float4*)(xp + k0);
        float4 bv = make_float4(0.f, 0.f, 0.f, 0.f);
        if (wvalid) bv = *(const float4*)(wp + k0);
        As[lc4 + 0][lrow] = av.x; As[lc4 + 1][lrow] = av.y;
        As[lc4 + 2][lrow] = av.z; As[lc4 + 3][lrow] = av.w;
        Bs[lc4 + 0][lrow] = bv.x; Bs[lc4 + 1][lrow] = bv.y;
        Bs[lc4 + 2][lrow] = bv.z; Bs[lc4 + 3][lrow] = bv.w;
        __syncthreads();
#pragma unroll
        for (int k = 0; k < BKF; ++k) {
            float4 a = *(const float4*)&As[k][m0];
            float4 b = *(const float4*)&Bs[k][n0];
            acc[0][0] += a.x * b.x; acc[0][1] += a.x * b.y; acc[0][2] += a.x * b.z; acc[0][3] += a.x * b.w;
            acc[1][0] += a.y * b.x; acc[1][1] += a.y * b.y; acc[1][2] += a.y * b.z; acc[1][3] += a.y * b.w;
            acc[2][0] += a.z * b.x; acc[2][1] += a.z * b.y; acc[2][2] += a.z * b.z; acc[2][3] += a.z * b.w;
            acc[3][0] += a.w * b.x; acc[3][1] += a.w * b.y; acc[3][2] += a.w * b.z; acc[3][3] += a.w * b.w;
        }
        __syncthreads();
    }
    const int gmo = bm * BMF + m0, gno = bn * BNF + n0;
#pragma unroll
    for (int i = 0; i < 4; ++i)
#pragma unroll
        for (int j = 0; j < 4; ++j) {
            int n = gno + j;
            if (n < C_DIM) e[(size_t)(gmo + i) * C_DIM + n] = acc[i][j] + bias[n];
        }
}

// ---------------------------------------------------------------------------
// Tree-CRF, barrier-free, register-resident: 4 rows per 256-thread block
// (one wave per row). Emissions loaded ONCE via aligned float4 from padded eb.
// Only log-odds DIFFERENCES (da, db) propagate: 2 lse2 per edge per direction.
// ---------------------------------------------------------------------------
__device__ __forceinline__ float lse2_2(float a, float b) {
    float m = fmaxf(a, b);
    return m + __log2f(1.f + exp2f(fminf(a, b) - m));
}
__device__ __forceinline__ float sigmoid2(float d) {
    return __builtin_amdgcn_rcpf(1.f + exp2f(-d));
}

__global__ __launch_bounds__(256) void crf_wave_kernel(
    const float4* __restrict__ packed,  // packed[c] * log2e
    const float* __restrict__ eb,       // (B, C_PAD) padded emissions, +1 shift
    float* __restrict__ out)            // (B, C_DIM) probabilities
{
    const int lane = threadIdx.x & 63;
    const int row  = blockIdx.x * 4 + (threadIdx.x >> 6);
    const float* ebr = eb + (size_t)row * C_PAD;
    float* orow = out + (size_t)row * C_DIM;

    const int L16 = 16 * lane, L8 = 8 * lane, L4 = 4 * lane, L2 = 2 * lane;

    // ---------------- load ALL emissions into registers (aligned vec4) ------
    float el[16], e9[8], e8[4], e7[2], e6, eup[6];
#pragma unroll
    for (int q = 0; q < 4; ++q) {
        float4 v = *(const float4*)(ebr + 1024 + L16 + 4 * q);
        el[4*q+0] = v.x * LOG2E; el[4*q+1] = v.y * LOG2E;
        el[4*q+2] = v.z * LOG2E; el[4*q+3] = v.w * LOG2E;
    }
#pragma unroll
    for (int q = 0; q < 2; ++q) {
        float4 v = *(const float4*)(ebr + 512 + L8 + 4 * q);
        e9[4*q+0] = v.x * LOG2E; e9[4*q+1] = v.y * LOG2E;
        e9[4*q+2] = v.z * LOG2E; e9[4*q+3] = v.w * LOG2E;
    }
    {
        float4 v = *(const float4*)(ebr + 256 + L4);
        e8[0] = v.x * LOG2E; e8[1] = v.y * LOG2E; e8[2] = v.z * LOG2E; e8[3] = v.w * LOG2E;
        float2 u = *(const float2*)(ebr + 128 + L2);
        e7[0] = u.x * LOG2E; e7[1] = u.y * LOG2E;
        e6 = ebr[64 + lane] * LOG2E;
    }
#pragma unroll
    for (int lvl = 0; lvl < 6; ++lvl)
        eup[lvl] = ebr[(1 << lvl) + lane] * LOG2E;   // node (2^lvl -1)+lane, +1 shift

    // ---------------- subtree UP (levels 10 -> 6): da only ------------------
    float da9[8];
#pragma unroll
    for (int t = 0; t < 8; ++t) {
        float dm = 0.f;
#pragma unroll
        for (int s = 0; s < 2; ++s) {
            const float e = el[2*t+s];
            float4 pk = packed[1023 + L16 + 2*t + s];
            dm += lse2_2(pk.z - e, pk.w + e) - lse2_2(pk.x - e, pk.y + e);
        }
        da9[t] = dm;
    }
    float da8[4];
#pragma unroll
    for (int t = 0; t < 4; ++t) {
        float dm = 0.f;
#pragma unroll
        for (int s = 0; s < 2; ++s) {
            const float e = e9[2*t+s], da = da9[2*t+s];
            float4 pk = packed[511 + L8 + 2*t + s];
            dm += lse2_2(pk.z - e, pk.w + e + da) - lse2_2(pk.x - e, pk.y + e + da);
        }
        da8[t] = dm;
    }
    float da7[2];
#pragma unroll
    for (int t = 0; t < 2; ++t) {
        float dm = 0.f;
#pragma unroll
        for (int s = 0; s < 2; ++s) {
            const float e = e8[2*t+s], da = da8[2*t+s];
            float4 pk = packed[255 + L4 + 2*t + s];
            dm += lse2_2(pk.z - e, pk.w + e + da) - lse2_2(pk.x - e, pk.y + e + da);
        }
        da7[t] = dm;
    }
    float da6;
    {
        float dm = 0.f;
#pragma unroll
        for (int s = 0; s < 2; ++s) {
            const float e = e7[s], da = da7[s];
            float4 pk = packed[127 + L2 + s];
            dm += lse2_2(pk.z - e, pk.w + e + da) - lse2_2(pk.x - e, pk.y + e + da);
        }
        da6 = dm;
    }

    // ---------------- shuffle UP (levels 5 -> 0), 2 lse2/level --------------
    float daS[6];
    {
        float da_cur = da6, e_cur = e6;
        int cbase = 63;
#pragma unroll
        for (int lvl = 5; lvl >= 0; --lvl) {
            float4 pk = packed[cbase + lane];        // own node's parent-edge
            float m0 = lse2_2(pk.x - e_cur, pk.y + e_cur + da_cur);
            float m1 = lse2_2(pk.z - e_cur, pk.w + e_cur + da_cur);
            float dm = m1 - m0;
            float da_new = __shfl(dm, (2 * lane) & 63, 64)
                         + __shfl(dm, (2 * lane + 1) & 63, 64);
            da_cur = da_new;
            e_cur  = eup[lvl];
            daS[lvl] = da_new;                       // valid lane < 2^lvl
            cbase = (1 << lvl) - 1;
        }
    }

    // ---------------- shuffle DOWN (levels 0 -> 5) + emit tops --------------
    float db_cur = 0.f;
#pragma unroll
    for (int lvl = 0; lvl < 6; ++lvl) {
        const int np = 1 << lvl;
        if (lane < np)
            orow[np - 1 + lane] = sigmoid2(2.f * eup[lvl] + daS[lvl] + db_cur);
        float pdb = __shfl(db_cur, lane >> 1, 64);
        float pe  = __shfl(eup[lvl], lane >> 1, 64);
        float4 pk = packed[2 * np - 1 + lane];       // own node at level lvl+1
        float lp0 = -pe, lp1 = pe + pdb;
        db_cur = lse2_2(lp0 + pk.y, lp1 + pk.w) - lse2_2(lp0 + pk.x, lp1 + pk.z);
    }
    // db_cur = db of level-6 node (63+lane)

    // ---------------- subtree DOWN (6 -> 10) + emit -------------------------
    orow[63 + lane] = sigmoid2(2.f * e6 + da6 + db_cur);
    float db7[2];
    {
        const float lp0 = -e6, lp1 = e6 + db_cur;
#pragma unroll
        for (int s = 0; s < 2; ++s) {
            float4 pk = packed[127 + L2 + s];
            db7[s] = lse2_2(lp0 + pk.y, lp1 + pk.w) - lse2_2(lp0 + pk.x, lp1 + pk.z);
            orow[127 + L2 + s] = sigmoid2(2.f * e7[s] + da7[s] + db7[s]);
        }
    }
    float db8[4];
#pragma unroll
    for (int t = 0; t < 2; ++t) {
        const float lp0 = -e7[t], lp1 = e7[t] + db7[t];
#pragma unroll
        for (int s = 0; s < 2; ++s) {
            float4 pk = packed[255 + L4 + 2*t + s];
            db8[2*t+s] = lse2_2(lp0 + pk.y, lp1 + pk.w) - lse2_2(lp0 + pk.x, lp1 + pk.z);
            orow[255 + L4 + 2*t + s] =
                sigmoid2(2.f * e8[2*t+s] + da8[2*t+s] + db8[2*t+s]);
        }
    }
    float db9[8];
#pragma unroll
    for (int t = 0; t < 4; ++t) {
        const float lp0 = -e8[t], lp1 = e8[t] + db8[t];
#pragma unroll
        for (int s = 0; s < 2; ++s) {
            float4 pk = packed[511 + L8 + 2*t + s];
            db9[2*t+s] = lse2_2(lp0 + pk.y, lp1 + pk.w) - lse2_2(lp0 + pk.x, lp1 + pk.z);
            orow[511 + L8 + 2*t + s] =
                sigmoid2(2.f * e9[2*t+s] + da9[2*t+s] + db9[2*t+s]);
        }
    }
#pragma unroll
    for (int t = 0; t < 8; ++t) {
        const float lp0 = -e9[t], lp1 = e9[t] + db9[t];
#pragma unroll
        for (int s = 0; s < 2; ++s) {
            float4 pk = packed[1023 + L16 + 2*t + s];
            float db = lse2_2(lp0 + pk.y, lp1 + pk.w) - lse2_2(lp0 + pk.x, lp1 + pk.z);
            orow[1023 + L16 + 2*t + s] = sigmoid2(2.f * el[2*t+s] + db);
        }
    }
}

// ---------------------------------------------------------------------------
// Fallback CRF (block-per-row, LDS, raw pairs, in-place on d_out)
// ---------------------------------------------------------------------------
__global__ __launch_bounds__(64) void crf_fallback_kernel(
    const float* __restrict__ pairs, float* __restrict__ eo)
{
    __shared__ float se[C_DIM];
    __shared__ float da[1023];
    __shared__ float P0[1024];
    __shared__ float P1[1024];

    const int row  = blockIdx.x;
    const int lane = threadIdx.x;
    float* erow = eo + (size_t)row * C_DIM;

    for (int c = lane; c < C_DIM; c += 64) se[c] = erow[c] * LOG2E;
    __syncthreads();

    float* cur = P0; float* nxt = P1;
    for (int l = DEPTH - 1; l >= 1; --l) {
        const int np = 1 << (l - 1);
        const int pg0 = np - 1;
        const bool leaf = (l == DEPTH - 1);
        for (int i = lane; i < np; i += 64) {
            const int p = pg0 + i;
            float a0 = 0.f, a1 = 0.f;
#pragma unroll
            for (int s = 0; s < 2; ++s) {
                const int c = 2 * p + 1 + s;
                const int jc = 2 * i + s;
                float ca0 = 0.f, ca1 = 0.f;
                if (!leaf) { ca0 = cur[jc * 2]; ca1 = cur[jc * 2 + 1]; }
                const float l0 = -se[c] + ca0;
                const float l1 =  se[c] + ca1;
                float4 pe = *(const float4*)(pairs + ((size_t)p * C_DIM + c) * 4);
                pe.x *= LOG2E; pe.y *= LOG2E; pe.z *= LOG2E; pe.w *= LOG2E;
                a0 += lse2_2(pe.x + l0, pe.y + l1);
                a1 += lse2_2(pe.z + l0, pe.w + l1);
            }
            nxt[i * 2] = a0; nxt[i * 2 + 1] = a1;
            da[p] = a1 - a0;
        }
        __syncthreads();
        float* t = cur; cur = nxt; nxt = t;
    }
    if (lane == 0) erow[0] = sigmoid2(2.f * se[0] + da[0]);

    float* bcur = P0; float* bnxt = P1;
    for (int l = 1; l <= DEPTH - 1; ++l) {
        const int nc = 1 << l;
        const int cg0 = nc - 1;
        const bool top = (l == 1), last = (l == DEPTH - 1);
        for (int j = lane; j < nc; j += 64) {
            const int c = cg0 + j;
            const int p = (c - 1) >> 1;
            const int ip = j >> 1;
            float b0 = 0.f, b1 = 0.f;
            if (!top) { b0 = bcur[ip * 2]; b1 = bcur[ip * 2 + 1]; }
            const float lp0 = -se[p] + b0;
            const float lp1 =  se[p] + b1;
            float4 pe = *(const float4*)(pairs + ((size_t)p * C_DIM + c) * 4);
            pe.x *= LOG2E; pe.y *= LOG2E; pe.z *= LOG2E; pe.w *= LOG2E;
            const float bc0 = lse2_2(lp0 + pe.x, lp1 + pe.z);
            const float bc1 = lse2_2(lp0 + pe.y, lp1 + pe.w);
            if (!last) { bnxt[j * 2] = bc0; bnxt[j * 2 + 1] = bc1; }
            float d = 2.f * se[c] + (bc1 - bc0);
            if (c < 1023) d += da[c];
            erow[c] = sigmoid2(d);
        }
        __syncthreads();
        float* t = bcur; bcur = bnxt; bnxt = t;
    }
}

// ---------------------------------------------------------------------------
extern "C" void kernel_launch(void* const* d_in, const int* in_sizes, int n_in,
                              void* d_out, int out_size, void* d_ws, size_t ws_size,
                              hipStream_t stream) {
    const float* x     = (const float*)d_in[0];
    const float* w     = (const float*)d_in[1];
    const float* bias  = (const float*)d_in[2];
    const float* pairs = (const float*)d_in[3];
    float* out = (float*)d_out;

    // ws layout: xb | wb | packed | eb (padded emissions)
    unsigned short* xb = (unsigned short*)d_ws;
    unsigned short* wb = xb + (size_t)XTOT;
    float4* packed = (float4*)(wb + (size_t)WTOT);
    float* ebuf = (float*)(packed + C_PAD);

    const size_t need = (size_t)(XTOT + WTOT) * 2 + (size_t)C_PAD * 16
                      + ((size_t)B_DIM * C_PAD + C_PAD) * 4;   // ~44.2 MiB

    if (ws_size >= need) {
        cvt_kernel<<<(XTOT + WTOT) / (256 * 4), 256, 0, stream>>>(x, w, xb, wb);
        pack_kernel<<<C_PAD / 256, 256, 0, stream>>>(pairs, packed);
        dim3 ggrid(C_PAD / 128, B_DIM / 128);
        gemm_bf16_kernel<<<ggrid, 256, 0, stream>>>(xb, wb, bias, ebuf);
        crf_wave_kernel<<<B_DIM / 4, 256, 0, stream>>>(packed, ebuf, out);
    } else {
        dim3 ggrid((C_DIM + BNF - 1) / BNF, B_DIM / BMF);
        gemm_f32_kernel<<<ggrid, 256, 0, stream>>>(x, w, bias, out);
        crf_fallback_kernel<<<B_DIM, 64, 0, stream>>>(pairs, out);
    }
}

// Round 8
// 68.386 us; speedup vs baseline: 2.3315x; 1.1817x over previous
//
#include <hip/hip_runtime.h>
#include <math.h>

// Problem dims (fixed by the reference)
#define B_DIM 4096
#define F_DIM 1024
#define C_DIM 2047
#define C_PAD 2048
#define DEPTH 11

#define LOG2E 1.4426950408889634f

typedef __attribute__((ext_vector_type(8))) short bf16x8;
typedef __attribute__((ext_vector_type(4))) float f32x4;

#define AS1(p) ((const __attribute__((address_space(1))) void*)(p))
#define AS3(p) ((__attribute__((address_space(3))) void*)(p))

// ---------------------------------------------------------------------------
// bf16 helpers (RNE)
// ---------------------------------------------------------------------------
__device__ __forceinline__ unsigned short f2bf(float f) {
    unsigned int u = __float_as_uint(f);
    unsigned int r = (u + 0x7fffu + ((u >> 16) & 1u)) >> 16;
    return (unsigned short)r;
}

// ---------------------------------------------------------------------------
// Convert: x (B,F) f32 -> xb bf16 ; w (C,F) f32 -> wb bf16 (padded to C_PAD)
// ---------------------------------------------------------------------------
#define XTOT (B_DIM * F_DIM)          // 4194304
#define WTOT (C_PAD * F_DIM)          // 2097152

__global__ __launch_bounds__(256) void cvt_kernel(
    const float* __restrict__ x, const float* __restrict__ w,
    unsigned short* __restrict__ xb, unsigned short* __restrict__ wb)
{
    const int i = (blockIdx.x * 256 + threadIdx.x) * 4;
    if (i < XTOT) {
        float4 v = *(const float4*)(x + i);
        ushort4 h;
        h.x = f2bf(v.x); h.y = f2bf(v.y); h.z = f2bf(v.z); h.w = f2bf(v.w);
        *(ushort4*)(xb + i) = h;
    } else {
        const int j = i - XTOT;                    // < WTOT
        const int row = j >> 10;                   // F = 1024
        ushort4 h = {0, 0, 0, 0};
        if (row < C_DIM) {
            float4 v = *(const float4*)(w + j);
            h.x = f2bf(v.x); h.y = f2bf(v.y); h.z = f2bf(v.z); h.w = f2bf(v.w);
        }
        *(ushort4*)(wb + j) = h;
    }
}

// ---------------------------------------------------------------------------
// Pack tree-edge potentials as SoA planes (x,y,z,w), +1-shifted, *LOG2E:
//   pk[comp*2048 + c + 1] = pairs[(c-1)/2][c][comp] * LOG2E, c in 1..2046
// ---------------------------------------------------------------------------
__global__ __launch_bounds__(256) void pack_kernel(
    const float* __restrict__ pairs, float* __restrict__ pk)
{
    const int c = blockIdx.x * 256 + threadIdx.x;
    if (c >= 1 && c < C_DIM) {
        const int p = (c - 1) >> 1;
        float4 v = *(const float4*)(pairs + ((size_t)p * C_DIM + c) * 4);
        pk[c + 1]        = v.x * LOG2E;
        pk[c + 1 + 2048] = v.y * LOG2E;
        pk[c + 1 + 4096] = v.z * LOG2E;
        pk[c + 1 + 6144] = v.w * LOG2E;
    }
}

// ---------------------------------------------------------------------------
// MFMA GEMM: eb[r*2048 + c + 1] = (x @ W^T + bias)[r,c]  (padded, +1 shifted).
// 128x128 tile, BK=32, 256 threads (4 waves 2x2), 16x16x32 bf16 MFMA,
// global_load_lds width-16 staging; conflict-free chunk swizzle s(row)=(row>>1)&3.
// XCD-aware block swizzle (nwg=512, bijective): each XCD gets 4 row-panels.
// ---------------------------------------------------------------------------
__global__ __launch_bounds__(256) void gemm_bf16_kernel(
    const unsigned short* __restrict__ xb, const unsigned short* __restrict__ wb,
    const float* __restrict__ bias, float* __restrict__ eb)
{
    __shared__ unsigned short smemA[128 * 32];  // [row][k] 64B rows
    __shared__ unsigned short smemB[128 * 32];

    const int tid  = threadIdx.x;
    const int lane = tid & 63;
    const int wave = tid >> 6;
    const int wr = wave >> 1, wc = wave & 1;

    // XCD swizzle: hw linear id -> contiguous chunk per XCD
    const int lin = blockIdx.x + blockIdx.y * gridDim.x;   // 0..511
    const int wg  = (lin & 7) * 64 + (lin >> 3);
    const int bn = wg & 15, bm = wg >> 4;

    f32x4 acc[4][4] = {};
    const int r0 = tid >> 2,         c0 = tid & 3;
    const int r1 = (tid + 256) >> 2, c1 = tid & 3;
    const int sc0 = ((c0 ^ ((r0 >> 1) & 3)) << 3);
    const int sc1 = ((c1 ^ ((r1 >> 1) & 3)) << 3);

    const size_t arow0 = (size_t)(bm * 128 + r0) * F_DIM;
    const size_t arow1 = (size_t)(bm * 128 + r1) * F_DIM;
    const size_t brow0 = (size_t)(bn * 128 + r0) * F_DIM;
    const size_t brow1 = (size_t)(bn * 128 + r1) * F_DIM;

    unsigned short* ldsA0 = smemA + wave * 512;
    unsigned short* ldsA1 = smemA + 2048 + wave * 512;
    unsigned short* ldsB0 = smemB + wave * 512;
    unsigned short* ldsB1 = smemB + 2048 + wave * 512;

    const int fra = wr * 64 + (lane & 15);
    const int frb = wc * 64 + (lane & 15);
    const int kc  = lane >> 4;

    for (int k0 = 0; k0 < F_DIM; k0 += 32) {
        __builtin_amdgcn_global_load_lds(AS1(xb + arow0 + k0 + sc0), AS3(ldsA0), 16, 0, 0);
        __builtin_amdgcn_global_load_lds(AS1(xb + arow1 + k0 + sc1), AS3(ldsA1), 16, 0, 0);
        __builtin_amdgcn_global_load_lds(AS1(wb + brow0 + k0 + sc0), AS3(ldsB0), 16, 0, 0);
        __builtin_amdgcn_global_load_lds(AS1(wb + brow1 + k0 + sc1), AS3(ldsB1), 16, 0, 0);
        __syncthreads();

        bf16x8 af[4], bfr[4];
#pragma unroll
        for (int m = 0; m < 4; ++m) {
            const int row = fra + m * 16;
            af[m] = *(const bf16x8*)(smemA + row * 32 + ((kc ^ ((row >> 1) & 3)) << 3));
        }
#pragma unroll
        for (int n = 0; n < 4; ++n) {
            const int row = frb + n * 16;
            bfr[n] = *(const bf16x8*)(smemB + row * 32 + ((kc ^ ((row >> 1) & 3)) << 3));
        }
#pragma unroll
        for (int m = 0; m < 4; ++m)
#pragma unroll
            for (int n = 0; n < 4; ++n)
                acc[m][n] = __builtin_amdgcn_mfma_f32_16x16x32_bf16(
                    af[m], bfr[n], acc[m][n], 0, 0, 0);
        __syncthreads();
    }

    const int colbase = bn * 128 + wc * 64 + (lane & 15);
    const int rowbase = bm * 128 + wr * 64 + ((lane >> 4) << 2);
#pragma unroll
    for (int m = 0; m < 4; ++m)
#pragma unroll
        for (int n = 0; n < 4; ++n) {
            const int gc = colbase + n * 16;
            if (gc < C_DIM) {
                const float bv = bias[gc];
#pragma unroll
                for (int r = 0; r < 4; ++r)
                    eb[(size_t)(rowbase + m * 16 + r) * C_PAD + gc + 1] = acc[m][n][r] + bv;
            }
        }
}

// ---------------------------------------------------------------------------
// Fallback f32 GEMM (only if ws too small) — writes d_out directly
// ---------------------------------------------------------------------------
#define BMF 64
#define BNF 64
#define BKF 16

__global__ __launch_bounds__(256) void gemm_f32_kernel(
    const float* __restrict__ x, const float* __restrict__ w,
    const float* __restrict__ bias, float* __restrict__ e)
{
    __shared__ float As[BKF][BMF];
    __shared__ float Bs[BKF][BNF];
    const int bn = blockIdx.x, bm = blockIdx.y;
    const int tid = threadIdx.x;
    const int tx = tid & 15, ty = tid >> 4;
    const int m0 = ty * 4, n0 = tx * 4;
    const int lrow = tid >> 2, lc4 = (tid & 3) * 4;
    const int gm = bm * BMF + lrow;
    const int gn = bn * BNF + lrow;
    const bool wvalid = (gn < C_DIM);
    const float* xp = x + (size_t)gm * F_DIM + lc4;
    const float* wp = wvalid ? (w + (size_t)gn * F_DIM + lc4) : w;
    float acc[4][4] = {};
    for (int k0 = 0; k0 < F_DIM; k0 += BKF) {
        float4 av = *(const float4*)(xp + k0);
        float4 bv = make_float4(0.f, 0.f, 0.f, 0.f);
        if (wvalid) bv = *(const float4*)(wp + k0);
        As[lc4 + 0][lrow] = av.x; As[lc4 + 1][lrow] = av.y;
        As[lc4 + 2][lrow] = av.z; As[lc4 + 3][lrow] = av.w;
        Bs[lc4 + 0][lrow] = bv.x; Bs[lc4 + 1][lrow] = bv.y;
        Bs[lc4 + 2][lrow] = bv.z; Bs[lc4 + 3][lrow] = bv.w;
        __syncthreads();
#pragma unroll
        for (int k = 0; k < BKF; ++k) {
            float4 a = *(const float4*)&As[k][m0];
            float4 b = *(const float4*)&Bs[k][n0];
            acc[0][0] += a.x * b.x; acc[0][1] += a.x * b.y; acc[0][2] += a.x * b.z; acc[0][3] += a.x * b.w;
            acc[1][0] += a.y * b.x; acc[1][1] += a.y * b.y; acc[1][2] += a.y * b.z; acc[1][3] += a.y * b.w;
            acc[2][0] += a.z * b.x; acc[2][1] += a.z * b.y; acc[2][2] += a.z * b.z; acc[2][3] += a.z * b.w;
            acc[3][0] += a.w * b.x; acc[3][1] += a.w * b.y; acc[3][2] += a.w * b.z; acc[3][3] += a.w * b.w;
        }
        __syncthreads();
    }
    const int gmo = bm * BMF + m0, gno = bn * BNF + n0;
#pragma unroll
    for (int i = 0; i < 4; ++i)
#pragma unroll
        for (int j = 0; j < 4; ++j) {
            int n = gno + j;
            if (n < C_DIM) e[(size_t)(gmo + i) * C_DIM + n] = acc[i][j] + bias[n];
        }
}

// ---------------------------------------------------------------------------
// Tree-CRF, barrier-free, INTERLEAVED lane ownership (all loads coalesced):
//   leaves:  lane L owns j = 4L+256q+r  (float4-dense)
//   level 9: lane L owns i = 2L+128q+u  (float2-dense)
//   level 8/7: lane L owns v = L+64q    (scalar-dense)
//   levels <=6: lane L owns node L      (as before)
// Sibling pairs are in-lane at 10->9 and 9->8; 8->7 and 7->6 combine via
// shfl_xor(1) + 2 bpermutes with STATIC register indices. Down-sweep mirrors.
// packed is SoA (4 planes) so per-component loads are lane-consecutive.
// ---------------------------------------------------------------------------
__device__ __forceinline__ float lse2_2(float a, float b) {
    float m = fmaxf(a, b);
    return m + __log2f(1.f + exp2f(fminf(a, b) - m));
}
__device__ __forceinline__ float sigmoid2(float d) {
    return __builtin_amdgcn_rcpf(1.f + exp2f(-d));
}

__global__ __launch_bounds__(256) void crf_wave_kernel(
    const float* __restrict__ pk,   // SoA [4][2048], +1 shifted, *LOG2E
    const float* __restrict__ eb,   // (B, C_PAD) padded emissions, +1 shift
    float* __restrict__ out)        // (B, C_DIM) probabilities
{
    const int lane = threadIdx.x & 63;
    const int row  = blockIdx.x * 4 + (threadIdx.x >> 6);
    const float* ebr = eb + (size_t)row * C_PAD;
    float* orow = out + (size_t)row * C_DIM;
    const float* pkx = pk;
    const float* pky = pk + 2048;
    const float* pkz = pk + 4096;
    const float* pkw = pk + 6144;

    // ================= UP: leaves (level 10) =================
    float el[4][4];            // emissions *LOG2E  [q][r]
    float da9[4][2];
#pragma unroll
    for (int q = 0; q < 4; ++q) {
        const int bi = 1024 + 4 * lane + 256 * q;
        float4 ev = *(const float4*)(ebr + bi);
        float4 k4x = *(const float4*)(pkx + bi);
        float4 k4y = *(const float4*)(pky + bi);
        float4 k4z = *(const float4*)(pkz + bi);
        float4 k4w = *(const float4*)(pkw + bi);
        float er[4] = {ev.x * LOG2E, ev.y * LOG2E, ev.z * LOG2E, ev.w * LOG2E};
        float xr[4] = {k4x.x, k4x.y, k4x.z, k4x.w};
        float yr[4] = {k4y.x, k4y.y, k4y.z, k4y.w};
        float zr[4] = {k4z.x, k4z.y, k4z.z, k4z.w};
        float wr4[4] = {k4w.x, k4w.y, k4w.z, k4w.w};
        float dm[4];
#pragma unroll
        for (int r = 0; r < 4; ++r) {
            el[q][r] = er[r];
            dm[r] = lse2_2(zr[r] - er[r], wr4[r] + er[r])
                  - lse2_2(xr[r] - er[r], yr[r] + er[r]);
        }
        da9[q][0] = dm[0] + dm[1];
        da9[q][1] = dm[2] + dm[3];
    }

    // ================= UP: level 9 =================
    float e9[4][2], da8[4];
#pragma unroll
    for (int q = 0; q < 4; ++q) {
        const int bi = 512 + 2 * lane + 128 * q;
        float2 ev = *(const float2*)(ebr + bi);
        float2 k2x = *(const float2*)(pkx + bi);
        float2 k2y = *(const float2*)(pky + bi);
        float2 k2z = *(const float2*)(pkz + bi);
        float2 k2w = *(const float2*)(pkw + bi);
        e9[q][0] = ev.x * LOG2E; e9[q][1] = ev.y * LOG2E;
        float dm0 = lse2_2(k2z.x - e9[q][0], k2w.x + e9[q][0] + da9[q][0])
                  - lse2_2(k2x.x - e9[q][0], k2y.x + e9[q][0] + da9[q][0]);
        float dm1 = lse2_2(k2z.y - e9[q][1], k2w.y + e9[q][1] + da9[q][1])
                  - lse2_2(k2x.y - e9[q][1], k2y.y + e9[q][1] + da9[q][1]);
        da8[q] = dm0 + dm1;
    }

    // ================= UP: level 8 =================
    float e8[4], ps8[4];
#pragma unroll
    for (int q = 0; q < 4; ++q) {
        const int bi = 256 + lane + 64 * q;
        e8[q] = ebr[bi] * LOG2E;
        float kx = pkx[bi], ky = pky[bi], kz = pkz[bi], kw = pkw[bi];
        float dm = lse2_2(kz - e8[q], kw + e8[q] + da8[q])
                 - lse2_2(kx - e8[q], ky + e8[q] + da8[q]);
        ps8[q] = dm + __shfl_xor(dm, 1, 64);
    }
    float da7[2];
    {
        const int s = (2 * lane) & 63;
        float t00 = __shfl(ps8[0], s, 64), t01 = __shfl(ps8[1], s, 64);
        float t10 = __shfl(ps8[2], s, 64), t11 = __shfl(ps8[3], s, 64);
        da7[0] = (lane >= 32) ? t01 : t00;
        da7[1] = (lane >= 32) ? t11 : t10;
    }

    // ================= UP: level 7 =================
    float e7[2], ps7[2];
#pragma unroll
    for (int q = 0; q < 2; ++q) {
        const int bi = 128 + lane + 64 * q;
        e7[q] = ebr[bi] * LOG2E;
        float kx = pkx[bi], ky = pky[bi], kz = pkz[bi], kw = pkw[bi];
        float dm = lse2_2(kz - e7[q], kw + e7[q] + da7[q])
                 - lse2_2(kx - e7[q], ky + e7[q] + da7[q]);
        ps7[q] = dm + __shfl_xor(dm, 1, 64);
    }
    float da6;
    {
        const int s = (2 * lane) & 63;
        float t0 = __shfl(ps7[0], s, 64), t1 = __shfl(ps7[1], s, 64);
        da6 = (lane >= 32) ? t1 : t0;
    }

    const float e6 = ebr[64 + lane] * LOG2E;
    float eup[6];
#pragma unroll
    for (int lvl = 0; lvl < 6; ++lvl)
        eup[lvl] = ebr[(1 << lvl) + lane] * LOG2E;

    // ================= UP: shuffle levels 5..0 =================
    float daS[6];
    {
        float da_cur = da6, e_cur = e6;
        int cb = 64;                                // pk idx of level-6 edges
#pragma unroll
        for (int lvl = 5; lvl >= 0; --lvl) {
            const int idx = cb + lane;
            float kx = pkx[idx], ky = pky[idx], kz = pkz[idx], kw = pkw[idx];
            float m0 = lse2_2(kx - e_cur, ky + e_cur + da_cur);
            float m1 = lse2_2(kz - e_cur, kw + e_cur + da_cur);
            float dm = m1 - m0;
            float da_new = __shfl(dm, (2 * lane) & 63, 64)
                         + __shfl(dm, (2 * lane + 1) & 63, 64);
            da_cur = da_new;
            e_cur  = eup[lvl];
            daS[lvl] = da_new;
            cb = (1 << lvl);
        }
    }

    // ================= DOWN: shuffle levels 0..5 =================
    float db_cur = 0.f;
#pragma unroll
    for (int lvl = 0; lvl < 6; ++lvl) {
        const int np = 1 << lvl;
        if (lane < np)
            orow[np - 1 + lane] = sigmoid2(2.f * eup[lvl] + daS[lvl] + db_cur);
        float pdb = __shfl(db_cur, lane >> 1, 64);
        float pe  = __shfl(eup[lvl], lane >> 1, 64);
        const int idx = 2 * np + lane;
        float kx = pkx[idx], ky = pky[idx], kz = pkz[idx], kw = pkw[idx];
        db_cur = lse2_2(-pe + ky, pe + pdb + kw) - lse2_2(-pe + kx, pe + pdb + kz);
    }
    const float db6 = db_cur;
    orow[63 + lane] = sigmoid2(2.f * e6 + da6 + db6);

    // ================= DOWN: 6 -> 7 =================
    float db7[2];
#pragma unroll
    for (int q = 0; q < 2; ++q) {
        const int u = (lane >> 1) + 32 * q;         // parent level-6 index
        float pe  = __shfl(e6, u, 64);
        float pdb = __shfl(db6, u, 64);
        const int bi = 128 + lane + 64 * q;
        float kx = pkx[bi], ky = pky[bi], kz = pkz[bi], kw = pkw[bi];
        db7[q] = lse2_2(-pe + ky, pe + pdb + kw) - lse2_2(-pe + kx, pe + pdb + kz);
        orow[127 + lane + 64 * q] = sigmoid2(2.f * e7[q] + da7[q] + db7[q]);
    }

    // ================= DOWN: 7 -> 8 =================
    float db8[4];
#pragma unroll
    for (int q = 0; q < 4; ++q) {
        const int u  = (lane >> 1) + 32 * q;        // parent level-7 index 0..127
        const int sl = u & 63;                      // src lane; src reg = q>>1
        float pe  = __shfl(e7[q >> 1], sl, 64);
        float pdb = __shfl(db7[q >> 1], sl, 64);
        const int bi = 256 + lane + 64 * q;
        float kx = pkx[bi], ky = pky[bi], kz = pkz[bi], kw = pkw[bi];
        db8[q] = lse2_2(-pe + ky, pe + pdb + kw) - lse2_2(-pe + kx, pe + pdb + kz);
        orow[255 + lane + 64 * q] = sigmoid2(2.f * e8[q] + da8[q] + db8[q]);
    }

    // ================= DOWN: 8 -> 9 (in-lane parents) =================
    float db9[4][2];
#pragma unroll
    for (int q = 0; q < 4; ++q) {
        const float lp0 = -e8[q], lp1 = e8[q] + db8[q];
        const int bi = 512 + 2 * lane + 128 * q;
        float2 k2x = *(const float2*)(pkx + bi);
        float2 k2y = *(const float2*)(pky + bi);
        float2 k2z = *(const float2*)(pkz + bi);
        float2 k2w = *(const float2*)(pkw + bi);
        db9[q][0] = lse2_2(lp0 + k2y.x, lp1 + k2w.x) - lse2_2(lp0 + k2x.x, lp1 + k2z.x);
        db9[q][1] = lse2_2(lp0 + k2y.y, lp1 + k2w.y) - lse2_2(lp0 + k2x.y, lp1 + k2z.y);
        orow[511 + 2 * lane + 128 * q]     = sigmoid2(2.f * e9[q][0] + da9[q][0] + db9[q][0]);
        orow[511 + 2 * lane + 128 * q + 1] = sigmoid2(2.f * e9[q][1] + da9[q][1] + db9[q][1]);
    }

    // ================= DOWN: 9 -> 10 (leaves, in-lane parents) =========
#pragma unroll
    for (int q = 0; q < 4; ++q) {
        const int bi = 1024 + 4 * lane + 256 * q;
        float4 k4x = *(const float4*)(pkx + bi);
        float4 k4y = *(const float4*)(pky + bi);
        float4 k4z = *(const float4*)(pkz + bi);
        float4 k4w = *(const float4*)(pkw + bi);
        float xr[4] = {k4x.x, k4x.y, k4x.z, k4x.w};
        float yr[4] = {k4y.x, k4y.y, k4y.z, k4y.w};
        float zr[4] = {k4z.x, k4z.y, k4z.z, k4z.w};
        float wr4[4] = {k4w.x, k4w.y, k4w.z, k4w.w};
#pragma unroll
        for (int r = 0; r < 4; ++r) {
            const float pe = e9[q][r >> 1], pdb = db9[q][r >> 1];
            float db = lse2_2(-pe + yr[r], pe + pdb + wr4[r])
                     - lse2_2(-pe + xr[r], pe + pdb + zr[r]);
            orow[1023 + 4 * lane + 256 * q + r] = sigmoid2(2.f * el[q][r] + db);
        }
    }
}

// ---------------------------------------------------------------------------
// Fallback CRF (block-per-row, LDS, raw pairs, in-place on d_out)
// ---------------------------------------------------------------------------
__global__ __launch_bounds__(64) void crf_fallback_kernel(
    const float* __restrict__ pairs, float* __restrict__ eo)
{
    __shared__ float se[C_DIM];
    __shared__ float da[1023];
    __shared__ float P0[1024];
    __shared__ float P1[1024];

    const int row  = blockIdx.x;
    const int lane = threadIdx.x;
    float* erow = eo + (size_t)row * C_DIM;

    for (int c = lane; c < C_DIM; c += 64) se[c] = erow[c] * LOG2E;
    __syncthreads();

    float* cur = P0; float* nxt = P1;
    for (int l = DEPTH - 1; l >= 1; --l) {
        const int np = 1 << (l - 1);
        const int pg0 = np - 1;
        const bool leaf = (l == DEPTH - 1);
        for (int i = lane; i < np; i += 64) {
            const int p = pg0 + i;
            float a0 = 0.f, a1 = 0.f;
#pragma unroll
            for (int s = 0; s < 2; ++s) {
                const int c = 2 * p + 1 + s;
                const int jc = 2 * i + s;
                float ca0 = 0.f, ca1 = 0.f;
                if (!leaf) { ca0 = cur[jc * 2]; ca1 = cur[jc * 2 + 1]; }
                const float l0 = -se[c] + ca0;
                const float l1 =  se[c] + ca1;
                float4 pe = *(const float4*)(pairs + ((size_t)p * C_DIM + c) * 4);
                pe.x *= LOG2E; pe.y *= LOG2E; pe.z *= LOG2E; pe.w *= LOG2E;
                a0 += lse2_2(pe.x + l0, pe.y + l1);
                a1 += lse2_2(pe.z + l0, pe.w + l1);
            }
            nxt[i * 2] = a0; nxt[i * 2 + 1] = a1;
            da[p] = a1 - a0;
        }
        __syncthreads();
        float* t = cur; cur = nxt; nxt = t;
    }
    if (lane == 0) erow[0] = sigmoid2(2.f * se[0] + da[0]);

    float* bcur = P0; float* bnxt = P1;
    for (int l = 1; l <= DEPTH - 1; ++l) {
        const int nc = 1 << l;
        const int cg0 = nc - 1;
        const bool top = (l == 1), last = (l == DEPTH - 1);
        for (int j = lane; j < nc; j += 64) {
            const int c = cg0 + j;
            const int p = (c - 1) >> 1;
            const int ip = j >> 1;
            float b0 = 0.f, b1 = 0.f;
            if (!top) { b0 = bcur[ip * 2]; b1 = bcur[ip * 2 + 1]; }
            const float lp0 = -se[p] + b0;
            const float lp1 =  se[p] + b1;
            float4 pe = *(const float4*)(pairs + ((size_t)p * C_DIM + c) * 4);
            pe.x *= LOG2E; pe.y *= LOG2E; pe.z *= LOG2E; pe.w *= LOG2E;
            const float bc0 = lse2_2(lp0 + pe.x, lp1 + pe.z);
            const float bc1 = lse2_2(lp0 + pe.y, lp1 + pe.w);
            if (!last) { bnxt[j * 2] = bc0; bnxt[j * 2 + 1] = bc1; }
            float d = 2.f * se[c] + (bc1 - bc0);
            if (c < 1023) d += da[c];
            erow[c] = sigmoid2(d);
        }
        __syncthreads();
        float* t = bcur; bcur = bnxt; bnxt = t;
    }
}

// ---------------------------------------------------------------------------
extern "C" void kernel_launch(void* const* d_in, const int* in_sizes, int n_in,
                              void* d_out, int out_size, void* d_ws, size_t ws_size,
                              hipStream_t stream) {
    const float* x     = (const float*)d_in[0];
    const float* w     = (const float*)d_in[1];
    const float* bias  = (const float*)d_in[2];
    const float* pairs = (const float*)d_in[3];
    float* out = (float*)d_out;

    // ws layout: xb | wb | pk (SoA 4 planes) | eb (padded emissions)
    unsigned short* xb = (unsigned short*)d_ws;
    unsigned short* wb = xb + (size_t)XTOT;
    float* pkbuf = (float*)(wb + (size_t)WTOT);
    float* ebuf  = pkbuf + 4 * 2048;

    const size_t need = (size_t)(XTOT + WTOT) * 2 + (size_t)4 * 2048 * 4
                      + ((size_t)B_DIM * C_PAD + C_PAD) * 4;   // ~44.2 MiB

    if (ws_size >= need) {
        cvt_kernel<<<(XTOT + WTOT) / (256 * 4), 256, 0, stream>>>(x, w, xb, wb);
        pack_kernel<<<C_PAD / 256, 256, 0, stream>>>(pairs, pkbuf);
        dim3 ggrid(C_PAD / 128, B_DIM / 128);
        gemm_bf16_kernel<<<ggrid, 256, 0, stream>>>(xb, wb, bias, ebuf);
        crf_wave_kernel<<<B_DIM / 4, 256, 0, stream>>>(pkbuf, ebuf, out);
    } else {
        dim3 ggrid((C_DIM + BNF - 1) / BNF, B_DIM / BMF);
        gemm_f32_kernel<<<ggrid, 256, 0, stream>>>(x, w, bias, out);
        crf_fallback_kernel<<<B_DIM, 64, 0, stream>>>(pairs, out);
    }
}

// Round 9
// 65.374 us; speedup vs baseline: 2.4389x; 1.0461x over previous
//
#include <hip/hip_runtime.h>
#include <math.h>

// Problem dims (fixed by the reference)
#define B_DIM 4096
#define F_DIM 1024
#define C_DIM 2047
#define C_PAD 2048
#define DEPTH 11

#define LOG2E 1.4426950408889634f

typedef __attribute__((ext_vector_type(8))) short bf16x8;
typedef __attribute__((ext_vector_type(4))) float f32x4;

#define AS1(p) ((const __attribute__((address_space(1))) void*)(p))
#define AS3(p) ((__attribute__((address_space(3))) void*)(p))

#define XTOT (B_DIM * F_DIM)          // 4194304
#define WTOT (C_PAD * F_DIM)          // 2097152

// ---------------------------------------------------------------------------
// bf16 helpers (RNE)
// ---------------------------------------------------------------------------
__device__ __forceinline__ unsigned short f2bf(float f) {
    unsigned int u = __float_as_uint(f);
    unsigned int r = (u + 0x7fffu + ((u >> 16) & 1u)) >> 16;
    return (unsigned short)r;
}
__device__ __forceinline__ float bf2f(unsigned short u) {
    return __uint_as_float(((unsigned int)u) << 16);
}

// ---------------------------------------------------------------------------
// Fused convert + pack:
//   x (B,F) f32 -> xb bf16 ; w (C,F) f32 -> wb bf16 (padded to C_PAD rows)
//   pairs tree edges -> pk SoA [4][2048], +1-shifted, * LOG2E
// ---------------------------------------------------------------------------
__global__ __launch_bounds__(256) void cvt_pack_kernel(
    const float* __restrict__ x, const float* __restrict__ w,
    const float* __restrict__ pairs,
    unsigned short* __restrict__ xb, unsigned short* __restrict__ wb,
    float* __restrict__ pk)
{
    const int i = (blockIdx.x * 256 + threadIdx.x) * 4;
    if (i < XTOT) {
        float4 v = *(const float4*)(x + i);
        ushort4 h;
        h.x = f2bf(v.x); h.y = f2bf(v.y); h.z = f2bf(v.z); h.w = f2bf(v.w);
        *(ushort4*)(xb + i) = h;
    } else if (i < XTOT + WTOT) {
        const int j = i - XTOT;                    // < WTOT
        const int row = j >> 10;                   // F = 1024
        ushort4 h = {0, 0, 0, 0};
        if (row < C_DIM) {
            float4 v = *(const float4*)(w + j);
            h.x = f2bf(v.x); h.y = f2bf(v.y); h.z = f2bf(v.z); h.w = f2bf(v.w);
        }
        *(ushort4*)(wb + j) = h;
    } else {
        const int c0 = i - XTOT - WTOT;            // 0..2044 step 4
#pragma unroll
        for (int t = 0; t < 4; ++t) {
            const int c = c0 + t;
            if (c >= 1 && c < C_DIM) {
                const int p = (c - 1) >> 1;
                float4 v = *(const float4*)(pairs + ((size_t)p * C_DIM + c) * 4);
                pk[c + 1]        = v.x * LOG2E;
                pk[c + 1 + 2048] = v.y * LOG2E;
                pk[c + 1 + 4096] = v.z * LOG2E;
                pk[c + 1 + 6144] = v.w * LOG2E;
            }
        }
    }
}

// ---------------------------------------------------------------------------
// MFMA GEMM: eb[r*2048 + c + 1] = bf16(x @ W^T + bias)[r,c]  (padded, +1).
// 128x128 tile, BK=32, 256 threads (4 waves 2x2), 16x16x32 bf16 MFMA,
// global_load_lds width-16 staging; conflict-free chunk swizzle s(row)=(row>>1)&3.
// XCD-aware block swizzle (nwg=512, bijective).
// ---------------------------------------------------------------------------
__global__ __launch_bounds__(256) void gemm_bf16_kernel(
    const unsigned short* __restrict__ xb, const unsigned short* __restrict__ wb,
    const float* __restrict__ bias, unsigned short* __restrict__ eb)
{
    __shared__ unsigned short smemA[128 * 32];  // [row][k] 64B rows
    __shared__ unsigned short smemB[128 * 32];

    const int tid  = threadIdx.x;
    const int lane = tid & 63;
    const int wave = tid >> 6;
    const int wr = wave >> 1, wc = wave & 1;

    const int lin = blockIdx.x + blockIdx.y * gridDim.x;   // 0..511
    const int wg  = (lin & 7) * 64 + (lin >> 3);
    const int bn = wg & 15, bm = wg >> 4;

    f32x4 acc[4][4] = {};
    const int r0 = tid >> 2,         c0 = tid & 3;
    const int r1 = (tid + 256) >> 2, c1 = tid & 3;
    const int sc0 = ((c0 ^ ((r0 >> 1) & 3)) << 3);
    const int sc1 = ((c1 ^ ((r1 >> 1) & 3)) << 3);

    const size_t arow0 = (size_t)(bm * 128 + r0) * F_DIM;
    const size_t arow1 = (size_t)(bm * 128 + r1) * F_DIM;
    const size_t brow0 = (size_t)(bn * 128 + r0) * F_DIM;
    const size_t brow1 = (size_t)(bn * 128 + r1) * F_DIM;

    unsigned short* ldsA0 = smemA + wave * 512;
    unsigned short* ldsA1 = smemA + 2048 + wave * 512;
    unsigned short* ldsB0 = smemB + wave * 512;
    unsigned short* ldsB1 = smemB + 2048 + wave * 512;

    const int fra = wr * 64 + (lane & 15);
    const int frb = wc * 64 + (lane & 15);
    const int kc  = lane >> 4;

    for (int k0 = 0; k0 < F_DIM; k0 += 32) {
        __builtin_amdgcn_global_load_lds(AS1(xb + arow0 + k0 + sc0), AS3(ldsA0), 16, 0, 0);
        __builtin_amdgcn_global_load_lds(AS1(xb + arow1 + k0 + sc1), AS3(ldsA1), 16, 0, 0);
        __builtin_amdgcn_global_load_lds(AS1(wb + brow0 + k0 + sc0), AS3(ldsB0), 16, 0, 0);
        __builtin_amdgcn_global_load_lds(AS1(wb + brow1 + k0 + sc1), AS3(ldsB1), 16, 0, 0);
        __syncthreads();

        bf16x8 af[4], bfr[4];
#pragma unroll
        for (int m = 0; m < 4; ++m) {
            const int row = fra + m * 16;
            af[m] = *(const bf16x8*)(smemA + row * 32 + ((kc ^ ((row >> 1) & 3)) << 3));
        }
#pragma unroll
        for (int n = 0; n < 4; ++n) {
            const int row = frb + n * 16;
            bfr[n] = *(const bf16x8*)(smemB + row * 32 + ((kc ^ ((row >> 1) & 3)) << 3));
        }
#pragma unroll
        for (int m = 0; m < 4; ++m)
#pragma unroll
            for (int n = 0; n < 4; ++n)
                acc[m][n] = __builtin_amdgcn_mfma_f32_16x16x32_bf16(
                    af[m], bfr[n], acc[m][n], 0, 0, 0);
        __syncthreads();
    }

    const int colbase = bn * 128 + wc * 64 + (lane & 15);
    const int rowbase = bm * 128 + wr * 64 + ((lane >> 4) << 2);
#pragma unroll
    for (int m = 0; m < 4; ++m)
#pragma unroll
        for (int n = 0; n < 4; ++n) {
            const int gc = colbase + n * 16;
            if (gc < C_DIM) {
                const float bv = bias[gc];
#pragma unroll
                for (int r = 0; r < 4; ++r)
                    eb[(size_t)(rowbase + m * 16 + r) * C_PAD + gc + 1] =
                        f2bf(acc[m][n][r] + bv);
            }
        }
}

// ---------------------------------------------------------------------------
// Fallback f32 GEMM (only if ws too small) — writes d_out directly
// ---------------------------------------------------------------------------
#define BMF 64
#define BNF 64
#define BKF 16

__global__ __launch_bounds__(256) void gemm_f32_kernel(
    const float* __restrict__ x, const float* __restrict__ w,
    const float* __restrict__ bias, float* __restrict__ e)
{
    __shared__ float As[BKF][BMF];
    __shared__ float Bs[BKF][BNF];
    const int bn = blockIdx.x, bm = blockIdx.y;
    const int tid = threadIdx.x;
    const int tx = tid & 15, ty = tid >> 4;
    const int m0 = ty * 4, n0 = tx * 4;
    const int lrow = tid >> 2, lc4 = (tid & 3) * 4;
    const int gm = bm * BMF + lrow;
    const int gn = bn * BNF + lrow;
    const bool wvalid = (gn < C_DIM);
    const float* xp = x + (size_t)gm * F_DIM + lc4;
    const float* wp = wvalid ? (w + (size_t)gn * F_DIM + lc4) : w;
    float acc[4][4] = {};
    for (int k0 = 0; k0 < F_DIM; k0 += BKF) {
        float4 av = *(const float4*)(xp + k0);
        float4 bv = make_float4(0.f, 0.f, 0.f, 0.f);
        if (wvalid) bv = *(const float4*)(wp + k0);
        As[lc4 + 0][lrow] = av.x; As[lc4 + 1][lrow] = av.y;
        As[lc4 + 2][lrow] = av.z; As[lc4 + 3][lrow] = av.w;
        Bs[lc4 + 0][lrow] = bv.x; Bs[lc4 + 1][lrow] = bv.y;
        Bs[lc4 + 2][lrow] = bv.z; Bs[lc4 + 3][lrow] = bv.w;
        __syncthreads();
#pragma unroll
        for (int k = 0; k < BKF; ++k) {
            float4 a = *(const float4*)&As[k][m0];
            float4 b = *(const float4*)&Bs[k][n0];
            acc[0][0] += a.x * b.x; acc[0][1] += a.x * b.y; acc[0][2] += a.x * b.z; acc[0][3] += a.x * b.w;
            acc[1][0] += a.y * b.x; acc[1][1] += a.y * b.y; acc[1][2] += a.y * b.z; acc[1][3] += a.y * b.w;
            acc[2][0] += a.z * b.x; acc[2][1] += a.z * b.y; acc[2][2] += a.z * b.z; acc[2][3] += a.z * b.w;
            acc[3][0] += a.w * b.x; acc[3][1] += a.w * b.y; acc[3][2] += a.w * b.z; acc[3][3] += a.w * b.w;
        }
        __syncthreads();
    }
    const int gmo = bm * BMF + m0, gno = bn * BNF + n0;
#pragma unroll
    for (int i = 0; i < 4; ++i)
#pragma unroll
        for (int j = 0; j < 4; ++j) {
            int n = gno + j;
            if (n < C_DIM) e[(size_t)(gmo + i) * C_DIM + n] = acc[i][j] + bias[n];
        }
}

// ---------------------------------------------------------------------------
// Tree-CRF, barrier-free, interleaved lane ownership, ILP-2:
// each wave processes TWO rows; pk loads (identical across rows) are loaded
// once and used for both rows. All emission/pk loads coalesced (as round 8).
// ---------------------------------------------------------------------------
__device__ __forceinline__ float lse2_2(float a, float b) {
    float m = fmaxf(a, b);
    return m + __log2f(1.f + exp2f(fminf(a, b) - m));
}
__device__ __forceinline__ float sigmoid2(float d) {
    return __builtin_amdgcn_rcpf(1.f + exp2f(-d));
}

__global__ __launch_bounds__(256) void crf_wave_kernel(
    const float* __restrict__ pk,          // SoA [4][2048], +1 shifted, *LOG2E
    const unsigned short* __restrict__ eb, // (B, C_PAD) bf16 emissions, +1 shift
    float* __restrict__ out)               // (B, C_DIM) probabilities
{
    const int lane = threadIdx.x & 63;
    const int wid  = blockIdx.x * 4 + (threadIdx.x >> 6);
    const unsigned short* ebr[2] = {eb + (size_t)(2 * wid) * C_PAD,
                                    eb + (size_t)(2 * wid + 1) * C_PAD};
    float* orow[2] = {out + (size_t)(2 * wid) * C_DIM,
                      out + (size_t)(2 * wid + 1) * C_DIM};
    const float* pkx = pk;
    const float* pky = pk + 2048;
    const float* pkz = pk + 4096;
    const float* pkw = pk + 6144;

    // ================= UP: leaves (level 10) =================
    float el[2][4][4], da9[2][4][2];
#pragma unroll
    for (int q = 0; q < 4; ++q) {
        const int bi = 1024 + 4 * lane + 256 * q;
        float4 k4x = *(const float4*)(pkx + bi);
        float4 k4y = *(const float4*)(pky + bi);
        float4 k4z = *(const float4*)(pkz + bi);
        float4 k4w = *(const float4*)(pkw + bi);
        float xr[4] = {k4x.x, k4x.y, k4x.z, k4x.w};
        float yr[4] = {k4y.x, k4y.y, k4y.z, k4y.w};
        float zr[4] = {k4z.x, k4z.y, k4z.z, k4z.w};
        float wr4[4] = {k4w.x, k4w.y, k4w.z, k4w.w};
#pragma unroll
        for (int rr = 0; rr < 2; ++rr) {
            ushort4 ev = *(const ushort4*)(ebr[rr] + bi);
            float er[4] = {bf2f(ev.x) * LOG2E, bf2f(ev.y) * LOG2E,
                           bf2f(ev.z) * LOG2E, bf2f(ev.w) * LOG2E};
            float dm[4];
#pragma unroll
            for (int r = 0; r < 4; ++r) {
                el[rr][q][r] = er[r];
                dm[r] = lse2_2(zr[r] - er[r], wr4[r] + er[r])
                      - lse2_2(xr[r] - er[r], yr[r] + er[r]);
            }
            da9[rr][q][0] = dm[0] + dm[1];
            da9[rr][q][1] = dm[2] + dm[3];
        }
    }

    // ================= UP: level 9 =================
    float e9[2][4][2], da8[2][4];
#pragma unroll
    for (int q = 0; q < 4; ++q) {
        const int bi = 512 + 2 * lane + 128 * q;
        float2 k2x = *(const float2*)(pkx + bi);
        float2 k2y = *(const float2*)(pky + bi);
        float2 k2z = *(const float2*)(pkz + bi);
        float2 k2w = *(const float2*)(pkw + bi);
#pragma unroll
        for (int rr = 0; rr < 2; ++rr) {
            ushort2 ev = *(const ushort2*)(ebr[rr] + bi);
            float e0 = bf2f(ev.x) * LOG2E, e1 = bf2f(ev.y) * LOG2E;
            e9[rr][q][0] = e0; e9[rr][q][1] = e1;
            float dm0 = lse2_2(k2z.x - e0, k2w.x + e0 + da9[rr][q][0])
                      - lse2_2(k2x.x - e0, k2y.x + e0 + da9[rr][q][0]);
            float dm1 = lse2_2(k2z.y - e1, k2w.y + e1 + da9[rr][q][1])
                      - lse2_2(k2x.y - e1, k2y.y + e1 + da9[rr][q][1]);
            da8[rr][q] = dm0 + dm1;
        }
    }

    // ================= UP: level 8 =================
    float e8[2][4], ps8[2][4];
#pragma unroll
    for (int q = 0; q < 4; ++q) {
        const int bi = 256 + lane + 64 * q;
        float kx = pkx[bi], ky = pky[bi], kz = pkz[bi], kw = pkw[bi];
#pragma unroll
        for (int rr = 0; rr < 2; ++rr) {
            float e = bf2f(ebr[rr][bi]) * LOG2E;
            e8[rr][q] = e;
            float dm = lse2_2(kz - e, kw + e + da8[rr][q])
                     - lse2_2(kx - e, ky + e + da8[rr][q]);
            ps8[rr][q] = dm + __shfl_xor(dm, 1, 64);
        }
    }
    float da7[2][2];
    {
        const int s = (2 * lane) & 63;
#pragma unroll
        for (int rr = 0; rr < 2; ++rr) {
            float t00 = __shfl(ps8[rr][0], s, 64), t01 = __shfl(ps8[rr][1], s, 64);
            float t10 = __shfl(ps8[rr][2], s, 64), t11 = __shfl(ps8[rr][3], s, 64);
            da7[rr][0] = (lane >= 32) ? t01 : t00;
            da7[rr][1] = (lane >= 32) ? t11 : t10;
        }
    }

    // ================= UP: level 7 =================
    float e7[2][2], ps7[2][2];
#pragma unroll
    for (int q = 0; q < 2; ++q) {
        const int bi = 128 + lane + 64 * q;
        float kx = pkx[bi], ky = pky[bi], kz = pkz[bi], kw = pkw[bi];
#pragma unroll
        for (int rr = 0; rr < 2; ++rr) {
            float e = bf2f(ebr[rr][bi]) * LOG2E;
            e7[rr][q] = e;
            float dm = lse2_2(kz - e, kw + e + da7[rr][q])
                     - lse2_2(kx - e, ky + e + da7[rr][q]);
            ps7[rr][q] = dm + __shfl_xor(dm, 1, 64);
        }
    }
    float da6[2];
    {
        const int s = (2 * lane) & 63;
#pragma unroll
        for (int rr = 0; rr < 2; ++rr) {
            float t0 = __shfl(ps7[rr][0], s, 64), t1 = __shfl(ps7[rr][1], s, 64);
            da6[rr] = (lane >= 32) ? t1 : t0;
        }
    }

    float e6[2], eup[2][6];
#pragma unroll
    for (int rr = 0; rr < 2; ++rr) {
        e6[rr] = bf2f(ebr[rr][64 + lane]) * LOG2E;
#pragma unroll
        for (int lvl = 0; lvl < 6; ++lvl)
            eup[rr][lvl] = bf2f(ebr[rr][(1 << lvl) + lane]) * LOG2E;
    }

    // ================= UP: shuffle levels 5..0 =================
    float daS[2][6];
    {
        float da_cur[2] = {da6[0], da6[1]};
        float e_cur[2]  = {e6[0], e6[1]};
        int cb = 64;
#pragma unroll
        for (int lvl = 5; lvl >= 0; --lvl) {
            const int idx = cb + lane;
            float kx = pkx[idx], ky = pky[idx], kz = pkz[idx], kw = pkw[idx];
#pragma unroll
            for (int rr = 0; rr < 2; ++rr) {
                float m0 = lse2_2(kx - e_cur[rr], ky + e_cur[rr] + da_cur[rr]);
                float m1 = lse2_2(kz - e_cur[rr], kw + e_cur[rr] + da_cur[rr]);
                float dm = m1 - m0;
                float da_new = __shfl(dm, (2 * lane) & 63, 64)
                             + __shfl(dm, (2 * lane + 1) & 63, 64);
                da_cur[rr] = da_new;
                e_cur[rr]  = eup[rr][lvl];
                daS[rr][lvl] = da_new;
            }
            cb = (1 << lvl);
        }
    }

    // ================= DOWN: shuffle levels 0..5 =================
    float db_cur[2] = {0.f, 0.f};
#pragma unroll
    for (int lvl = 0; lvl < 6; ++lvl) {
        const int np = 1 << lvl;
        const int idx = 2 * np + lane;
        float kx = pkx[idx], ky = pky[idx], kz = pkz[idx], kw = pkw[idx];
#pragma unroll
        for (int rr = 0; rr < 2; ++rr) {
            if (lane < np)
                orow[rr][np - 1 + lane] =
                    sigmoid2(2.f * eup[rr][lvl] + daS[rr][lvl] + db_cur[rr]);
            float pdb = __shfl(db_cur[rr], lane >> 1, 64);
            float pe  = __shfl(eup[rr][lvl], lane >> 1, 64);
            db_cur[rr] = lse2_2(-pe + ky, pe + pdb + kw)
                       - lse2_2(-pe + kx, pe + pdb + kz);
        }
    }
    float db6[2] = {db_cur[0], db_cur[1]};
#pragma unroll
    for (int rr = 0; rr < 2; ++rr)
        orow[rr][63 + lane] = sigmoid2(2.f * e6[rr] + da6[rr] + db6[rr]);

    // ================= DOWN: 6 -> 7 =================
    float db7[2][2];
#pragma unroll
    for (int q = 0; q < 2; ++q) {
        const int u = (lane >> 1) + 32 * q;
        const int bi = 128 + lane + 64 * q;
        float kx = pkx[bi], ky = pky[bi], kz = pkz[bi], kw = pkw[bi];
#pragma unroll
        for (int rr = 0; rr < 2; ++rr) {
            float pe  = __shfl(e6[rr], u, 64);
            float pdb = __shfl(db6[rr], u, 64);
            db7[rr][q] = lse2_2(-pe + ky, pe + pdb + kw)
                       - lse2_2(-pe + kx, pe + pdb + kz);
            orow[rr][127 + lane + 64 * q] =
                sigmoid2(2.f * e7[rr][q] + da7[rr][q] + db7[rr][q]);
        }
    }

    // ================= DOWN: 7 -> 8 =================
    float db8[2][4];
#pragma unroll
    for (int q = 0; q < 4; ++q) {
        const int u  = (lane >> 1) + 32 * q;
        const int sl = u & 63;
        const int bi = 256 + lane + 64 * q;
        float kx = pkx[bi], ky = pky[bi], kz = pkz[bi], kw = pkw[bi];
#pragma unroll
        for (int rr = 0; rr < 2; ++rr) {
            float pe  = __shfl(e7[rr][q >> 1], sl, 64);
            float pdb = __shfl(db7[rr][q >> 1], sl, 64);
            db8[rr][q] = lse2_2(-pe + ky, pe + pdb + kw)
                       - lse2_2(-pe + kx, pe + pdb + kz);
            orow[rr][255 + lane + 64 * q] =
                sigmoid2(2.f * e8[rr][q] + da8[rr][q] + db8[rr][q]);
        }
    }

    // ================= DOWN: 8 -> 9 (in-lane parents) =================
    float db9[2][4][2];
#pragma unroll
    for (int q = 0; q < 4; ++q) {
        const int bi = 512 + 2 * lane + 128 * q;
        float2 k2x = *(const float2*)(pkx + bi);
        float2 k2y = *(const float2*)(pky + bi);
        float2 k2z = *(const float2*)(pkz + bi);
        float2 k2w = *(const float2*)(pkw + bi);
#pragma unroll
        for (int rr = 0; rr < 2; ++rr) {
            const float lp0 = -e8[rr][q], lp1 = e8[rr][q] + db8[rr][q];
            db9[rr][q][0] = lse2_2(lp0 + k2y.x, lp1 + k2w.x)
                          - lse2_2(lp0 + k2x.x, lp1 + k2z.x);
            db9[rr][q][1] = lse2_2(lp0 + k2y.y, lp1 + k2w.y)
                          - lse2_2(lp0 + k2x.y, lp1 + k2z.y);
            orow[rr][511 + 2 * lane + 128 * q] =
                sigmoid2(2.f * e9[rr][q][0] + da9[rr][q][0] + db9[rr][q][0]);
            orow[rr][511 + 2 * lane + 128 * q + 1] =
                sigmoid2(2.f * e9[rr][q][1] + da9[rr][q][1] + db9[rr][q][1]);
        }
    }

    // ================= DOWN: 9 -> 10 (leaves, in-lane parents) =========
#pragma unroll
    for (int q = 0; q < 4; ++q) {
        const int bi = 1024 + 4 * lane + 256 * q;
        float4 k4x = *(const float4*)(pkx + bi);
        float4 k4y = *(const float4*)(pky + bi);
        float4 k4z = *(const float4*)(pkz + bi);
        float4 k4w = *(const float4*)(pkw + bi);
        float xr[4] = {k4x.x, k4x.y, k4x.z, k4x.w};
        float yr[4] = {k4y.x, k4y.y, k4y.z, k4y.w};
        float zr[4] = {k4z.x, k4z.y, k4z.z, k4z.w};
        float wr4[4] = {k4w.x, k4w.y, k4w.z, k4w.w};
#pragma unroll
        for (int rr = 0; rr < 2; ++rr) {
#pragma unroll
            for (int r = 0; r < 4; ++r) {
                const float pe = e9[rr][q][r >> 1], pdb = db9[rr][q][r >> 1];
                float db = lse2_2(-pe + yr[r], pe + pdb + wr4[r])
                         - lse2_2(-pe + xr[r], pe + pdb + zr[r]);
                orow[rr][1023 + 4 * lane + 256 * q + r] =
                    sigmoid2(2.f * el[rr][q][r] + db);
            }
        }
    }
}

// ---------------------------------------------------------------------------
// Fallback CRF (block-per-row, LDS, raw pairs, in-place on d_out)
// ---------------------------------------------------------------------------
__global__ __launch_bounds__(64) void crf_fallback_kernel(
    const float* __restrict__ pairs, float* __restrict__ eo)
{
    __shared__ float se[C_DIM];
    __shared__ float da[1023];
    __shared__ float P0[1024];
    __shared__ float P1[1024];

    const int row  = blockIdx.x;
    const int lane = threadIdx.x;
    float* erow = eo + (size_t)row * C_DIM;

    for (int c = lane; c < C_DIM; c += 64) se[c] = erow[c] * LOG2E;
    __syncthreads();

    float* cur = P0; float* nxt = P1;
    for (int l = DEPTH - 1; l >= 1; --l) {
        const int np = 1 << (l - 1);
        const int pg0 = np - 1;
        const bool leaf = (l == DEPTH - 1);
        for (int i = lane; i < np; i += 64) {
            const int p = pg0 + i;
            float a0 = 0.f, a1 = 0.f;
#pragma unroll
            for (int s = 0; s < 2; ++s) {
                const int c = 2 * p + 1 + s;
                const int jc = 2 * i + s;
                float ca0 = 0.f, ca1 = 0.f;
                if (!leaf) { ca0 = cur[jc * 2]; ca1 = cur[jc * 2 + 1]; }
                const float l0 = -se[c] + ca0;
                const float l1 =  se[c] + ca1;
                float4 pe = *(const float4*)(pairs + ((size_t)p * C_DIM + c) * 4);
                pe.x *= LOG2E; pe.y *= LOG2E; pe.z *= LOG2E; pe.w *= LOG2E;
                a0 += lse2_2(pe.x + l0, pe.y + l1);
                a1 += lse2_2(pe.z + l0, pe.w + l1);
            }
            nxt[i * 2] = a0; nxt[i * 2 + 1] = a1;
            da[p] = a1 - a0;
        }
        __syncthreads();
        float* t = cur; cur = nxt; nxt = t;
    }
    if (lane == 0) erow[0] = sigmoid2(2.f * se[0] + da[0]);

    float* bcur = P0; float* bnxt = P1;
    for (int l = 1; l <= DEPTH - 1; ++l) {
        const int nc = 1 << l;
        const int cg0 = nc - 1;
        const bool top = (l == 1), last = (l == DEPTH - 1);
        for (int j = lane; j < nc; j += 64) {
            const int c = cg0 + j;
            const int p = (c - 1) >> 1;
            const int ip = j >> 1;
            float b0 = 0.f, b1 = 0.f;
            if (!top) { b0 = bcur[ip * 2]; b1 = bcur[ip * 2 + 1]; }
            const float lp0 = -se[p] + b0;
            const float lp1 =  se[p] + b1;
            float4 pe = *(const float4*)(pairs + ((size_t)p * C_DIM + c) * 4);
            pe.x *= LOG2E; pe.y *= LOG2E; pe.z *= LOG2E; pe.w *= LOG2E;
            const float bc0 = lse2_2(lp0 + pe.x, lp1 + pe.z);
            const float bc1 = lse2_2(lp0 + pe.y, lp1 + pe.w);
            if (!last) { bnxt[j * 2] = bc0; bnxt[j * 2 + 1] = bc1; }
            float d = 2.f * se[c] + (bc1 - bc0);
            if (c < 1023) d += da[c];
            erow[c] = sigmoid2(d);
        }
        __syncthreads();
        float* t = bcur; bcur = bnxt; bnxt = t;
    }
}

// ---------------------------------------------------------------------------
extern "C" void kernel_launch(void* const* d_in, const int* in_sizes, int n_in,
                              void* d_out, int out_size, void* d_ws, size_t ws_size,
                              hipStream_t stream) {
    const float* x     = (const float*)d_in[0];
    const float* w     = (const float*)d_in[1];
    const float* bias  = (const float*)d_in[2];
    const float* pairs = (const float*)d_in[3];
    float* out = (float*)d_out;

    // ws layout: xb | wb | pk (SoA 4 planes f32) | eb (bf16 padded emissions)
    unsigned short* xb = (unsigned short*)d_ws;
    unsigned short* wb = xb + (size_t)XTOT;
    float* pkbuf = (float*)(wb + (size_t)WTOT);
    unsigned short* ebuf = (unsigned short*)(pkbuf + 4 * 2048);

    const size_t need = (size_t)(XTOT + WTOT) * 2 + (size_t)4 * 2048 * 4
                      + ((size_t)B_DIM * C_PAD + C_PAD) * 2;   // ~28.8 MiB

    if (ws_size >= need) {
        cvt_pack_kernel<<<(XTOT + WTOT + 2048) / (256 * 4), 256, 0, stream>>>(
            x, w, pairs, xb, wb, pkbuf);
        dim3 ggrid(C_PAD / 128, B_DIM / 128);
        gemm_bf16_kernel<<<ggrid, 256, 0, stream>>>(xb, wb, bias, ebuf);
        crf_wave_kernel<<<B_DIM / 8, 256, 0, stream>>>(pkbuf, ebuf, out);
    } else {
        dim3 ggrid((C_DIM + BNF - 1) / BNF, B_DIM / BMF);
        gemm_f32_kernel<<<ggrid, 256, 0, stream>>>(x, w, bias, out);
        crf_fallback_kernel<<<B_DIM, 64, 0, stream>>>(pairs, out);
    }
}

// Round 10
// 63.717 us; speedup vs baseline: 2.5023x; 1.0260x over previous
//
#include <hip/hip_runtime.h>
#include <math.h>

// Problem dims (fixed by the reference)
#define B_DIM 4096
#define F_DIM 1024
#define C_DIM 2047
#define C_PAD 2048
#define DEPTH 11

#define LOG2E 1.4426950408889634f

typedef __attribute__((ext_vector_type(8))) short bf16x8;
typedef __attribute__((ext_vector_type(4))) float f32x4;

#define AS1(p) ((const __attribute__((address_space(1))) void*)(p))
#define AS3(p) ((__attribute__((address_space(3))) void*)(p))

#define XTOT (B_DIM * F_DIM)          // 4194304
#define WTOT (C_PAD * F_DIM)          // 2097152

// ---------------------------------------------------------------------------
// bf16 helpers (RNE)
// ---------------------------------------------------------------------------
__device__ __forceinline__ unsigned short f2bf(float f) {
    unsigned int u = __float_as_uint(f);
    unsigned int r = (u + 0x7fffu + ((u >> 16) & 1u)) >> 16;
    return (unsigned short)r;
}
__device__ __forceinline__ float bf2f(unsigned short u) {
    return __uint_as_float(((unsigned int)u) << 16);
}

// ---------------------------------------------------------------------------
// Fused convert + pack:
//   x (B,F) f32 -> xb bf16 ; w (C,F) f32 -> wb bf16 (padded to C_PAD rows)
//   pairs tree edges -> pk SoA [4][2048], +1-shifted, * LOG2E
// ---------------------------------------------------------------------------
__global__ __launch_bounds__(256) void cvt_pack_kernel(
    const float* __restrict__ x, const float* __restrict__ w,
    const float* __restrict__ pairs,
    unsigned short* __restrict__ xb, unsigned short* __restrict__ wb,
    float* __restrict__ pk)
{
    const int i = (blockIdx.x * 256 + threadIdx.x) * 4;
    if (i < XTOT) {
        float4 v = *(const float4*)(x + i);
        ushort4 h;
        h.x = f2bf(v.x); h.y = f2bf(v.y); h.z = f2bf(v.z); h.w = f2bf(v.w);
        *(ushort4*)(xb + i) = h;
    } else if (i < XTOT + WTOT) {
        const int j = i - XTOT;                    // < WTOT
        const int row = j >> 10;                   // F = 1024
        ushort4 h = {0, 0, 0, 0};
        if (row < C_DIM) {
            float4 v = *(const float4*)(w + j);
            h.x = f2bf(v.x); h.y = f2bf(v.y); h.z = f2bf(v.z); h.w = f2bf(v.w);
        }
        *(ushort4*)(wb + j) = h;
    } else {
        const int c0 = i - XTOT - WTOT;            // 0..2044 step 4
#pragma unroll
        for (int t = 0; t < 4; ++t) {
            const int c = c0 + t;
            if (c >= 1 && c < C_DIM) {
                const int p = (c - 1) >> 1;
                float4 v = *(const float4*)(pairs + ((size_t)p * C_DIM + c) * 4);
                pk[c + 1]        = v.x * LOG2E;
                pk[c + 1 + 2048] = v.y * LOG2E;
                pk[c + 1 + 4096] = v.z * LOG2E;
                pk[c + 1 + 6144] = v.w * LOG2E;
            }
        }
    }
}

// ---------------------------------------------------------------------------
// MFMA GEMM, T3-minimum 2-phase pipeline:
//   eb[r*2048 + c + 1] = bf16(x @ W^T + bias)[r,c]  (padded, +1).
// 128x128 tile, K-tile = 64 (two BK=32 sub-tiles), double-buffered LDS (64KB).
// Per iteration: issue next tile's 8 global_load_lds FIRST, then 32 MFMA on
// the current buffer, then ONE barrier (compiler drains vmcnt/lgkmcnt there).
// Conflict-free chunk swizzle s(row)=(row>>1)&3 per 32-wide sub-tile.
// XCD-aware block swizzle (nwg=512, bijective).
// ---------------------------------------------------------------------------
__global__ __launch_bounds__(256) void gemm_bf16_kernel(
    const unsigned short* __restrict__ xb, const unsigned short* __restrict__ wb,
    const float* __restrict__ bias, unsigned short* __restrict__ eb)
{
    // [dbuf][mat(A,B)][ks][128 rows * 32 cols]
    __shared__ unsigned short smem[2][2][2][4096];

    const int tid  = threadIdx.x;
    const int lane = tid & 63;
    const int wave = tid >> 6;
    const int wr = wave >> 1, wc = wave & 1;

    const int lin = blockIdx.x + blockIdx.y * gridDim.x;   // 0..511
    const int wg  = (lin & 7) * 64 + (lin >> 3);
    const int bn = wg & 15, bm = wg >> 4;

    f32x4 acc[4][4] = {};

    // staging slots (per 32-wide sub-tile): slot s = tid (+256)
    const int r0 = tid >> 2,       c0 = tid & 3;
    const int r1 = 64 + (tid >> 2);
    const int sc0 = ((c0 ^ ((r0 >> 1) & 3)) << 3);   // element offset in sub-tile
    const int sc1 = ((c0 ^ ((r1 >> 1) & 3)) << 3);

    const size_t arow0 = (size_t)(bm * 128 + r0) * F_DIM;
    const size_t arow1 = (size_t)(bm * 128 + r1) * F_DIM;
    const size_t brow0 = (size_t)(bn * 128 + r0) * F_DIM;
    const size_t brow1 = (size_t)(bn * 128 + r1) * F_DIM;

    const int lb0 = wave * 512;          // issue-0 LDS base (ushort)
    const int lb1 = 2048 + wave * 512;   // issue-1 LDS base

    const int fra = wr * 64 + (lane & 15);
    const int frb = wc * 64 + (lane & 15);
    const int kc  = lane >> 4;

#define STAGE(buf, kt)                                                          \
    {                                                                           \
        const int kbase = (kt) * 64;                                            \
        _Pragma("unroll")                                                       \
        for (int ks = 0; ks < 2; ++ks) {                                        \
            const int k0 = kbase + ks * 32;                                     \
            __builtin_amdgcn_global_load_lds(AS1(xb + arow0 + k0 + sc0),        \
                AS3(&smem[buf][0][ks][lb0]), 16, 0, 0);                         \
            __builtin_amdgcn_global_load_lds(AS1(xb + arow1 + k0 + sc1),        \
                AS3(&smem[buf][0][ks][lb1]), 16, 0, 0);                         \
            __builtin_amdgcn_global_load_lds(AS1(wb + brow0 + k0 + sc0),        \
                AS3(&smem[buf][1][ks][lb0]), 16, 0, 0);                         \
            __builtin_amdgcn_global_load_lds(AS1(wb + brow1 + k0 + sc1),        \
                AS3(&smem[buf][1][ks][lb1]), 16, 0, 0);                         \
        }                                                                       \
    }

    const int NT = F_DIM / 64;   // 16
    STAGE(0, 0);
    __syncthreads();

    for (int kt = 0; kt < NT; ++kt) {
        const int cur = kt & 1;
        if (kt + 1 < NT) STAGE(cur ^ 1, kt + 1);   // issue next-tile loads FIRST

#pragma unroll
        for (int ks = 0; ks < 2; ++ks) {
            bf16x8 af[4], bfr[4];
#pragma unroll
            for (int m = 0; m < 4; ++m) {
                const int row = fra + m * 16;
                af[m] = *(const bf16x8*)(&smem[cur][0][ks]
                        [row * 32 + ((kc ^ ((row >> 1) & 3)) << 3)]);
            }
#pragma unroll
            for (int n = 0; n < 4; ++n) {
                const int row = frb + n * 16;
                bfr[n] = *(const bf16x8*)(&smem[cur][1][ks]
                        [row * 32 + ((kc ^ ((row >> 1) & 3)) << 3)]);
            }
#pragma unroll
            for (int m = 0; m < 4; ++m)
#pragma unroll
                for (int n = 0; n < 4; ++n)
                    acc[m][n] = __builtin_amdgcn_mfma_f32_16x16x32_bf16(
                        af[m], bfr[n], acc[m][n], 0, 0, 0);
        }
        __syncthreads();   // drains this iter's STAGE (vmcnt) + ds reads
    }
#undef STAGE

    const int colbase = bn * 128 + wc * 64 + (lane & 15);
    const int rowbase = bm * 128 + wr * 64 + ((lane >> 4) << 2);
#pragma unroll
    for (int m = 0; m < 4; ++m)
#pragma unroll
        for (int n = 0; n < 4; ++n) {
            const int gc = colbase + n * 16;
            if (gc < C_DIM) {
                const float bv = bias[gc];
#pragma unroll
                for (int r = 0; r < 4; ++r)
                    eb[(size_t)(rowbase + m * 16 + r) * C_PAD + gc + 1] =
                        f2bf(acc[m][n][r] + bv);
            }
        }
}

// ---------------------------------------------------------------------------
// Fallback f32 GEMM (only if ws too small) — writes d_out directly
// ---------------------------------------------------------------------------
#define BMF 64
#define BNF 64
#define BKF 16

__global__ __launch_bounds__(256) void gemm_f32_kernel(
    const float* __restrict__ x, const float* __restrict__ w,
    const float* __restrict__ bias, float* __restrict__ e)
{
    __shared__ float As[BKF][BMF];
    __shared__ float Bs[BKF][BNF];
    const int bn = blockIdx.x, bm = blockIdx.y;
    const int tid = threadIdx.x;
    const int tx = tid & 15, ty = tid >> 4;
    const int m0 = ty * 4, n0 = tx * 4;
    const int lrow = tid >> 2, lc4 = (tid & 3) * 4;
    const int gm = bm * BMF + lrow;
    const int gn = bn * BNF + lrow;
    const bool wvalid = (gn < C_DIM);
    const float* xp = x + (size_t)gm * F_DIM + lc4;
    const float* wp = wvalid ? (w + (size_t)gn * F_DIM + lc4) : w;
    float acc[4][4] = {};
    for (int k0 = 0; k0 < F_DIM; k0 += BKF) {
        float4 av = *(const float4*)(xp + k0);
        float4 bv = make_float4(0.f, 0.f, 0.f, 0.f);
        if (wvalid) bv = *(const float4*)(wp + k0);
        As[lc4 + 0][lrow] = av.x; As[lc4 + 1][lrow] = av.y;
        As[lc4 + 2][lrow] = av.z; As[lc4 + 3][lrow] = av.w;
        Bs[lc4 + 0][lrow] = bv.x; Bs[lc4 + 1][lrow] = bv.y;
        Bs[lc4 + 2][lrow] = bv.z; Bs[lc4 + 3][lrow] = bv.w;
        __syncthreads();
#pragma unroll
        for (int k = 0; k < BKF; ++k) {
            float4 a = *(const float4*)&As[k][m0];
            float4 b = *(const float4*)&Bs[k][n0];
            acc[0][0] += a.x * b.x; acc[0][1] += a.x * b.y; acc[0][2] += a.x * b.z; acc[0][3] += a.x * b.w;
            acc[1][0] += a.y * b.x; acc[1][1] += a.y * b.y; acc[1][2] += a.y * b.z; acc[1][3] += a.y * b.w;
            acc[2][0] += a.z * b.x; acc[2][1] += a.z * b.y; acc[2][2] += a.z * b.z; acc[2][3] += a.z * b.w;
            acc[3][0] += a.w * b.x; acc[3][1] += a.w * b.y; acc[3][2] += a.w * b.z; acc[3][3] += a.w * b.w;
        }
        __syncthreads();
    }
    const int gmo = bm * BMF + m0, gno = bn * BNF + n0;
#pragma unroll
    for (int i = 0; i < 4; ++i)
#pragma unroll
        for (int j = 0; j < 4; ++j) {
            int n = gno + j;
            if (n < C_DIM) e[(size_t)(gmo + i) * C_DIM + n] = acc[i][j] + bias[n];
        }
}

// ---------------------------------------------------------------------------
// Tree-CRF, barrier-free, interleaved lane ownership, ILP-2:
// each wave processes TWO rows; pk loads (identical across rows) are loaded
// once and used for both rows. All emission/pk loads coalesced.
// ---------------------------------------------------------------------------
__device__ __forceinline__ float lse2_2(float a, float b) {
    float m = fmaxf(a, b);
    return m + __log2f(1.f + exp2f(fminf(a, b) - m));
}
__device__ __forceinline__ float sigmoid2(float d) {
    return __builtin_amdgcn_rcpf(1.f + exp2f(-d));
}

__global__ __launch_bounds__(256) void crf_wave_kernel(
    const float* __restrict__ pk,          // SoA [4][2048], +1 shifted, *LOG2E
    const unsigned short* __restrict__ eb, // (B, C_PAD) bf16 emissions, +1 shift
    float* __restrict__ out)               // (B, C_DIM) probabilities
{
    const int lane = threadIdx.x & 63;
    const int wid  = blockIdx.x * 4 + (threadIdx.x >> 6);
    const unsigned short* ebr[2] = {eb + (size_t)(2 * wid) * C_PAD,
                                    eb + (size_t)(2 * wid + 1) * C_PAD};
    float* orow[2] = {out + (size_t)(2 * wid) * C_DIM,
                      out + (size_t)(2 * wid + 1) * C_DIM};
    const float* pkx = pk;
    const float* pky = pk + 2048;
    const float* pkz = pk + 4096;
    const float* pkw = pk + 6144;

    // ================= UP: leaves (level 10) =================
    float el[2][4][4], da9[2][4][2];
#pragma unroll
    for (int q = 0; q < 4; ++q) {
        const int bi = 1024 + 4 * lane + 256 * q;
        float4 k4x = *(const float4*)(pkx + bi);
        float4 k4y = *(const float4*)(pky + bi);
        float4 k4z = *(const float4*)(pkz + bi);
        float4 k4w = *(const float4*)(pkw + bi);
        float xr[4] = {k4x.x, k4x.y, k4x.z, k4x.w};
        float yr[4] = {k4y.x, k4y.y, k4y.z, k4y.w};
        float zr[4] = {k4z.x, k4z.y, k4z.z, k4z.w};
        float wr4[4] = {k4w.x, k4w.y, k4w.z, k4w.w};
#pragma unroll
        for (int rr = 0; rr < 2; ++rr) {
            ushort4 ev = *(const ushort4*)(ebr[rr] + bi);
            float er[4] = {bf2f(ev.x) * LOG2E, bf2f(ev.y) * LOG2E,
                           bf2f(ev.z) * LOG2E, bf2f(ev.w) * LOG2E};
            float dm[4];
#pragma unroll
            for (int r = 0; r < 4; ++r) {
                el[rr][q][r] = er[r];
                dm[r] = lse2_2(zr[r] - er[r], wr4[r] + er[r])
                      - lse2_2(xr[r] - er[r], yr[r] + er[r]);
            }
            da9[rr][q][0] = dm[0] + dm[1];
            da9[rr][q][1] = dm[2] + dm[3];
        }
    }

    // ================= UP: level 9 =================
    float e9[2][4][2], da8[2][4];
#pragma unroll
    for (int q = 0; q < 4; ++q) {
        const int bi = 512 + 2 * lane + 128 * q;
        float2 k2x = *(const float2*)(pkx + bi);
        float2 k2y = *(const float2*)(pky + bi);
        float2 k2z = *(const float2*)(pkz + bi);
        float2 k2w = *(const float2*)(pkw + bi);
#pragma unroll
        for (int rr = 0; rr < 2; ++rr) {
            ushort2 ev = *(const ushort2*)(ebr[rr] + bi);
            float e0 = bf2f(ev.x) * LOG2E, e1 = bf2f(ev.y) * LOG2E;
            e9[rr][q][0] = e0; e9[rr][q][1] = e1;
            float dm0 = lse2_2(k2z.x - e0, k2w.x + e0 + da9[rr][q][0])
                      - lse2_2(k2x.x - e0, k2y.x + e0 + da9[rr][q][0]);
            float dm1 = lse2_2(k2z.y - e1, k2w.y + e1 + da9[rr][q][1])
                      - lse2_2(k2x.y - e1, k2y.y + e1 + da9[rr][q][1]);
            da8[rr][q] = dm0 + dm1;
        }
    }

    // ================= UP: level 8 =================
    float e8[2][4], ps8[2][4];
#pragma unroll
    for (int q = 0; q < 4; ++q) {
        const int bi = 256 + lane + 64 * q;
        float kx = pkx[bi], ky = pky[bi], kz = pkz[bi], kw = pkw[bi];
#pragma unroll
        for (int rr = 0; rr < 2; ++rr) {
            float e = bf2f(ebr[rr][bi]) * LOG2E;
            e8[rr][q] = e;
            float dm = lse2_2(kz - e, kw + e + da8[rr][q])
                     - lse2_2(kx - e, ky + e + da8[rr][q]);
            ps8[rr][q] = dm + __shfl_xor(dm, 1, 64);
        }
    }
    float da7[2][2];
    {
        const int s = (2 * lane) & 63;
#pragma unroll
        for (int rr = 0; rr < 2; ++rr) {
            float t00 = __shfl(ps8[rr][0], s, 64), t01 = __shfl(ps8[rr][1], s, 64);
            float t10 = __shfl(ps8[rr][2], s, 64), t11 = __shfl(ps8[rr][3], s, 64);
            da7[rr][0] = (lane >= 32) ? t01 : t00;
            da7[rr][1] = (lane >= 32) ? t11 : t10;
        }
    }

    // ================= UP: level 7 =================
    float e7[2][2], ps7[2][2];
#pragma unroll
    for (int q = 0; q < 2; ++q) {
        const int bi = 128 + lane + 64 * q;
        float kx = pkx[bi], ky = pky[bi], kz = pkz[bi], kw = pkw[bi];
#pragma unroll
        for (int rr = 0; rr < 2; ++rr) {
            float e = bf2f(ebr[rr][bi]) * LOG2E;
            e7[rr][q] = e;
            float dm = lse2_2(kz - e, kw + e + da7[rr][q])
                     - lse2_2(kx - e, ky + e + da7[rr][q]);
            ps7[rr][q] = dm + __shfl_xor(dm, 1, 64);
        }
    }
    float da6[2];
    {
        const int s = (2 * lane) & 63;
#pragma unroll
        for (int rr = 0; rr < 2; ++rr) {
            float t0 = __shfl(ps7[rr][0], s, 64), t1 = __shfl(ps7[rr][1], s, 64);
            da6[rr] = (lane >= 32) ? t1 : t0;
        }
    }

    float e6[2], eup[2][6];
#pragma unroll
    for (int rr = 0; rr < 2; ++rr) {
        e6[rr] = bf2f(ebr[rr][64 + lane]) * LOG2E;
#pragma unroll
        for (int lvl = 0; lvl < 6; ++lvl)
            eup[rr][lvl] = bf2f(ebr[rr][(1 << lvl) + lane]) * LOG2E;
    }

    // ================= UP: shuffle levels 5..0 =================
    float daS[2][6];
    {
        float da_cur[2] = {da6[0], da6[1]};
        float e_cur[2]  = {e6[0], e6[1]};
        int cb = 64;
#pragma unroll
        for (int lvl = 5; lvl >= 0; --lvl) {
            const int idx = cb + lane;
            float kx = pkx[idx], ky = pky[idx], kz = pkz[idx], kw = pkw[idx];
#pragma unroll
            for (int rr = 0; rr < 2; ++rr) {
                float m0 = lse2_2(kx - e_cur[rr], ky + e_cur[rr] + da_cur[rr]);
                float m1 = lse2_2(kz - e_cur[rr], kw + e_cur[rr] + da_cur[rr]);
                float dm = m1 - m0;
                float da_new = __shfl(dm, (2 * lane) & 63, 64)
                             + __shfl(dm, (2 * lane + 1) & 63, 64);
                da_cur[rr] = da_new;
                e_cur[rr]  = eup[rr][lvl];
                daS[rr][lvl] = da_new;
            }
            cb = (1 << lvl);
        }
    }

    // ================= DOWN: shuffle levels 0..5 =================
    float db_cur[2] = {0.f, 0.f};
#pragma unroll
    for (int lvl = 0; lvl < 6; ++lvl) {
        const int np = 1 << lvl;
        const int idx = 2 * np + lane;
        float kx = pkx[idx], ky = pky[idx], kz = pkz[idx], kw = pkw[idx];
#pragma unroll
        for (int rr = 0; rr < 2; ++rr) {
            if (lane < np)
                orow[rr][np - 1 + lane] =
                    sigmoid2(2.f * eup[rr][lvl] + daS[rr][lvl] + db_cur[rr]);
            float pdb = __shfl(db_cur[rr], lane >> 1, 64);
            float pe  = __shfl(eup[rr][lvl], lane >> 1, 64);
            db_cur[rr] = lse2_2(-pe + ky, pe + pdb + kw)
                       - lse2_2(-pe + kx, pe + pdb + kz);
        }
    }
    float db6[2] = {db_cur[0], db_cur[1]};
#pragma unroll
    for (int rr = 0; rr < 2; ++rr)
        orow[rr][63 + lane] = sigmoid2(2.f * e6[rr] + da6[rr] + db6[rr]);

    // ================= DOWN: 6 -> 7 =================
    float db7[2][2];
#pragma unroll
    for (int q = 0; q < 2; ++q) {
        const int u = (lane >> 1) + 32 * q;
        const int bi = 128 + lane + 64 * q;
        float kx = pkx[bi], ky = pky[bi], kz = pkz[bi], kw = pkw[bi];
#pragma unroll
        for (int rr = 0; rr < 2; ++rr) {
            float pe  = __shfl(e6[rr], u, 64);
            float pdb = __shfl(db6[rr], u, 64);
            db7[rr][q] = lse2_2(-pe + ky, pe + pdb + kw)
                       - lse2_2(-pe + kx, pe + pdb + kz);
            orow[rr][127 + lane + 64 * q] =
                sigmoid2(2.f * e7[rr][q] + da7[rr][q] + db7[rr][q]);
        }
    }

    // ================= DOWN: 7 -> 8 =================
    float db8[2][4];
#pragma unroll
    for (int q = 0; q < 4; ++q) {
        const int u  = (lane >> 1) + 32 * q;
        const int sl = u & 63;
        const int bi = 256 + lane + 64 * q;
        float kx = pkx[bi], ky = pky[bi], kz = pkz[bi], kw = pkw[bi];
#pragma unroll
        for (int rr = 0; rr < 2; ++rr) {
            float pe  = __shfl(e7[rr][q >> 1], sl, 64);
            float pdb = __shfl(db7[rr][q >> 1], sl, 64);
            db8[rr][q] = lse2_2(-pe + ky, pe + pdb + kw)
                       - lse2_2(-pe + kx, pe + pdb + kz);
            orow[rr][255 + lane + 64 * q] =
                sigmoid2(2.f * e8[rr][q] + da8[rr][q] + db8[rr][q]);
        }
    }

    // ================= DOWN: 8 -> 9 (in-lane parents) =================
    float db9[2][4][2];
#pragma unroll
    for (int q = 0; q < 4; ++q) {
        const int bi = 512 + 2 * lane + 128 * q;
        float2 k2x = *(const float2*)(pkx + bi);
        float2 k2y = *(const float2*)(pky + bi);
        float2 k2z = *(const float2*)(pkz + bi);
        float2 k2w = *(const float2*)(pkw + bi);
#pragma unroll
        for (int rr = 0; rr < 2; ++rr) {
            const float lp0 = -e8[rr][q], lp1 = e8[rr][q] + db8[rr][q];
            db9[rr][q][0] = lse2_2(lp0 + k2y.x, lp1 + k2w.x)
                          - lse2_2(lp0 + k2x.x, lp1 + k2z.x);
            db9[rr][q][1] = lse2_2(lp0 + k2y.y, lp1 + k2w.y)
                          - lse2_2(lp0 + k2x.y, lp1 + k2z.y);
            orow[rr][511 + 2 * lane + 128 * q] =
                sigmoid2(2.f * e9[rr][q][0] + da9[rr][q][0] + db9[rr][q][0]);
            orow[rr][511 + 2 * lane + 128 * q + 1] =
                sigmoid2(2.f * e9[rr][q][1] + da9[rr][q][1] + db9[rr][q][1]);
        }
    }

    // ================= DOWN: 9 -> 10 (leaves, in-lane parents) =========
#pragma unroll
    for (int q = 0; q < 4; ++q) {
        const int bi = 1024 + 4 * lane + 256 * q;
        float4 k4x = *(const float4*)(pkx + bi);
        float4 k4y = *(const float4*)(pky + bi);
        float4 k4z = *(const float4*)(pkz + bi);
        float4 k4w = *(const float4*)(pkw + bi);
        float xr[4] = {k4x.x, k4x.y, k4x.z, k4x.w};
        float yr[4] = {k4y.x, k4y.y, k4y.z, k4y.w};
        float zr[4] = {k4z.x, k4z.y, k4z.z, k4z.w};
        float wr4[4] = {k4w.x, k4w.y, k4w.z, k4w.w};
#pragma unroll
        for (int rr = 0; rr < 2; ++rr) {
#pragma unroll
            for (int r = 0; r < 4; ++r) {
                const float pe = e9[rr][q][r >> 1], pdb = db9[rr][q][r >> 1];
                float db = lse2_2(-pe + yr[r], pe + pdb + wr4[r])
                         - lse2_2(-pe + xr[r], pe + pdb + zr[r]);
                orow[rr][1023 + 4 * lane + 256 * q + r] =
                    sigmoid2(2.f * el[rr][q][r] + db);
            }
        }
    }
}

// ---------------------------------------------------------------------------
// Fallback CRF (block-per-row, LDS, raw pairs, in-place on d_out)
// ---------------------------------------------------------------------------
__global__ __launch_bounds__(64) void crf_fallback_kernel(
    const float* __restrict__ pairs, float* __restrict__ eo)
{
    __shared__ float se[C_DIM];
    __shared__ float da[1023];
    __shared__ float P0[1024];
    __shared__ float P1[1024];

    const int row  = blockIdx.x;
    const int lane = threadIdx.x;
    float* erow = eo + (size_t)row * C_DIM;

    for (int c = lane; c < C_DIM; c += 64) se[c] = erow[c] * LOG2E;
    __syncthreads();

    float* cur = P0; float* nxt = P1;
    for (int l = DEPTH - 1; l >= 1; --l) {
        const int np = 1 << (l - 1);
        const int pg0 = np - 1;
        const bool leaf = (l == DEPTH - 1);
        for (int i = lane; i < np; i += 64) {
            const int p = pg0 + i;
            float a0 = 0.f, a1 = 0.f;
#pragma unroll
            for (int s = 0; s < 2; ++s) {
                const int c = 2 * p + 1 + s;
                const int jc = 2 * i + s;
                float ca0 = 0.f, ca1 = 0.f;
                if (!leaf) { ca0 = cur[jc * 2]; ca1 = cur[jc * 2 + 1]; }
                const float l0 = -se[c] + ca0;
                const float l1 =  se[c] + ca1;
                float4 pe = *(const float4*)(pairs + ((size_t)p * C_DIM + c) * 4);
                pe.x *= LOG2E; pe.y *= LOG2E; pe.z *= LOG2E; pe.w *= LOG2E;
                a0 += lse2_2(pe.x + l0, pe.y + l1);
                a1 += lse2_2(pe.z + l0, pe.w + l1);
            }
            nxt[i * 2] = a0; nxt[i * 2 + 1] = a1;
            da[p] = a1 - a0;
        }
        __syncthreads();
        float* t = cur; cur = nxt; nxt = t;
    }
    if (lane == 0) erow[0] = sigmoid2(2.f * se[0] + da[0]);

    float* bcur = P0; float* bnxt = P1;
    for (int l = 1; l <= DEPTH - 1; ++l) {
        const int nc = 1 << l;
        const int cg0 = nc - 1;
        const bool top = (l == 1), last = (l == DEPTH - 1);
        for (int j = lane; j < nc; j += 64) {
            const int c = cg0 + j;
            const int p = (c - 1) >> 1;
            const int ip = j >> 1;
            float b0 = 0.f, b1 = 0.f;
            if (!top) { b0 = bcur[ip * 2]; b1 = bcur[ip * 2 + 1]; }
            const float lp0 = -se[p] + b0;
            const float lp1 =  se[p] + b1;
            float4 pe = *(const float4*)(pairs + ((size_t)p * C_DIM + c) * 4);
            pe.x *= LOG2E; pe.y *= LOG2E; pe.z *= LOG2E; pe.w *= LOG2E;
            const float bc0 = lse2_2(lp0 + pe.x, lp1 + pe.z);
            const float bc1 = lse2_2(lp0 + pe.y, lp1 + pe.w);
            if (!last) { bnxt[j * 2] = bc0; bnxt[j * 2 + 1] = bc1; }
            float d = 2.f * se[c] + (bc1 - bc0);
            if (c < 1023) d += da[c];
            erow[c] = sigmoid2(d);
        }
        __syncthreads();
        float* t = bcur; bcur = bnxt; bnxt = t;
    }
}

// ---------------------------------------------------------------------------
extern "C" void kernel_launch(void* const* d_in, const int* in_sizes, int n_in,
                              void* d_out, int out_size, void* d_ws, size_t ws_size,
                              hipStream_t stream) {
    const float* x     = (const float*)d_in[0];
    const float* w     = (const float*)d_in[1];
    const float* bias  = (const float*)d_in[2];
    const float* pairs = (const float*)d_in[3];
    float* out = (float*)d_out;

    // ws layout: xb | wb | pk (SoA 4 planes f32) | eb (bf16 padded emissions)
    unsigned short* xb = (unsigned short*)d_ws;
    unsigned short* wb = xb + (size_t)XTOT;
    float* pkbuf = (float*)(wb + (size_t)WTOT);
    unsigned short* ebuf = (unsigned short*)(pkbuf + 4 * 2048);

    const size_t need = (size_t)(XTOT + WTOT) * 2 + (size_t)4 * 2048 * 4
                      + ((size_t)B_DIM * C_PAD + C_PAD) * 2;   // ~28.8 MiB

    if (ws_size >= need) {
        cvt_pack_kernel<<<(XTOT + WTOT + 2048) / (256 * 4), 256, 0, stream>>>(
            x, w, pairs, xb, wb, pkbuf);
        dim3 ggrid(C_PAD / 128, B_DIM / 128);
        gemm_bf16_kernel<<<ggrid, 256, 0, stream>>>(xb, wb, bias, ebuf);
        crf_wave_kernel<<<B_DIM / 8, 256, 0, stream>>>(pkbuf, ebuf, out);
    } else {
        dim3 ggrid((C_DIM + BNF - 1) / BNF, B_DIM / BMF);
        gemm_f32_kernel<<<ggrid, 256, 0, stream>>>(x, w, bias, out);
        crf_fallback_kernel<<<B_DIM, 64, 0, stream>>>(pairs, out);
    }
}

// Round 11
// 62.153 us; speedup vs baseline: 2.5653x; 1.0252x over previous
//
#include <hip/hip_runtime.h>
#include <math.h>

// Problem dims (fixed by the reference)
#define B_DIM 4096
#define F_DIM 1024
#define C_DIM 2047
#define C_PAD 2048
#define DEPTH 11

#define LOG2E 1.4426950408889634f

typedef __attribute__((ext_vector_type(8))) short bf16x8;
typedef __attribute__((ext_vector_type(4))) float f32x4;

#define AS1(p) ((const __attribute__((address_space(1))) void*)(p))
#define AS3(p) ((__attribute__((address_space(3))) void*)(p))

#define XTOT (B_DIM * F_DIM)          // 4194304
#define WTOT (C_PAD * F_DIM)          // 2097152

// ---------------------------------------------------------------------------
// bf16 helpers (RNE)
// ---------------------------------------------------------------------------
__device__ __forceinline__ unsigned short f2bf(float f) {
    unsigned int u = __float_as_uint(f);
    unsigned int r = (u + 0x7fffu + ((u >> 16) & 1u)) >> 16;
    return (unsigned short)r;
}
__device__ __forceinline__ float bf2f(unsigned short u) {
    return __uint_as_float(((unsigned int)u) << 16);
}

// ---------------------------------------------------------------------------
// Fused convert + pack:
//   x (B,F) f32 -> xb bf16 ; w (C,F) f32 -> wb bf16 (padded to C_PAD rows)
//   pairs tree edges -> pk SoA [4][2048], +1-shifted, * LOG2E
// ---------------------------------------------------------------------------
__global__ __launch_bounds__(256) void cvt_pack_kernel(
    const float* __restrict__ x, const float* __restrict__ w,
    const float* __restrict__ pairs,
    unsigned short* __restrict__ xb, unsigned short* __restrict__ wb,
    float* __restrict__ pk)
{
    const int i = (blockIdx.x * 256 + threadIdx.x) * 4;
    if (i < XTOT) {
        float4 v = *(const float4*)(x + i);
        ushort4 h;
        h.x = f2bf(v.x); h.y = f2bf(v.y); h.z = f2bf(v.z); h.w = f2bf(v.w);
        *(ushort4*)(xb + i) = h;
    } else if (i < XTOT + WTOT) {
        const int j = i - XTOT;                    // < WTOT
        const int row = j >> 10;                   // F = 1024
        ushort4 h = {0, 0, 0, 0};
        if (row < C_DIM) {
            float4 v = *(const float4*)(w + j);
            h.x = f2bf(v.x); h.y = f2bf(v.y); h.z = f2bf(v.z); h.w = f2bf(v.w);
        }
        *(ushort4*)(wb + j) = h;
    } else {
        const int c0 = i - XTOT - WTOT;            // 0..2044 step 4
#pragma unroll
        for (int t = 0; t < 4; ++t) {
            const int c = c0 + t;
            if (c >= 1 && c < C_DIM) {
                const int p = (c - 1) >> 1;
                float4 v = *(const float4*)(pairs + ((size_t)p * C_DIM + c) * 4);
                pk[c + 1]        = v.x * LOG2E;
                pk[c + 1 + 2048] = v.y * LOG2E;
                pk[c + 1 + 4096] = v.z * LOG2E;
                pk[c + 1 + 6144] = v.w * LOG2E;
            }
        }
    }
}

// ---------------------------------------------------------------------------
// MFMA GEMM, 2-phase pipeline (round-10 structure, kept):
//   eb[r*2048 + c + 1] = bf16(x @ W^T + bias)[r,c]  (padded, +1).
// 128x128 tile, K-tile = 64, double-buffered LDS, one barrier per K-tile.
// Conflict-free chunk swizzle s(row)=(row>>1)&3; XCD-aware block swizzle.
// ---------------------------------------------------------------------------
__global__ __launch_bounds__(256) void gemm_bf16_kernel(
    const unsigned short* __restrict__ xb, const unsigned short* __restrict__ wb,
    const float* __restrict__ bias, unsigned short* __restrict__ eb)
{
    __shared__ unsigned short smem[2][2][2][4096];

    const int tid  = threadIdx.x;
    const int lane = tid & 63;
    const int wave = tid >> 6;
    const int wr = wave >> 1, wc = wave & 1;

    const int lin = blockIdx.x + blockIdx.y * gridDim.x;   // 0..511
    const int wg  = (lin & 7) * 64 + (lin >> 3);
    const int bn = wg & 15, bm = wg >> 4;

    f32x4 acc[4][4] = {};

    const int r0 = tid >> 2,       c0 = tid & 3;
    const int r1 = 64 + (tid >> 2);
    const int sc0 = ((c0 ^ ((r0 >> 1) & 3)) << 3);
    const int sc1 = ((c0 ^ ((r1 >> 1) & 3)) << 3);

    const size_t arow0 = (size_t)(bm * 128 + r0) * F_DIM;
    const size_t arow1 = (size_t)(bm * 128 + r1) * F_DIM;
    const size_t brow0 = (size_t)(bn * 128 + r0) * F_DIM;
    const size_t brow1 = (size_t)(bn * 128 + r1) * F_DIM;

    const int lb0 = wave * 512;
    const int lb1 = 2048 + wave * 512;

    const int fra = wr * 64 + (lane & 15);
    const int frb = wc * 64 + (lane & 15);
    const int kc  = lane >> 4;

#define STAGE(buf, kt)                                                          \
    {                                                                           \
        const int kbase = (kt) * 64;                                            \
        _Pragma("unroll")                                                       \
        for (int ks = 0; ks < 2; ++ks) {                                        \
            const int k0 = kbase + ks * 32;                                     \
            __builtin_amdgcn_global_load_lds(AS1(xb + arow0 + k0 + sc0),        \
                AS3(&smem[buf][0][ks][lb0]), 16, 0, 0);                         \
            __builtin_amdgcn_global_load_lds(AS1(xb + arow1 + k0 + sc1),        \
                AS3(&smem[buf][0][ks][lb1]), 16, 0, 0);                         \
            __builtin_amdgcn_global_load_lds(AS1(wb + brow0 + k0 + sc0),        \
                AS3(&smem[buf][1][ks][lb0]), 16, 0, 0);                         \
            __builtin_amdgcn_global_load_lds(AS1(wb + brow1 + k0 + sc1),        \
                AS3(&smem[buf][1][ks][lb1]), 16, 0, 0);                         \
        }                                                                       \
    }

    const int NT = F_DIM / 64;   // 16
    STAGE(0, 0);
    __syncthreads();

    for (int kt = 0; kt < NT; ++kt) {
        const int cur = kt & 1;
        if (kt + 1 < NT) STAGE(cur ^ 1, kt + 1);

#pragma unroll
        for (int ks = 0; ks < 2; ++ks) {
            bf16x8 af[4], bfr[4];
#pragma unroll
            for (int m = 0; m < 4; ++m) {
                const int row = fra + m * 16;
                af[m] = *(const bf16x8*)(&smem[cur][0][ks]
                        [row * 32 + ((kc ^ ((row >> 1) & 3)) << 3)]);
            }
#pragma unroll
            for (int n = 0; n < 4; ++n) {
                const int row = frb + n * 16;
                bfr[n] = *(const bf16x8*)(&smem[cur][1][ks]
                        [row * 32 + ((kc ^ ((row >> 1) & 3)) << 3)]);
            }
#pragma unroll
            for (int m = 0; m < 4; ++m)
#pragma unroll
                for (int n = 0; n < 4; ++n)
                    acc[m][n] = __builtin_amdgcn_mfma_f32_16x16x32_bf16(
                        af[m], bfr[n], acc[m][n], 0, 0, 0);
        }
        __syncthreads();
    }
#undef STAGE

    const int colbase = bn * 128 + wc * 64 + (lane & 15);
    const int rowbase = bm * 128 + wr * 64 + ((lane >> 4) << 2);
#pragma unroll
    for (int m = 0; m < 4; ++m)
#pragma unroll
        for (int n = 0; n < 4; ++n) {
            const int gc = colbase + n * 16;
            if (gc < C_DIM) {
                const float bv = bias[gc];
#pragma unroll
                for (int r = 0; r < 4; ++r)
                    eb[(size_t)(rowbase + m * 16 + r) * C_PAD + gc + 1] =
                        f2bf(acc[m][n][r] + bv);
            }
        }
}

// ---------------------------------------------------------------------------
// Fallback f32 GEMM (only if ws too small) — writes d_out directly
// ---------------------------------------------------------------------------
#define BMF 64
#define BNF 64
#define BKF 16

__global__ __launch_bounds__(256) void gemm_f32_kernel(
    const float* __restrict__ x, const float* __restrict__ w,
    const float* __restrict__ bias, float* __restrict__ e)
{
    __shared__ float As[BKF][BMF];
    __shared__ float Bs[BKF][BNF];
    const int bn = blockIdx.x, bm = blockIdx.y;
    const int tid = threadIdx.x;
    const int tx = tid & 15, ty = tid >> 4;
    const int m0 = ty * 4, n0 = tx * 4;
    const int lrow = tid >> 2, lc4 = (tid & 3) * 4;
    const int gm = bm * BMF + lrow;
    const int gn = bn * BNF + lrow;
    const bool wvalid = (gn < C_DIM);
    const float* xp = x + (size_t)gm * F_DIM + lc4;
    const float* wp = wvalid ? (w + (size_t)gn * F_DIM + lc4) : w;
    float acc[4][4] = {};
    for (int k0 = 0; k0 < F_DIM; k0 += BKF) {
        float4 av = *(const float4*)(xp + k0);
        float4 bv = make_float4(0.f, 0.f, 0.f, 0.f);
        if (wvalid) bv = *(const float4*)(wp + k0);
        As[lc4 + 0][lrow] = av.x; As[lc4 + 1][lrow] = av.y;
        As[lc4 + 2][lrow] = av.z; As[lc4 + 3][lrow] = av.w;
        Bs[lc4 + 0][lrow] = bv.x; Bs[lc4 + 1][lrow] = bv.y;
        Bs[lc4 + 2][lrow] = bv.z; Bs[lc4 + 3][lrow] = bv.w;
        __syncthreads();
#pragma unroll
        for (int k = 0; k < BKF; ++k) {
            float4 a = *(const float4*)&As[k][m0];
            float4 b = *(const float4*)&Bs[k][n0];
            acc[0][0] += a.x * b.x; acc[0][1] += a.x * b.y; acc[0][2] += a.x * b.z; acc[0][3] += a.x * b.w;
            acc[1][0] += a.y * b.x; acc[1][1] += a.y * b.y; acc[1][2] += a.y * b.z; acc[1][3] += a.y * b.w;
            acc[2][0] += a.z * b.x; acc[2][1] += a.z * b.y; acc[2][2] += a.z * b.z; acc[2][3] += a.z * b.w;
            acc[3][0] += a.w * b.x; acc[3][1] += a.w * b.y; acc[3][2] += a.w * b.z; acc[3][3] += a.w * b.w;
        }
        __syncthreads();
    }
    const int gmo = bm * BMF + m0, gno = bn * BNF + n0;
#pragma unroll
    for (int i = 0; i < 4; ++i)
#pragma unroll
        for (int j = 0; j < 4; ++j) {
            int n = gno + j;
            if (n < C_DIM) e[(size_t)(gmo + i) * C_DIM + n] = acc[i][j] + bias[n];
        }
}

// ---------------------------------------------------------------------------
// Tree-CRF: ONE ROW PER WAVE, 4 waves/block, grid 1024 (16 waves/CU).
// pk staged once per block into LDS (32 KB) — shared by all 4 waves.
// All 21 emission loads issued UPFRONT (independent VMEM burst), then the
// level phases are pure VALU + LDS. Interleaved lane ownership (coalesced).
// ---------------------------------------------------------------------------
__device__ __forceinline__ float lse2_2(float a, float b) {
    float m = fmaxf(a, b);
    return m + __log2f(1.f + exp2f(fminf(a, b) - m));
}
__device__ __forceinline__ float sigmoid2(float d) {
    return __builtin_amdgcn_rcpf(1.f + exp2f(-d));
}

__global__ __launch_bounds__(256) void crf_wave_kernel(
    const float* __restrict__ pk,          // SoA [4][2048], +1 shifted, *LOG2E
    const unsigned short* __restrict__ eb, // (B, C_PAD) bf16 emissions, +1 shift
    float* __restrict__ out)               // (B, C_DIM) probabilities
{
    __shared__ float spk[4 * 2048];        // 32 KB: planes x,y,z,w

    const int tid  = threadIdx.x;
    // stage pk (coalesced float4, 8 per thread)
#pragma unroll
    for (int t = 0; t < 8; ++t) {
        const int idx = t * 1024 + tid * 4;
        *(float4*)(spk + idx) = *(const float4*)(pk + idx);
    }
    __syncthreads();

    const int lane = tid & 63;
    const int row  = blockIdx.x * 4 + (tid >> 6);
    const unsigned short* ebr = eb + (size_t)row * C_PAD;
    float* orow = out + (size_t)row * C_DIM;

    const float* pkx = spk;
    const float* pky = spk + 2048;
    const float* pkz = spk + 4096;
    const float* pkw = spk + 6144;

    // ---------------- ALL emission loads upfront (independent) --------------
    ushort4 evl[4]; ushort2 ev9[4];
    unsigned short ev8[4], ev7[2], ev6s, evu[6];
#pragma unroll
    for (int q = 0; q < 4; ++q)
        evl[q] = *(const ushort4*)(ebr + 1024 + 4 * lane + 256 * q);
#pragma unroll
    for (int q = 0; q < 4; ++q)
        ev9[q] = *(const ushort2*)(ebr + 512 + 2 * lane + 128 * q);
#pragma unroll
    for (int q = 0; q < 4; ++q) ev8[q] = ebr[256 + lane + 64 * q];
#pragma unroll
    for (int q = 0; q < 2; ++q) ev7[q] = ebr[128 + lane + 64 * q];
    ev6s = ebr[64 + lane];
#pragma unroll
    for (int lvl = 0; lvl < 6; ++lvl) evu[lvl] = ebr[(1 << lvl) + lane];

    // ================= UP: leaves (level 10) =================
    float el[4][4], da9[4][2];
#pragma unroll
    for (int q = 0; q < 4; ++q) {
        const int bi = 1024 + 4 * lane + 256 * q;
        float4 k4x = *(const float4*)(pkx + bi);
        float4 k4y = *(const float4*)(pky + bi);
        float4 k4z = *(const float4*)(pkz + bi);
        float4 k4w = *(const float4*)(pkw + bi);
        float er[4] = {bf2f(evl[q].x) * LOG2E, bf2f(evl[q].y) * LOG2E,
                       bf2f(evl[q].z) * LOG2E, bf2f(evl[q].w) * LOG2E};
        float xr[4] = {k4x.x, k4x.y, k4x.z, k4x.w};
        float yr[4] = {k4y.x, k4y.y, k4y.z, k4y.w};
        float zr[4] = {k4z.x, k4z.y, k4z.z, k4z.w};
        float wr4[4] = {k4w.x, k4w.y, k4w.z, k4w.w};
        float dm[4];
#pragma unroll
        for (int r = 0; r < 4; ++r) {
            el[q][r] = er[r];
            dm[r] = lse2_2(zr[r] - er[r], wr4[r] + er[r])
                  - lse2_2(xr[r] - er[r], yr[r] + er[r]);
        }
        da9[q][0] = dm[0] + dm[1];
        da9[q][1] = dm[2] + dm[3];
    }

    // ================= UP: level 9 =================
    float e9[4][2], da8[4];
#pragma unroll
    for (int q = 0; q < 4; ++q) {
        const int bi = 512 + 2 * lane + 128 * q;
        float2 k2x = *(const float2*)(pkx + bi);
        float2 k2y = *(const float2*)(pky + bi);
        float2 k2z = *(const float2*)(pkz + bi);
        float2 k2w = *(const float2*)(pkw + bi);
        float e0 = bf2f(ev9[q].x) * LOG2E, e1 = bf2f(ev9[q].y) * LOG2E;
        e9[q][0] = e0; e9[q][1] = e1;
        float dm0 = lse2_2(k2z.x - e0, k2w.x + e0 + da9[q][0])
                  - lse2_2(k2x.x - e0, k2y.x + e0 + da9[q][0]);
        float dm1 = lse2_2(k2z.y - e1, k2w.y + e1 + da9[q][1])
                  - lse2_2(k2x.y - e1, k2y.y + e1 + da9[q][1]);
        da8[q] = dm0 + dm1;
    }

    // ================= UP: level 8 =================
    float e8[4], ps8[4];
#pragma unroll
    for (int q = 0; q < 4; ++q) {
        const int bi = 256 + lane + 64 * q;
        float kx = pkx[bi], ky = pky[bi], kz = pkz[bi], kw = pkw[bi];
        float e = bf2f(ev8[q]) * LOG2E;
        e8[q] = e;
        float dm = lse2_2(kz - e, kw + e + da8[q])
                 - lse2_2(kx - e, ky + e + da8[q]);
        ps8[q] = dm + __shfl_xor(dm, 1, 64);
    }
    float da7[2];
    {
        const int s = (2 * lane) & 63;
        float t00 = __shfl(ps8[0], s, 64), t01 = __shfl(ps8[1], s, 64);
        float t10 = __shfl(ps8[2], s, 64), t11 = __shfl(ps8[3], s, 64);
        da7[0] = (lane >= 32) ? t01 : t00;
        da7[1] = (lane >= 32) ? t11 : t10;
    }

    // ================= UP: level 7 =================
    float e7[2], ps7[2];
#pragma unroll
    for (int q = 0; q < 2; ++q) {
        const int bi = 128 + lane + 64 * q;
        float kx = pkx[bi], ky = pky[bi], kz = pkz[bi], kw = pkw[bi];
        float e = bf2f(ev7[q]) * LOG2E;
        e7[q] = e;
        float dm = lse2_2(kz - e, kw + e + da7[q])
                 - lse2_2(kx - e, ky + e + da7[q]);
        ps7[q] = dm + __shfl_xor(dm, 1, 64);
    }
    float da6;
    {
        const int s = (2 * lane) & 63;
        float t0 = __shfl(ps7[0], s, 64), t1 = __shfl(ps7[1], s, 64);
        da6 = (lane >= 32) ? t1 : t0;
    }

    const float e6 = bf2f(ev6s) * LOG2E;
    float eup[6];
#pragma unroll
    for (int lvl = 0; lvl < 6; ++lvl) eup[lvl] = bf2f(evu[lvl]) * LOG2E;

    // ================= UP: shuffle levels 5..0 =================
    float daS[6];
    {
        float da_cur = da6, e_cur = e6;
        int cb = 64;
#pragma unroll
        for (int lvl = 5; lvl >= 0; --lvl) {
            const int idx = cb + lane;
            float kx = pkx[idx], ky = pky[idx], kz = pkz[idx], kw = pkw[idx];
            float m0 = lse2_2(kx - e_cur, ky + e_cur + da_cur);
            float m1 = lse2_2(kz - e_cur, kw + e_cur + da_cur);
            float dm = m1 - m0;
            float da_new = __shfl(dm, (2 * lane) & 63, 64)
                         + __shfl(dm, (2 * lane + 1) & 63, 64);
            da_cur = da_new;
            e_cur  = eup[lvl];
            daS[lvl] = da_new;
            cb = (1 << lvl);
        }
    }

    // ================= DOWN: shuffle levels 0..5 =================
    float db_cur = 0.f;
#pragma unroll
    for (int lvl = 0; lvl < 6; ++lvl) {
        const int np = 1 << lvl;
        const int idx = 2 * np + lane;
        float kx = pkx[idx], ky = pky[idx], kz = pkz[idx], kw = pkw[idx];
        if (lane < np)
            orow[np - 1 + lane] = sigmoid2(2.f * eup[lvl] + daS[lvl] + db_cur);
        float pdb = __shfl(db_cur, lane >> 1, 64);
        float pe  = __shfl(eup[lvl], lane >> 1, 64);
        db_cur = lse2_2(-pe + ky, pe + pdb + kw) - lse2_2(-pe + kx, pe + pdb + kz);
    }
    const float db6 = db_cur;
    orow[63 + lane] = sigmoid2(2.f * e6 + da6 + db6);

    // ================= DOWN: 6 -> 7 =================
    float db7[2];
#pragma unroll
    for (int q = 0; q < 2; ++q) {
        const int u = (lane >> 1) + 32 * q;
        const int bi = 128 + lane + 64 * q;
        float kx = pkx[bi], ky = pky[bi], kz = pkz[bi], kw = pkw[bi];
        float pe  = __shfl(e6, u, 64);
        float pdb = __shfl(db6, u, 64);
        db7[q] = lse2_2(-pe + ky, pe + pdb + kw) - lse2_2(-pe + kx, pe + pdb + kz);
        orow[127 + lane + 64 * q] = sigmoid2(2.f * e7[q] + da7[q] + db7[q]);
    }

    // ================= DOWN: 7 -> 8 =================
    float db8[4];
#pragma unroll
    for (int q = 0; q < 4; ++q) {
        const int u  = (lane >> 1) + 32 * q;
        const int sl = u & 63;
        const int bi = 256 + lane + 64 * q;
        float kx = pkx[bi], ky = pky[bi], kz = pkz[bi], kw = pkw[bi];
        float pe  = __shfl(e7[q >> 1], sl, 64);
        float pdb = __shfl(db7[q >> 1], sl, 64);
        db8[q] = lse2_2(-pe + ky, pe + pdb + kw) - lse2_2(-pe + kx, pe + pdb + kz);
        orow[255 + lane + 64 * q] = sigmoid2(2.f * e8[q] + da8[q] + db8[q]);
    }

    // ================= DOWN: 8 -> 9 (in-lane parents) =================
    float db9[4][2];
#pragma unroll
    for (int q = 0; q < 4; ++q) {
        const int bi = 512 + 2 * lane + 128 * q;
        float2 k2x = *(const float2*)(pkx + bi);
        float2 k2y = *(const float2*)(pky + bi);
        float2 k2z = *(const float2*)(pkz + bi);
        float2 k2w = *(const float2*)(pkw + bi);
        const float lp0 = -e8[q], lp1 = e8[q] + db8[q];
        db9[q][0] = lse2_2(lp0 + k2y.x, lp1 + k2w.x) - lse2_2(lp0 + k2x.x, lp1 + k2z.x);
        db9[q][1] = lse2_2(lp0 + k2y.y, lp1 + k2w.y) - lse2_2(lp0 + k2x.y, lp1 + k2z.y);
        orow[511 + 2 * lane + 128 * q]     = sigmoid2(2.f * e9[q][0] + da9[q][0] + db9[q][0]);
        orow[511 + 2 * lane + 128 * q + 1] = sigmoid2(2.f * e9[q][1] + da9[q][1] + db9[q][1]);
    }

    // ================= DOWN: 9 -> 10 (leaves, in-lane parents) =========
#pragma unroll
    for (int q = 0; q < 4; ++q) {
        const int bi = 1024 + 4 * lane + 256 * q;
        float4 k4x = *(const float4*)(pkx + bi);
        float4 k4y = *(const float4*)(pky + bi);
        float4 k4z = *(const float4*)(pkz + bi);
        float4 k4w = *(const float4*)(pkw + bi);
        float xr[4] = {k4x.x, k4x.y, k4x.z, k4x.w};
        float yr[4] = {k4y.x, k4y.y, k4y.z, k4y.w};
        float zr[4] = {k4z.x, k4z.y, k4z.z, k4z.w};
        float wr4[4] = {k4w.x, k4w.y, k4w.z, k4w.w};
#pragma unroll
        for (int r = 0; r < 4; ++r) {
            const float pe = e9[q][r >> 1], pdb = db9[q][r >> 1];
            float db = lse2_2(-pe + yr[r], pe + pdb + wr4[r])
                     - lse2_2(-pe + xr[r], pe + pdb + zr[r]);
            orow[1023 + 4 * lane + 256 * q + r] = sigmoid2(2.f * el[q][r] + db);
        }
    }
}

// ---------------------------------------------------------------------------
// Fallback CRF (block-per-row, LDS, raw pairs, in-place on d_out)
// ---------------------------------------------------------------------------
__global__ __launch_bounds__(64) void crf_fallback_kernel(
    const float* __restrict__ pairs, float* __restrict__ eo)
{
    __shared__ float se[C_DIM];
    __shared__ float da[1023];
    __shared__ float P0[1024];
    __shared__ float P1[1024];

    const int row  = blockIdx.x;
    const int lane = threadIdx.x;
    float* erow = eo + (size_t)row * C_DIM;

    for (int c = lane; c < C_DIM; c += 64) se[c] = erow[c] * LOG2E;
    __syncthreads();

    float* cur = P0; float* nxt = P1;
    for (int l = DEPTH - 1; l >= 1; --l) {
        const int np = 1 << (l - 1);
        const int pg0 = np - 1;
        const bool leaf = (l == DEPTH - 1);
        for (int i = lane; i < np; i += 64) {
            const int p = pg0 + i;
            float a0 = 0.f, a1 = 0.f;
#pragma unroll
            for (int s = 0; s < 2; ++s) {
                const int c = 2 * p + 1 + s;
                const int jc = 2 * i + s;
                float ca0 = 0.f, ca1 = 0.f;
                if (!leaf) { ca0 = cur[jc * 2]; ca1 = cur[jc * 2 + 1]; }
                const float l0 = -se[c] + ca0;
                const float l1 =  se[c] + ca1;
                float4 pe = *(const float4*)(pairs + ((size_t)p * C_DIM + c) * 4);
                pe.x *= LOG2E; pe.y *= LOG2E; pe.z *= LOG2E; pe.w *= LOG2E;
                a0 += lse2_2(pe.x + l0, pe.y + l1);
                a1 += lse2_2(pe.z + l0, pe.w + l1);
            }
            nxt[i * 2] = a0; nxt[i * 2 + 1] = a1;
            da[p] = a1 - a0;
        }
        __syncthreads();
        float* t = cur; cur = nxt; nxt = t;
    }
    if (lane == 0) erow[0] = sigmoid2(2.f * se[0] + da[0]);

    float* bcur = P0; float* bnxt = P1;
    for (int l = 1; l <= DEPTH - 1; ++l) {
        const int nc = 1 << l;
        const int cg0 = nc - 1;
        const bool top = (l == 1), last = (l == DEPTH - 1);
        for (int j = lane; j < nc; j += 64) {
            const int c = cg0 + j;
            const int p = (c - 1) >> 1;
            const int ip = j >> 1;
            float b0 = 0.f, b1 = 0.f;
            if (!top) { b0 = bcur[ip * 2]; b1 = bcur[ip * 2 + 1]; }
            const float lp0 = -se[p] + b0;
            const float lp1 =  se[p] + b1;
            float4 pe = *(const float4*)(pairs + ((size_t)p * C_DIM + c) * 4);
            pe.x *= LOG2E; pe.y *= LOG2E; pe.z *= LOG2E; pe.w *= LOG2E;
            const float bc0 = lse2_2(lp0 + pe.x, lp1 + pe.z);
            const float bc1 = lse2_2(lp0 + pe.y, lp1 + pe.w);
            if (!last) { bnxt[j * 2] = bc0; bnxt[j * 2 + 1] = bc1; }
            float d = 2.f * se[c] + (bc1 - bc0);
            if (c < 1023) d += da[c];
            erow[c] = sigmoid2(d);
        }
        __syncthreads();
        float* t = bcur; bcur = bnxt; bnxt = t;
    }
}

// ---------------------------------------------------------------------------
extern "C" void kernel_launch(void* const* d_in, const int* in_sizes, int n_in,
                              void* d_out, int out_size, void* d_ws, size_t ws_size,
                              hipStream_t stream) {
    const float* x     = (const float*)d_in[0];
    const float* w     = (const float*)d_in[1];
    const float* bias  = (const float*)d_in[2];
    const float* pairs = (const float*)d_in[3];
    float* out = (float*)d_out;

    // ws layout: xb | wb | pk (SoA 4 planes f32) | eb (bf16 padded emissions)
    unsigned short* xb = (unsigned short*)d_ws;
    unsigned short* wb = xb + (size_t)XTOT;
    float* pkbuf = (float*)(wb + (size_t)WTOT);
    unsigned short* ebuf = (unsigned short*)(pkbuf + 4 * 2048);

    const size_t need = (size_t)(XTOT + WTOT) * 2 + (size_t)4 * 2048 * 4
                      + ((size_t)B_DIM * C_PAD + C_PAD) * 2;   // ~28.8 MiB

    if (ws_size >= need) {
        cvt_pack_kernel<<<(XTOT + WTOT + 2048) / (256 * 4), 256, 0, stream>>>(
            x, w, pairs, xb, wb, pkbuf);
        dim3 ggrid(C_PAD / 128, B_DIM / 128);
        gemm_bf16_kernel<<<ggrid, 256, 0, stream>>>(xb, wb, bias, ebuf);
        crf_wave_kernel<<<B_DIM / 4, 256, 0, stream>>>(pkbuf, ebuf, out);
    } else {
        dim3 ggrid((C_DIM + BNF - 1) / BNF, B_DIM / BMF);
        gemm_f32_kernel<<<ggrid, 256, 0, stream>>>(x, w, bias, out);
        crf_fallback_kernel<<<B_DIM, 64, 0, stream>>>(pairs, out);
    }
}

// Round 12
// 61.601 us; speedup vs baseline: 2.5883x; 1.0090x over previous
//
#include <hip/hip_runtime.h>
#include <math.h>

// Problem dims (fixed by the reference)
#define B_DIM 4096
#define F_DIM 1024
#define C_DIM 2047
#define C_PAD 2048
#define DEPTH 11

#define LOG2E 1.4426950408889634f

typedef __attribute__((ext_vector_type(8))) short bf16x8;
typedef __attribute__((ext_vector_type(4))) float f32x4;

#define AS1(p) ((const __attribute__((address_space(1))) void*)(p))
#define AS3(p) ((__attribute__((address_space(3))) void*)(p))

#define XTOT (B_DIM * F_DIM)          // 4194304
#define WTOT (C_PAD * F_DIM)          // 2097152

// ---------------------------------------------------------------------------
// bf16 helpers (RNE)
// ---------------------------------------------------------------------------
__device__ __forceinline__ unsigned short f2bf(float f) {
    unsigned int u = __float_as_uint(f);
    unsigned int r = (u + 0x7fffu + ((u >> 16) & 1u)) >> 16;
    return (unsigned short)r;
}
__device__ __forceinline__ float bf2f(unsigned short u) {
    return __uint_as_float(((unsigned int)u) << 16);
}

// ---------------------------------------------------------------------------
// Fused convert + pack:
//   x (B,F) f32 -> xb bf16 ; w (C,F) f32 -> wb bf16 (padded to C_PAD rows)
//   pairs tree edges -> pk SoA [4][2048], +1-shifted, * LOG2E
// ---------------------------------------------------------------------------
__global__ __launch_bounds__(256) void cvt_pack_kernel(
    const float* __restrict__ x, const float* __restrict__ w,
    const float* __restrict__ pairs,
    unsigned short* __restrict__ xb, unsigned short* __restrict__ wb,
    float* __restrict__ pk)
{
    const int i = (blockIdx.x * 256 + threadIdx.x) * 4;
    if (i < XTOT) {
        float4 v = *(const float4*)(x + i);
        ushort4 h;
        h.x = f2bf(v.x); h.y = f2bf(v.y); h.z = f2bf(v.z); h.w = f2bf(v.w);
        *(ushort4*)(xb + i) = h;
    } else if (i < XTOT + WTOT) {
        const int j = i - XTOT;                    // < WTOT
        const int row = j >> 10;                   // F = 1024
        ushort4 h = {0, 0, 0, 0};
        if (row < C_DIM) {
            float4 v = *(const float4*)(w + j);
            h.x = f2bf(v.x); h.y = f2bf(v.y); h.z = f2bf(v.z); h.w = f2bf(v.w);
        }
        *(ushort4*)(wb + j) = h;
    } else {
        const int c0 = i - XTOT - WTOT;            // 0..2044 step 4
#pragma unroll
        for (int t = 0; t < 4; ++t) {
            const int c = c0 + t;
            if (c >= 1 && c < C_DIM) {
                const int p = (c - 1) >> 1;
                float4 v = *(const float4*)(pairs + ((size_t)p * C_DIM + c) * 4);
                pk[c + 1]        = v.x * LOG2E;
                pk[c + 1 + 2048] = v.y * LOG2E;
                pk[c + 1 + 4096] = v.z * LOG2E;
                pk[c + 1 + 6144] = v.w * LOG2E;
            }
        }
    }
}

// ---------------------------------------------------------------------------
// MFMA GEMM, 2-phase pipeline:
//   eb[r*2048 + c + 1] = bf16( (x @ W^T + bias)[r,c] * LOG2E )  (padded, +1,
//   pre-scaled to log2 domain for the CRF).
// 128x128 tile, K-tile = 64, double-buffered LDS, one barrier per K-tile.
// Conflict-free chunk swizzle s(row)=(row>>1)&3.
// XCD mapping: each XCD owns an 8bm x 8bn chunk (4 MB working set = L2 size).
// ---------------------------------------------------------------------------
__global__ __launch_bounds__(256) void gemm_bf16_kernel(
    const unsigned short* __restrict__ xb, const unsigned short* __restrict__ wb,
    const float* __restrict__ bias, unsigned short* __restrict__ eb)
{
    __shared__ unsigned short smem[2][2][2][4096];

    const int tid  = threadIdx.x;
    const int lane = tid & 63;
    const int wave = tid >> 6;
    const int wr = wave >> 1, wc = wave & 1;

    // XCD chunking: lin%8 = XCD; each XCD gets an 8x8 (bm,bn) chunk.
    const int lin   = blockIdx.x + blockIdx.y * gridDim.x;   // 0..511
    const int xcd   = lin & 7, local = lin >> 3;             // 8 x 64
    const int bm = (xcd >> 1) * 8 + (local >> 3);            // 0..31
    const int bn = (xcd & 1) * 8 + (local & 7);              // 0..15

    f32x4 acc[4][4] = {};

    const int r0 = tid >> 2,       c0 = tid & 3;
    const int r1 = 64 + (tid >> 2);
    const int sc0 = ((c0 ^ ((r0 >> 1) & 3)) << 3);
    const int sc1 = ((c0 ^ ((r1 >> 1) & 3)) << 3);

    const size_t arow0 = (size_t)(bm * 128 + r0) * F_DIM;
    const size_t arow1 = (size_t)(bm * 128 + r1) * F_DIM;
    const size_t brow0 = (size_t)(bn * 128 + r0) * F_DIM;
    const size_t brow1 = (size_t)(bn * 128 + r1) * F_DIM;

    const int lb0 = wave * 512;
    const int lb1 = 2048 + wave * 512;

    const int fra = wr * 64 + (lane & 15);
    const int frb = wc * 64 + (lane & 15);
    const int kc  = lane >> 4;

#define STAGE(buf, kt)                                                          \
    {                                                                           \
        const int kbase = (kt) * 64;                                            \
        _Pragma("unroll")                                                       \
        for (int ks = 0; ks < 2; ++ks) {                                        \
            const int k0 = kbase + ks * 32;                                     \
            __builtin_amdgcn_global_load_lds(AS1(xb + arow0 + k0 + sc0),        \
                AS3(&smem[buf][0][ks][lb0]), 16, 0, 0);                         \
            __builtin_amdgcn_global_load_lds(AS1(xb + arow1 + k0 + sc1),        \
                AS3(&smem[buf][0][ks][lb1]), 16, 0, 0);                         \
            __builtin_amdgcn_global_load_lds(AS1(wb + brow0 + k0 + sc0),        \
                AS3(&smem[buf][1][ks][lb0]), 16, 0, 0);                         \
            __builtin_amdgcn_global_load_lds(AS1(wb + brow1 + k0 + sc1),        \
                AS3(&smem[buf][1][ks][lb1]), 16, 0, 0);                         \
        }                                                                       \
    }

    const int NT = F_DIM / 64;   // 16
    STAGE(0, 0);
    __syncthreads();

    for (int kt = 0; kt < NT; ++kt) {
        const int cur = kt & 1;
        if (kt + 1 < NT) STAGE(cur ^ 1, kt + 1);

#pragma unroll
        for (int ks = 0; ks < 2; ++ks) {
            bf16x8 af[4], bfr[4];
#pragma unroll
            for (int m = 0; m < 4; ++m) {
                const int row = fra + m * 16;
                af[m] = *(const bf16x8*)(&smem[cur][0][ks]
                        [row * 32 + ((kc ^ ((row >> 1) & 3)) << 3)]);
            }
#pragma unroll
            for (int n = 0; n < 4; ++n) {
                const int row = frb + n * 16;
                bfr[n] = *(const bf16x8*)(&smem[cur][1][ks]
                        [row * 32 + ((kc ^ ((row >> 1) & 3)) << 3)]);
            }
#pragma unroll
            for (int m = 0; m < 4; ++m)
#pragma unroll
                for (int n = 0; n < 4; ++n)
                    acc[m][n] = __builtin_amdgcn_mfma_f32_16x16x32_bf16(
                        af[m], bfr[n], acc[m][n], 0, 0, 0);
        }
        __syncthreads();
    }
#undef STAGE

    const int colbase = bn * 128 + wc * 64 + (lane & 15);
    const int rowbase = bm * 128 + wr * 64 + ((lane >> 4) << 2);
#pragma unroll
    for (int m = 0; m < 4; ++m)
#pragma unroll
        for (int n = 0; n < 4; ++n) {
            const int gc = colbase + n * 16;
            if (gc < C_DIM) {
                const float bv = bias[gc];
#pragma unroll
                for (int r = 0; r < 4; ++r)
                    eb[(size_t)(rowbase + m * 16 + r) * C_PAD + gc + 1] =
                        f2bf((acc[m][n][r] + bv) * LOG2E);
            }
        }
}

// ---------------------------------------------------------------------------
// Fallback f32 GEMM (only if ws too small) — writes d_out directly
// ---------------------------------------------------------------------------
#define BMF 64
#define BNF 64
#define BKF 16

__global__ __launch_bounds__(256) void gemm_f32_kernel(
    const float* __restrict__ x, const float* __restrict__ w,
    const float* __restrict__ bias, float* __restrict__ e)
{
    __shared__ float As[BKF][BMF];
    __shared__ float Bs[BKF][BNF];
    const int bn = blockIdx.x, bm = blockIdx.y;
    const int tid = threadIdx.x;
    const int tx = tid & 15, ty = tid >> 4;
    const int m0 = ty * 4, n0 = tx * 4;
    const int lrow = tid >> 2, lc4 = (tid & 3) * 4;
    const int gm = bm * BMF + lrow;
    const int gn = bn * BNF + lrow;
    const bool wvalid = (gn < C_DIM);
    const float* xp = x + (size_t)gm * F_DIM + lc4;
    const float* wp = wvalid ? (w + (size_t)gn * F_DIM + lc4) : w;
    float acc[4][4] = {};
    for (int k0 = 0; k0 < F_DIM; k0 += BKF) {
        float4 av = *(const float4*)(xp + k0);
        float4 bv = make_float4(0.f, 0.f, 0.f, 0.f);
        if (wvalid) bv = *(const float4*)(wp + k0);
        As[lc4 + 0][lrow] = av.x; As[lc4 + 1][lrow] = av.y;
        As[lc4 + 2][lrow] = av.z; As[lc4 + 3][lrow] = av.w;
        Bs[lc4 + 0][lrow] = bv.x; Bs[lc4 + 1][lrow] = bv.y;
        Bs[lc4 + 2][lrow] = bv.z; Bs[lc4 + 3][lrow] = bv.w;
        __syncthreads();
#pragma unroll
        for (int k = 0; k < BKF; ++k) {
            float4 a = *(const float4*)&As[k][m0];
            float4 b = *(const float4*)&Bs[k][n0];
            acc[0][0] += a.x * b.x; acc[0][1] += a.x * b.y; acc[0][2] += a.x * b.z; acc[0][3] += a.x * b.w;
            acc[1][0] += a.y * b.x; acc[1][1] += a.y * b.y; acc[1][2] += a.y * b.z; acc[1][3] += a.y * b.w;
            acc[2][0] += a.z * b.x; acc[2][1] += a.z * b.y; acc[2][2] += a.z * b.z; acc[2][3] += a.z * b.w;
            acc[3][0] += a.w * b.x; acc[3][1] += a.w * b.y; acc[3][2] += a.w * b.z; acc[3][3] += a.w * b.w;
        }
        __syncthreads();
    }
    const int gmo = bm * BMF + m0, gno = bn * BNF + n0;
#pragma unroll
    for (int i = 0; i < 4; ++i)
#pragma unroll
        for (int j = 0; j < 4; ++j) {
            int n = gno + j;
            if (n < C_DIM) e[(size_t)(gmo + i) * C_DIM + n] = acc[i][j] + bias[n];
        }
}

// ---------------------------------------------------------------------------
// Tree-CRF: ONE ROW PER WAVE, 8 waves/block (512 thr), grid 512.
// pk staged once per block into LDS (32 KB) — shared by all 8 waves.
// Emissions arrive PRE-SCALED by log2e (GEMM epilogue) — no muls here.
// All 21 emission loads issued upfront; interleaved lane ownership.
// ---------------------------------------------------------------------------
__device__ __forceinline__ float lse2_2(float a, float b) {
    float m = fmaxf(a, b);
    return m + __log2f(1.f + exp2f(fminf(a, b) - m));
}
__device__ __forceinline__ float sigmoid2(float d) {
    return __builtin_amdgcn_rcpf(1.f + exp2f(-d));
}

__global__ __launch_bounds__(512) void crf_wave_kernel(
    const float* __restrict__ pk,          // SoA [4][2048], +1 shifted, *LOG2E
    const unsigned short* __restrict__ eb, // (B, C_PAD) bf16 emissions*LOG2E, +1
    float* __restrict__ out)               // (B, C_DIM) probabilities
{
    __shared__ float spk[4 * 2048];        // 32 KB: planes x,y,z,w

    const int tid  = threadIdx.x;
#pragma unroll
    for (int t = 0; t < 4; ++t) {
        const int idx = t * 2048 + tid * 4;
        *(float4*)(spk + idx) = *(const float4*)(pk + idx);
    }
    __syncthreads();

    const int lane = tid & 63;
    const int row  = blockIdx.x * 8 + (tid >> 6);
    const unsigned short* ebr = eb + (size_t)row * C_PAD;
    float* orow = out + (size_t)row * C_DIM;

    const float* pkx = spk;
    const float* pky = spk + 2048;
    const float* pkz = spk + 4096;
    const float* pkw = spk + 6144;

    // ---------------- ALL emission loads upfront (independent) --------------
    ushort4 evl[4]; ushort2 ev9[4];
    unsigned short ev8[4], ev7[2], ev6s, evu[6];
#pragma unroll
    for (int q = 0; q < 4; ++q)
        evl[q] = *(const ushort4*)(ebr + 1024 + 4 * lane + 256 * q);
#pragma unroll
    for (int q = 0; q < 4; ++q)
        ev9[q] = *(const ushort2*)(ebr + 512 + 2 * lane + 128 * q);
#pragma unroll
    for (int q = 0; q < 4; ++q) ev8[q] = ebr[256 + lane + 64 * q];
#pragma unroll
    for (int q = 0; q < 2; ++q) ev7[q] = ebr[128 + lane + 64 * q];
    ev6s = ebr[64 + lane];
#pragma unroll
    for (int lvl = 0; lvl < 6; ++lvl) evu[lvl] = ebr[(1 << lvl) + lane];

    // ================= UP: leaves (level 10) =================
    float el[4][4], da9[4][2];
#pragma unroll
    for (int q = 0; q < 4; ++q) {
        const int bi = 1024 + 4 * lane + 256 * q;
        float4 k4x = *(const float4*)(pkx + bi);
        float4 k4y = *(const float4*)(pky + bi);
        float4 k4z = *(const float4*)(pkz + bi);
        float4 k4w = *(const float4*)(pkw + bi);
        float er[4] = {bf2f(evl[q].x), bf2f(evl[q].y), bf2f(evl[q].z), bf2f(evl[q].w)};
        float xr[4] = {k4x.x, k4x.y, k4x.z, k4x.w};
        float yr[4] = {k4y.x, k4y.y, k4y.z, k4y.w};
        float zr[4] = {k4z.x, k4z.y, k4z.z, k4z.w};
        float wr4[4] = {k4w.x, k4w.y, k4w.z, k4w.w};
        float dm[4];
#pragma unroll
        for (int r = 0; r < 4; ++r) {
            el[q][r] = er[r];
            dm[r] = lse2_2(zr[r] - er[r], wr4[r] + er[r])
                  - lse2_2(xr[r] - er[r], yr[r] + er[r]);
        }
        da9[q][0] = dm[0] + dm[1];
        da9[q][1] = dm[2] + dm[3];
    }

    // ================= UP: level 9 =================
    float e9[4][2], da8[4];
#pragma unroll
    for (int q = 0; q < 4; ++q) {
        const int bi = 512 + 2 * lane + 128 * q;
        float2 k2x = *(const float2*)(pkx + bi);
        float2 k2y = *(const float2*)(pky + bi);
        float2 k2z = *(const float2*)(pkz + bi);
        float2 k2w = *(const float2*)(pkw + bi);
        float e0 = bf2f(ev9[q].x), e1 = bf2f(ev9[q].y);
        e9[q][0] = e0; e9[q][1] = e1;
        float dm0 = lse2_2(k2z.x - e0, k2w.x + e0 + da9[q][0])
                  - lse2_2(k2x.x - e0, k2y.x + e0 + da9[q][0]);
        float dm1 = lse2_2(k2z.y - e1, k2w.y + e1 + da9[q][1])
                  - lse2_2(k2x.y - e1, k2y.y + e1 + da9[q][1]);
        da8[q] = dm0 + dm1;
    }

    // ================= UP: level 8 =================
    float e8[4], ps8[4];
#pragma unroll
    for (int q = 0; q < 4; ++q) {
        const int bi = 256 + lane + 64 * q;
        float kx = pkx[bi], ky = pky[bi], kz = pkz[bi], kw = pkw[bi];
        float e = bf2f(ev8[q]);
        e8[q] = e;
        float dm = lse2_2(kz - e, kw + e + da8[q])
                 - lse2_2(kx - e, ky + e + da8[q]);
        ps8[q] = dm + __shfl_xor(dm, 1, 64);
    }
    float da7[2];
    {
        const int s = (2 * lane) & 63;
        float t00 = __shfl(ps8[0], s, 64), t01 = __shfl(ps8[1], s, 64);
        float t10 = __shfl(ps8[2], s, 64), t11 = __shfl(ps8[3], s, 64);
        da7[0] = (lane >= 32) ? t01 : t00;
        da7[1] = (lane >= 32) ? t11 : t10;
    }

    // ================= UP: level 7 =================
    float e7[2], ps7[2];
#pragma unroll
    for (int q = 0; q < 2; ++q) {
        const int bi = 128 + lane + 64 * q;
        float kx = pkx[bi], ky = pky[bi], kz = pkz[bi], kw = pkw[bi];
        float e = bf2f(ev7[q]);
        e7[q] = e;
        float dm = lse2_2(kz - e, kw + e + da7[q])
                 - lse2_2(kx - e, ky + e + da7[q]);
        ps7[q] = dm + __shfl_xor(dm, 1, 64);
    }
    float da6;
    {
        const int s = (2 * lane) & 63;
        float t0 = __shfl(ps7[0], s, 64), t1 = __shfl(ps7[1], s, 64);
        da6 = (lane >= 32) ? t1 : t0;
    }

    const float e6 = bf2f(ev6s);
    float eup[6];
#pragma unroll
    for (int lvl = 0; lvl < 6; ++lvl) eup[lvl] = bf2f(evu[lvl]);

    // ================= UP: shuffle levels 5..0 =================
    float daS[6];
    {
        float da_cur = da6, e_cur = e6;
        int cb = 64;
#pragma unroll
        for (int lvl = 5; lvl >= 0; --lvl) {
            const int idx = cb + lane;
            float kx = pkx[idx], ky = pky[idx], kz = pkz[idx], kw = pkw[idx];
            float m0 = lse2_2(kx - e_cur, ky + e_cur + da_cur);
            float m1 = lse2_2(kz - e_cur, kw + e_cur + da_cur);
            float dm = m1 - m0;
            float da_new = __shfl(dm, (2 * lane) & 63, 64)
                         + __shfl(dm, (2 * lane + 1) & 63, 64);
            da_cur = da_new;
            e_cur  = eup[lvl];
            daS[lvl] = da_new;
            cb = (1 << lvl);
        }
    }

    // ================= DOWN: shuffle levels 0..5 =================
    float db_cur = 0.f;
#pragma unroll
    for (int lvl = 0; lvl < 6; ++lvl) {
        const int np = 1 << lvl;
        const int idx = 2 * np + lane;
        float kx = pkx[idx], ky = pky[idx], kz = pkz[idx], kw = pkw[idx];
        if (lane < np)
            orow[np - 1 + lane] = sigmoid2(2.f * eup[lvl] + daS[lvl] + db_cur);
        float pdb = __shfl(db_cur, lane >> 1, 64);
        float pe  = __shfl(eup[lvl], lane >> 1, 64);
        db_cur = lse2_2(-pe + ky, pe + pdb + kw) - lse2_2(-pe + kx, pe + pdb + kz);
    }
    const float db6 = db_cur;
    orow[63 + lane] = sigmoid2(2.f * e6 + da6 + db6);

    // ================= DOWN: 6 -> 7 =================
    float db7[2];
#pragma unroll
    for (int q = 0; q < 2; ++q) {
        const int u = (lane >> 1) + 32 * q;
        const int bi = 128 + lane + 64 * q;
        float kx = pkx[bi], ky = pky[bi], kz = pkz[bi], kw = pkw[bi];
        float pe  = __shfl(e6, u, 64);
        float pdb = __shfl(db6, u, 64);
        db7[q] = lse2_2(-pe + ky, pe + pdb + kw) - lse2_2(-pe + kx, pe + pdb + kz);
        orow[127 + lane + 64 * q] = sigmoid2(2.f * e7[q] + da7[q] + db7[q]);
    }

    // ================= DOWN: 7 -> 8 =================
    float db8[4];
#pragma unroll
    for (int q = 0; q < 4; ++q) {
        const int u  = (lane >> 1) + 32 * q;
        const int sl = u & 63;
        const int bi = 256 + lane + 64 * q;
        float kx = pkx[bi], ky = pky[bi], kz = pkz[bi], kw = pkw[bi];
        float pe  = __shfl(e7[q >> 1], sl, 64);
        float pdb = __shfl(db7[q >> 1], sl, 64);
        db8[q] = lse2_2(-pe + ky, pe + pdb + kw) - lse2_2(-pe + kx, pe + pdb + kz);
        orow[255 + lane + 64 * q] = sigmoid2(2.f * e8[q] + da8[q] + db8[q]);
    }

    // ================= DOWN: 8 -> 9 (in-lane parents) =================
    float db9[4][2];
#pragma unroll
    for (int q = 0; q < 4; ++q) {
        const int bi = 512 + 2 * lane + 128 * q;
        float2 k2x = *(const float2*)(pkx + bi);
        float2 k2y = *(const float2*)(pky + bi);
        float2 k2z = *(const float2*)(pkz + bi);
        float2 k2w = *(const float2*)(pkw + bi);
        const float lp0 = -e8[q], lp1 = e8[q] + db8[q];
        db9[q][0] = lse2_2(lp0 + k2y.x, lp1 + k2w.x) - lse2_2(lp0 + k2x.x, lp1 + k2z.x);
        db9[q][1] = lse2_2(lp0 + k2y.y, lp1 + k2w.y) - lse2_2(lp0 + k2x.y, lp1 + k2z.y);
        orow[511 + 2 * lane + 128 * q]     = sigmoid2(2.f * e9[q][0] + da9[q][0] + db9[q][0]);
        orow[511 + 2 * lane + 128 * q + 1] = sigmoid2(2.f * e9[q][1] + da9[q][1] + db9[q][1]);
    }

    // ================= DOWN: 9 -> 10 (leaves, in-lane parents) =========
#pragma unroll
    for (int q = 0; q < 4; ++q) {
        const int bi = 1024 + 4 * lane + 256 * q;
        float4 k4x = *(const float4*)(pkx + bi);
        float4 k4y = *(const float4*)(pky + bi);
        float4 k4z = *(const float4*)(pkz + bi);
        float4 k4w = *(const float4*)(pkw + bi);
        float xr[4] = {k4x.x, k4x.y, k4x.z, k4x.w};
        float yr[4] = {k4y.x, k4y.y, k4y.z, k4y.w};
        float zr[4] = {k4z.x, k4z.y, k4z.z, k4z.w};
        float wr4[4] = {k4w.x, k4w.y, k4w.z, k4w.w};
#pragma unroll
        for (int r = 0; r < 4; ++r) {
            const float pe = e9[q][r >> 1], pdb = db9[q][r >> 1];
            float db = lse2_2(-pe + yr[r], pe + pdb + wr4[r])
                     - lse2_2(-pe + xr[r], pe + pdb + zr[r]);
            orow[1023 + 4 * lane + 256 * q + r] = sigmoid2(2.f * el[q][r] + db);
        }
    }
}

// ---------------------------------------------------------------------------
// Fallback CRF (block-per-row, LDS, raw pairs, in-place on d_out)
// ---------------------------------------------------------------------------
__global__ __launch_bounds__(64) void crf_fallback_kernel(
    const float* __restrict__ pairs, float* __restrict__ eo)
{
    __shared__ float se[C_DIM];
    __shared__ float da[1023];
    __shared__ float P0[1024];
    __shared__ float P1[1024];

    const int row  = blockIdx.x;
    const int lane = threadIdx.x;
    float* erow = eo + (size_t)row * C_DIM;

    for (int c = lane; c < C_DIM; c += 64) se[c] = erow[c] * LOG2E;
    __syncthreads();

    float* cur = P0; float* nxt = P1;
    for (int l = DEPTH - 1; l >= 1; --l) {
        const int np = 1 << (l - 1);
        const int pg0 = np - 1;
        const bool leaf = (l == DEPTH - 1);
        for (int i = lane; i < np; i += 64) {
            const int p = pg0 + i;
            float a0 = 0.f, a1 = 0.f;
#pragma unroll
            for (int s = 0; s < 2; ++s) {
                const int c = 2 * p + 1 + s;
                const int jc = 2 * i + s;
                float ca0 = 0.f, ca1 = 0.f;
                if (!leaf) { ca0 = cur[jc * 2]; ca1 = cur[jc * 2 + 1]; }
                const float l0 = -se[c] + ca0;
                const float l1 =  se[c] + ca1;
                float4 pe = *(const float4*)(pairs + ((size_t)p * C_DIM + c) * 4);
                pe.x *= LOG2E; pe.y *= LOG2E; pe.z *= LOG2E; pe.w *= LOG2E;
                a0 += lse2_2(pe.x + l0, pe.y + l1);
                a1 += lse2_2(pe.z + l0, pe.w + l1);
            }
            nxt[i * 2] = a0; nxt[i * 2 + 1] = a1;
            da[p] = a1 - a0;
        }
        __syncthreads();
        float* t = cur; cur = nxt; nxt = t;
    }
    if (lane == 0) erow[0] = sigmoid2(2.f * se[0] + da[0]);

    float* bcur = P0; float* bnxt = P1;
    for (int l = 1; l <= DEPTH - 1; ++l) {
        const int nc = 1 << l;
        const int cg0 = nc - 1;
        const bool top = (l == 1), last = (l == DEPTH - 1);
        for (int j = lane; j < nc; j += 64) {
            const int c = cg0 + j;
            const int p = (c - 1) >> 1;
            const int ip = j >> 1;
            float b0 = 0.f, b1 = 0.f;
            if (!top) { b0 = bcur[ip * 2]; b1 = bcur[ip * 2 + 1]; }
            const float lp0 = -se[p] + b0;
            const float lp1 =  se[p] + b1;
            float4 pe = *(const float4*)(pairs + ((size_t)p * C_DIM + c) * 4);
            pe.x *= LOG2E; pe.y *= LOG2E; pe.z *= LOG2E; pe.w *= LOG2E;
            const float bc0 = lse2_2(lp0 + pe.x, lp1 + pe.z);
            const float bc1 = lse2_2(lp0 + pe.y, lp1 + pe.w);
            if (!last) { bnxt[j * 2] = bc0; bnxt[j * 2 + 1] = bc1; }
            float d = 2.f * se[c] + (bc1 - bc0);
            if (c < 1023) d += da[c];
            erow[c] = sigmoid2(d);
        }
        __syncthreads();
        float* t = bcur; bcur = bnxt; bnxt = t;
    }
}

// ---------------------------------------------------------------------------
extern "C" void kernel_launch(void* const* d_in, const int* in_sizes, int n_in,
                              void* d_out, int out_size, void* d_ws, size_t ws_size,
                              hipStream_t stream) {
    const float* x     = (const float*)d_in[0];
    const float* w     = (const float*)d_in[1];
    const float* bias  = (const float*)d_in[2];
    const float* pairs = (const float*)d_in[3];
    float* out = (float*)d_out;

    // ws layout: xb | wb | pk (SoA 4 planes f32) | eb (bf16 padded emissions)
    unsigned short* xb = (unsigned short*)d_ws;
    unsigned short* wb = xb + (size_t)XTOT;
    float* pkbuf = (float*)(wb + (size_t)WTOT);
    unsigned short* ebuf = (unsigned short*)(pkbuf + 4 * 2048);

    const size_t need = (size_t)(XTOT + WTOT) * 2 + (size_t)4 * 2048 * 4
                      + ((size_t)B_DIM * C_PAD + C_PAD) * 2;   // ~28.8 MiB

    if (ws_size >= need) {
        cvt_pack_kernel<<<(XTOT + WTOT + 2048) / (256 * 4), 256, 0, stream>>>(
            x, w, pairs, xb, wb, pkbuf);
        dim3 ggrid(C_PAD / 128, B_DIM / 128);
        gemm_bf16_kernel<<<ggrid, 256, 0, stream>>>(xb, wb, bias, ebuf);
        crf_wave_kernel<<<B_DIM / 8, 512, 0, stream>>>(pkbuf, ebuf, out);
    } else {
        dim3 ggrid((C_DIM + BNF - 1) / BNF, B_DIM / BMF);
        gemm_f32_kernel<<<ggrid, 256, 0, stream>>>(x, w, bias, out);
        crf_fallback_kernel<<<B_DIM, 64, 0, stream>>>(pairs, out);
    }
}